// Round 5
// baseline (1738.838 us; speedup 1.0000x reference)
//
#include <hip/hip_runtime.h>
#include <stdint.h>

typedef __attribute__((ext_vector_type(8))) short short8;
typedef __attribute__((ext_vector_type(4))) float f32x4;

#define DEV __device__ __forceinline__

#define L2E 1.4426950408889634f

DEV unsigned short f2bf(float f) {
    union { float f; uint32_t u; } v; v.f = f;
    return (unsigned short)((v.u + 0x7FFFu + ((v.u >> 16) & 1u)) >> 16);
}
DEV float sig_(float x) {
    return __builtin_amdgcn_rcpf(1.f + __builtin_amdgcn_exp2f(-L2E * x));
}
DEV float tanh_(float x) {
    return 1.f - 2.f * __builtin_amdgcn_rcpf(1.f + __builtin_amdgcn_exp2f(2.f * L2E * x));
}
DEV float elu_(float x) {
    return x > 0.f ? x : __builtin_amdgcn_exp2f(L2E * x) - 1.f;
}
DEV f32x4 splat4(float v) { f32x4 r; r[0]=v; r[1]=v; r[2]=v; r[3]=v; return r; }
DEV void pin(short8& v) { asm volatile("" : "+v"(v)); }

// ---------------------------------------------------------------------------
// Fused weight pack: fp32 -> bf16, MFMA B-operand layout [NG rows pad][Kd pad].
// 11 jobs in one launch (blockIdx.y selects job).
// ---------------------------------------------------------------------------
struct PJob { const float* s; unsigned short* d; int Hs, NG, Ks, Kd, total; };
struct PJobs { PJob j[11]; };

__global__ __launch_bounds__(256) void pack_all(PJobs P)
{
    PJob jb = P.j[blockIdx.y];
    int e = blockIdx.x * 256 + threadIdx.x;
    if (e >= jb.total) return;
    int n = e / jb.Kd, k = e - n * jb.Kd;
    int g = n / jb.NG, jj = n - g * jb.NG;
    float v = (jj < jb.Hs && k < jb.Ks) ? jb.s[(size_t)(g * jb.Hs + jj) * jb.Ks + k] : 0.f;
    jb.d[e] = f2bf(v);
}

// ---------------------------------------------------------------------------
// Fused encoder + GRU, software-pipelined, ONE barrier per iter.
// Stages at iter i: l1 -> h1(i) | l2 -> xs(i-1) | gx(i-2) into acc[(i-2)&1] |
// gh(i-3) + gates(i-3) from acc[(i-3)&1]. gx runs AHEAD so the MFMA pipe has
// work during the gates VALU burst and the post-barrier chain is gh-only.
// Wave w owns gate-col tile w; whh/wih B-frags pinned in regs (96 VGPR).
// LDS (prox-max sizes, 33280 B):
//   0      hlds [2][16][200] bf16 (12800)   22016  w2s [64][72] bf16 (9216)
//   12800  xs   [2][16][72] bf16  (4608)    31232  pts [2][16][4] f32 (512)
//   17408  h1s  [2][16][72] bf16  (4608)    31744  w1s [64][4] f32 (1024)
//   32768  b1s[64] f32 ; 33024 b2s[64] f32
// ---------------------------------------------------------------------------
template<int H, int KP>
DEV void gru_body(int blk,
                  const float* __restrict__ obs, const int* __restrict__ idx,
                  const float* __restrict__ w1, const float* __restrict__ b1,
                  const float* __restrict__ w2, const float* __restrict__ b2,
                  const unsigned short* __restrict__ wih, const unsigned short* __restrict__ whh,
                  const float* __restrict__ bih, const float* __restrict__ bhh,
                  unsigned short* __restrict__ houtb, char* smem)
{
    constexpr int NCT = KP / 16;
    constexpr int KS  = KP / 32;
    constexpr int HP8 = KP + 8;

    unsigned short* hlds = (unsigned short*)(smem);
    unsigned short* xs   = (unsigned short*)(smem + 12800);
    unsigned short* h1s  = (unsigned short*)(smem + 17408);
    unsigned short* w2s  = (unsigned short*)(smem + 22016);
    float* ptsb          = (float*)(smem + 31232);
    float* w1s           = (float*)(smem + 31744);
    float* b1s           = (float*)(smem + 32768);
    float* b2s           = (float*)(smem + 33024);

    const int tid  = threadIdx.x;
    const int wave = tid >> 6, lane = tid & 63, quad = lane >> 4, l16 = lane & 15;
    const int b0   = blk * 16;
    const int ct   = wave;
    const bool act = (ct < NCT);
    const int c    = ct * 16 + l16;

    // ---- one-time staging ----
    for (int e = tid; e < 2*16*HP8; e += 768) hlds[e] = 0;
    for (int e = tid; e < 4096; e += 768) { int n = e >> 6, k = e & 63; w2s[n*72 + k] = f2bf(w2[e]); }
    if (tid < 192) w1s[(tid/3)*4 + (tid - (tid/3)*3)] = w1[tid];
    if (tid < 64) { b1s[tid] = b1[tid]; b2s[tid] = b2[tid]; }

    const float* myrow = obs + (size_t)(b0 + (tid & 15)) * 3120 + 48;
    float px = 0.f, py = 0.f, pz = 0.f;
    if (tid < 16) {
        int p0 = idx[0];
        ptsb[tid*4 + 0] = myrow[3*p0 + 0];
        ptsb[tid*4 + 1] = myrow[3*p0 + 1];
        ptsb[tid*4 + 2] = myrow[3*p0 + 2];
        int p1 = idx[1];
        px = myrow[3*p1 + 0]; py = myrow[3*p1 + 1]; pz = myrow[3*p1 + 2];
    }

    // ---- register-resident (pinned) weight fragments ----
    short8 whr[3][KS];
    short8 wxr[3][2];
    float bsr = 0.f, bsz = 0.f, binx = 0.f, bhnn = 0.f;
    {
        const int cl = act ? c : l16;
#pragma unroll
        for (int g = 0; g < 3; ++g) {
#pragma unroll
            for (int ks = 0; ks < KS; ++ks)
                whr[g][ks] = *(const short8*)(whh + ((size_t)(g*KP + cl))*KP + ks*32 + quad*8);
#pragma unroll
            for (int ks = 0; ks < 2; ++ks)
                wxr[g][ks] = *(const short8*)(wih + ((size_t)(g*KP + cl))*64 + ks*32 + quad*8);
        }
    }
#pragma unroll
    for (int g = 0; g < 3; ++g) {
#pragma unroll
        for (int ks = 0; ks < KS; ++ks) pin(whr[g][ks]);
#pragma unroll
        for (int ks = 0; ks < 2; ++ks)  pin(wxr[g][ks]);
    }
    if (act && c < H) {
        bsr  = bih[c]       + bhh[c];
        bsz  = bih[H + c]   + bhh[H + c];
        binx = bih[2*H + c];
        bhnn = bhh[2*H + c];
    }
    float hreg[4] = {0.f, 0.f, 0.f, 0.f};
    f32x4 acc[2][4];                       // two in-flight steps (r,z,nx,nh)

    __syncthreads();

    int cur = 0;
    for (int i = 0; i < 515; ++i) {
        const int t = i - 3;               // gh+gates step
        const int s = i - 2;               // gx step

        // ---- gh MFMAs for step t (critical chain head) ----
        if (t >= 0 && act) {
            const unsigned short* hc = hlds + cur * (16*HP8);
            f32x4* A = acc[t & 1];
#pragma unroll
            for (int ks = 0; ks < KS; ++ks) {
                short8 ah = *(const short8*)(hc + l16*HP8 + ks*32 + quad*8);
                A[0] = __builtin_amdgcn_mfma_f32_16x16x32_bf16(ah, whr[0][ks], A[0], 0, 0, 0);
                A[1] = __builtin_amdgcn_mfma_f32_16x16x32_bf16(ah, whr[1][ks], A[1], 0, 0, 0);
                A[3] = __builtin_amdgcn_mfma_f32_16x16x32_bf16(ah, whr[2][ks], A[3], 0, 0, 0);
            }
        }
        // ---- gx MFMAs for step s = t+1 (background work) ----
        if (s >= 0 && s <= 511 && act) {
            f32x4* N = acc[s & 1];
            N[0] = splat4(bsr); N[1] = splat4(bsz); N[2] = splat4(binx); N[3] = splat4(bhnn);
            const unsigned short* xsr = xs + (s & 1) * (16*72);
#pragma unroll
            for (int ks = 0; ks < 2; ++ks) {
                short8 xf = *(const short8*)(xsr + l16*72 + ks*32 + quad*8);
                N[0] = __builtin_amdgcn_mfma_f32_16x16x32_bf16(xf, wxr[0][ks], N[0], 0, 0, 0);
                N[1] = __builtin_amdgcn_mfma_f32_16x16x32_bf16(xf, wxr[1][ks], N[1], 0, 0, 0);
                N[2] = __builtin_amdgcn_mfma_f32_16x16x32_bf16(xf, wxr[2][ks], N[2], 0, 0, 0);
            }
        }
        // ---- l1: encoder layer 1 for step i ----
        if (i <= 511) {
            const float* pt = ptsb + (i & 1) * 64;
            unsigned short* h1w = h1s + (i & 1) * (16*72);
#pragma unroll
            for (int e = tid; e < 1024; e += 768) {
                int p = e >> 6, ch = e & 63;
                float v = w1s[ch*4+0]*pt[p*4+0] + w1s[ch*4+1]*pt[p*4+1]
                        + w1s[ch*4+2]*pt[p*4+2] + b1s[ch];
                h1w[p*72 + ch] = f2bf(elu_(v));
            }
        }
        // ---- pts store for i+1 + prefetch i+2 ----
        if (tid < 16) {
            float* dst = ptsb + ((i+1) & 1) * 64 + tid*4;
            dst[0] = px; dst[1] = py; dst[2] = pz;
            int tn = (i + 2 < 512) ? i + 2 : 511;
            int pn = idx[tn];
            px = myrow[3*pn + 0]; py = myrow[3*pn + 1]; pz = myrow[3*pn + 2];
        }
        // ---- l2: encoder layer 2 for step i-1 (waves 0..3) ----
        if (i >= 1 && i <= 512 && wave < 4) {
            const unsigned short* h1r = h1s + ((i-1) & 1) * (16*72);
            unsigned short*       xw  = xs  + ((i-1) & 1) * (16*72);
            f32x4 a2 = splat4(0.f);
#pragma unroll
            for (int ks = 0; ks < 2; ++ks) {
                short8 af = *(const short8*)(h1r + l16*72 + ks*32 + quad*8);
                short8 bf = *(const short8*)(w2s + (wave*16 + l16)*72 + ks*32 + quad*8);
                a2 = __builtin_amdgcn_mfma_f32_16x16x32_bf16(af, bf, a2, 0, 0, 0);
            }
            int c2 = wave*16 + l16;
            float b2v = b2s[c2];
#pragma unroll
            for (int j = 0; j < 4; ++j)
                xw[(quad*4 + j)*72 + c2] = f2bf(elu_(a2[j] + b2v));
        }
        // ---- gates + h update for step t ----
        if (t >= 0) {
            if (act) {
                unsigned short* hn = hlds + (cur ^ 1) * (16*HP8);
                f32x4* A = acc[t & 1];
#pragma unroll
                for (int j = 0; j < 4; ++j) {
                    int m = quad*4 + j;
                    float r  = sig_(A[0][j]);
                    float zg = sig_(A[1][j]);
                    float nn = tanh_(A[2][j] + r * A[3][j]);
                    float hv = nn + zg * (hreg[j] - nn);
                    hreg[j] = hv;
                    hn[m*HP8 + c] = f2bf(hv);
                }
            }
            cur ^= 1;
        }
        __syncthreads();
    }

    // ---- final h -> bf16 [16][KP], zero-padded cols ----
    if (act)
#pragma unroll
        for (int j = 0; j < 4; ++j) {
            int m = quad*4 + j;
            houtb[(size_t)(b0 + m)*KP + c] = (c < H) ? f2bf(hreg[j]) : 0;
        }
}

__global__ __launch_bounds__(768, 3) void gru_kernel(
    const float* __restrict__ obs,
    const int* __restrict__ prox_idx, const int* __restrict__ dist_idx,
    const float* __restrict__ w1p, const float* __restrict__ b1p,
    const float* __restrict__ w2p, const float* __restrict__ b2p,
    const float* __restrict__ w1d, const float* __restrict__ b1d,
    const float* __restrict__ w2d, const float* __restrict__ b2d,
    const unsigned short* __restrict__ wihp, const unsigned short* __restrict__ whhp,
    const unsigned short* __restrict__ wihd, const unsigned short* __restrict__ whhd,
    const float* __restrict__ bihp, const float* __restrict__ bhhp,
    const float* __restrict__ bihd, const float* __restrict__ bhhd,
    unsigned short* __restrict__ hpb, unsigned short* __restrict__ hdb)
{
    __shared__ __align__(16) char smem[33280];
    if (blockIdx.x < 128)
        gru_body<187, 192>(blockIdx.x, obs, prox_idx, w1p, b1p, w2p, b2p,
                           wihp, whhp, bihp, bhhp, hpb, smem);
    else
        gru_body<64, 64>(blockIdx.x - 128, obs, dist_idx, w1d, b1d, w2d, b2d,
                         wihd, whhd, bihd, bhhd, hdb, smem);
}

// ---------------------------------------------------------------------------
// bf16 MFMA GEMM: C[m][n] = act(A[m][:] . B[n][:] + bias[n])
// A [M][Kp] bf16, B [Np][Kp] bf16 (both row-major, Kp%32==0). Block = 64x64
// tile, 256 thr (4 waves, each 16m x 64n). mode 0: fp32 out (stride Nstore,
// store n<Nstore). mode 1: ELU + bf16 out (stride Np).
// ---------------------------------------------------------------------------
__global__ __launch_bounds__(256) void bgemm_kernel(
    const unsigned short* __restrict__ A, const unsigned short* __restrict__ B,
    const float* __restrict__ bias, void* __restrict__ C,
    int Kp, int Np, int Nstore, int mode)
{
    __shared__ __align__(16) unsigned short Asl[64*40];
    __shared__ __align__(16) unsigned short Bsl[64*40];
    const int tid = threadIdx.x;
    const int wave = tid >> 6, lane = tid & 63, quad = lane >> 4, l16 = lane & 15;
    const int n0 = blockIdx.x * 64, m0 = blockIdx.y * 64;
    const int r = tid >> 2, sg = (tid & 3) * 8;

    f32x4 acc[4];
#pragma unroll
    for (int nt = 0; nt < 4; ++nt) acc[nt] = splat4(0.f);

    for (int k0 = 0; k0 < Kp; k0 += 32) {
        short8 av = *(const short8*)(A + (size_t)(m0 + r)*Kp + k0 + sg);
        short8 bv;
        if (n0 + r < Np) bv = *(const short8*)(B + (size_t)(n0 + r)*Kp + k0 + sg);
        else { short8 z; for (int q = 0; q < 8; ++q) z[q] = 0; bv = z; }
        *(short8*)(Asl + r*40 + sg) = av;
        *(short8*)(Bsl + r*40 + sg) = bv;
        __syncthreads();
        short8 af = *(const short8*)(Asl + (wave*16 + l16)*40 + quad*8);
#pragma unroll
        for (int nt = 0; nt < 4; ++nt) {
            short8 bf = *(const short8*)(Bsl + (nt*16 + l16)*40 + quad*8);
            acc[nt] = __builtin_amdgcn_mfma_f32_16x16x32_bf16(af, bf, acc[nt], 0, 0, 0);
        }
        __syncthreads();
    }
#pragma unroll
    for (int nt = 0; nt < 4; ++nt) {
        int n = n0 + nt*16 + l16;
        float bv = (bias && n < Np) ? bias[n] : 0.f;
#pragma unroll
        for (int j = 0; j < 4; ++j) {
            int m = m0 + wave*16 + quad*4 + j;
            float v = acc[nt][j] + bv;
            if (mode == 1) {
                ((unsigned short*)C)[(size_t)m*Np + n] = f2bf(elu_(v));
            } else {
                if (n < Nstore) ((float*)C)[(size_t)m*Nstore + n] = v;
            }
        }
    }
}

// ---------------------------------------------------------------------------
// Fused mem-GRU gates (T=1, h0=0 => f=(1-z)*n) + concat -> bf16 x0 [2048][320]
// cols: [0,48) proprio | [48,235) f_prox | [235,299) f_dist | [299,320) zero
// ---------------------------------------------------------------------------
__global__ __launch_bounds__(256) void memcat_kernel(
    const float* __restrict__ obs, const float* __restrict__ Gp, const float* __restrict__ Gd,
    const float* __restrict__ mbip, const float* __restrict__ mbhp,
    const float* __restrict__ mbid, const float* __restrict__ mbhd,
    unsigned short* __restrict__ x0b)
{
    int i = blockIdx.x * 256 + threadIdx.x;
    if (i >= 2048 * 320) return;
    int b = i / 320, cc = i - b * 320;
    float v;
    if (cc < 48) {
        v = obs[(size_t)b*3120 + cc];
    } else if (cc < 235) {
        int j = cc - 48;
        float dr = Gp[(size_t)b*576 + j];
        float dz = Gp[(size_t)b*576 + 192 + j];
        float dn = Gp[(size_t)b*576 + 384 + j];
        float r  = sig_(dr + mbip[j] + mbhp[j]);
        float zg = sig_(dz + mbip[187+j] + mbhp[187+j]);
        float nn = tanh_(dn + mbip[374+j] + r * mbhp[374+j]);
        v = (1.f - zg) * nn;
    } else if (cc < 299) {
        int j = cc - 235;
        float dr = Gd[(size_t)b*192 + j];
        float dz = Gd[(size_t)b*192 + 64 + j];
        float dn = Gd[(size_t)b*192 + 128 + j];
        float r  = sig_(dr + mbid[j] + mbhd[j]);
        float zg = sig_(dz + mbid[64+j] + mbhd[64+j]);
        float nn = tanh_(dn + mbid[128+j] + r * mbhd[128+j]);
        v = (1.f - zg) * nn;
    } else {
        v = 0.f;
    }
    x0b[i] = f2bf(v);
}

// ---------------------------------------------------------------------------
extern "C" void kernel_launch(void* const* d_in, const int* in_sizes, int n_in,
                              void* d_out, int out_size, void* d_ws, size_t ws_size,
                              hipStream_t stream)
{
    (void)in_sizes; (void)n_in; (void)out_size; (void)ws_size;
    const float* obs        = (const float*)d_in[0];
    const int*   prox_idx   = (const int*)d_in[1];
    const int*   dist_idx   = (const int*)d_in[2];
    const float* pe_prox_w1 = (const float*)d_in[3];
    const float* pe_prox_b1 = (const float*)d_in[4];
    const float* pe_prox_w2 = (const float*)d_in[5];
    const float* pe_prox_b2 = (const float*)d_in[6];
    const float* pe_dist_w1 = (const float*)d_in[7];
    const float* pe_dist_b1 = (const float*)d_in[8];
    const float* pe_dist_w2 = (const float*)d_in[9];
    const float* pe_dist_b2 = (const float*)d_in[10];
    const float* gp_wih = (const float*)d_in[11];
    const float* gp_whh = (const float*)d_in[12];
    const float* gp_bih = (const float*)d_in[13];
    const float* gp_bhh = (const float*)d_in[14];
    const float* gd_wih = (const float*)d_in[15];
    const float* gd_whh = (const float*)d_in[16];
    const float* gd_bih = (const float*)d_in[17];
    const float* gd_bhh = (const float*)d_in[18];
    const float* mp_wih = (const float*)d_in[19];
    const float* mp_bih = (const float*)d_in[21];
    const float* mp_bhh = (const float*)d_in[22];
    const float* md_wih = (const float*)d_in[23];
    const float* md_bih = (const float*)d_in[25];
    const float* md_bhh = (const float*)d_in[26];
    const float* aw0 = (const float*)d_in[27]; const float* ab0 = (const float*)d_in[28];
    const float* aw1 = (const float*)d_in[29]; const float* ab1 = (const float*)d_in[30];
    const float* aw2 = (const float*)d_in[31]; const float* ab2 = (const float*)d_in[32];
    const float* aw3 = (const float*)d_in[33]; const float* ab3 = (const float*)d_in[34];
    const float* aw4 = (const float*)d_in[35]; const float* ab4 = (const float*)d_in[36];
    float* out = (float*)d_out;

    char* ws = (char*)d_ws;
    size_t off = 0;
    auto alloc = [&](size_t bytes) -> char* {
        char* p = ws + off;
        off = (off + bytes + 255) & ~(size_t)255;
        return p;
    };
    unsigned short* wih_p = (unsigned short*)alloc(36864*2);
    unsigned short* whh_p = (unsigned short*)alloc(110592*2);
    unsigned short* wih_d = (unsigned short*)alloc(12288*2);
    unsigned short* whh_d = (unsigned short*)alloc(12288*2);
    unsigned short* mw_p  = (unsigned short*)alloc(110592*2);
    unsigned short* mw_d  = (unsigned short*)alloc(12288*2);
    unsigned short* w0p   = (unsigned short*)alloc((size_t)1024*320*2);
    unsigned short* w1p   = (unsigned short*)alloc((size_t)512*1024*2);
    unsigned short* w2p   = (unsigned short*)alloc((size_t)256*512*2);
    unsigned short* w3p   = (unsigned short*)alloc((size_t)128*256*2);
    unsigned short* w4p   = (unsigned short*)alloc((size_t)16*128*2);
    unsigned short* hpb   = (unsigned short*)alloc((size_t)2048*192*2);
    unsigned short* hdb   = (unsigned short*)alloc((size_t)2048*64*2);
    float* Gp             = (float*)alloc((size_t)2048*576*4);
    float* Gd             = (float*)alloc((size_t)2048*192*4);
    unsigned short* x0b   = (unsigned short*)alloc((size_t)2048*320*2);
    unsigned short* a1b   = (unsigned short*)alloc((size_t)2048*1024*2);
    unsigned short* a2b   = (unsigned short*)alloc((size_t)2048*512*2);
    unsigned short* a3b   = (unsigned short*)alloc((size_t)2048*256*2);
    unsigned short* a4b   = (unsigned short*)alloc((size_t)2048*128*2);

    // --- one fused pack launch (11 jobs) ---
    PJobs P;
    P.j[0]  = { gp_wih, wih_p, 187, 192, 64, 64, 36864 };
    P.j[1]  = { gp_whh, whh_p, 187, 192, 187, 192, 110592 };
    P.j[2]  = { gd_wih, wih_d, 64, 64, 64, 64, 12288 };
    P.j[3]  = { gd_whh, whh_d, 64, 64, 64, 64, 12288 };
    P.j[4]  = { mp_wih, mw_p, 187, 192, 187, 192, 110592 };
    P.j[5]  = { md_wih, mw_d, 64, 64, 64, 64, 12288 };
    P.j[6]  = { aw0, w0p, 1024, 1024, 299, 320, 327680 };
    P.j[7]  = { aw1, w1p, 512, 512, 1024, 1024, 524288 };
    P.j[8]  = { aw2, w2p, 256, 256, 512, 512, 131072 };
    P.j[9]  = { aw3, w3p, 128, 128, 256, 256, 32768 };
    P.j[10] = { aw4, w4p, 12, 16, 128, 128, 2048 };
    pack_all<<<dim3(2048, 11), 256, 0, stream>>>(P);

    // --- fused encoder + GRU recurrence (128 prox + 128 dist blocks) ---
    gru_kernel<<<256, 768, 0, stream>>>(
        obs, prox_idx, dist_idx,
        pe_prox_w1, pe_prox_b1, pe_prox_w2, pe_prox_b2,
        pe_dist_w1, pe_dist_b1, pe_dist_w2, pe_dist_b2,
        wih_p, whh_p, wih_d, whh_d,
        gp_bih, gp_bhh, gd_bih, gd_bhh, hpb, hdb);

    // --- mem GRUs: G = h @ W^T (MFMA), then fused gates+concat -> bf16 x0 ---
    bgemm_kernel<<<dim3(9, 32), 256, 0, stream>>>(hpb, mw_p, nullptr, Gp, 192, 576, 576, 0);
    bgemm_kernel<<<dim3(3, 32), 256, 0, stream>>>(hdb, mw_d, nullptr, Gd, 64, 192, 192, 0);
    memcat_kernel<<<2560, 256, 0, stream>>>(obs, Gp, Gd, mp_bih, mp_bhh, md_bih, md_bhh, x0b);

    // --- actor MLP (bf16 MFMA chain) ---
    bgemm_kernel<<<dim3(16, 32), 256, 0, stream>>>(x0b, w0p, ab0, a1b, 320, 1024, 1024, 1);
    bgemm_kernel<<<dim3(8,  32), 256, 0, stream>>>(a1b, w1p, ab1, a2b, 1024, 512, 512, 1);
    bgemm_kernel<<<dim3(4,  32), 256, 0, stream>>>(a2b, w2p, ab2, a3b, 512, 256, 256, 1);
    bgemm_kernel<<<dim3(2,  32), 256, 0, stream>>>(a3b, w3p, ab3, a4b, 256, 128, 128, 1);
    bgemm_kernel<<<dim3(1,  32), 256, 0, stream>>>(a4b, w4p, ab4, out, 128, 16, 12, 0);
}

// Round 6
// 867.806 us; speedup vs baseline: 2.0037x; 2.0037x over previous
//
#include <hip/hip_runtime.h>
#include <stdint.h>

typedef __attribute__((ext_vector_type(8))) short short8;
typedef __attribute__((ext_vector_type(4))) float f32x4;

#define DEV __device__ __forceinline__

#define L2E 1.4426950408889634f

DEV unsigned short f2bf(float f) {
    union { float f; uint32_t u; } v; v.f = f;
    return (unsigned short)((v.u + 0x7FFFu + ((v.u >> 16) & 1u)) >> 16);
}
DEV float sig_(float x) {
    return __builtin_amdgcn_rcpf(1.f + __builtin_amdgcn_exp2f(-L2E * x));
}
DEV float tanh_(float x) {
    return 1.f - 2.f * __builtin_amdgcn_rcpf(1.f + __builtin_amdgcn_exp2f(2.f * L2E * x));
}
DEV float elu_(float x) {
    return x > 0.f ? x : __builtin_amdgcn_exp2f(L2E * x) - 1.f;
}
DEV f32x4 splat4(float v) { f32x4 r; r[0]=v; r[1]=v; r[2]=v; r[3]=v; return r; }
DEV void pin(short8& v) { asm volatile("" : "+v"(v)); }

// ---------------------------------------------------------------------------
// Fused weight pack: fp32 -> bf16, MFMA B-operand layout [NG rows pad][Kd pad].
// ---------------------------------------------------------------------------
struct PJob { const float* s; unsigned short* d; int Hs, NG, Ks, Kd, total; };
struct PJobs { PJob j[11]; };

__global__ __launch_bounds__(256) void pack_all(PJobs P)
{
    PJob jb = P.j[blockIdx.y];
    int e = blockIdx.x * 256 + threadIdx.x;
    if (e >= jb.total) return;
    int n = e / jb.Kd, k = e - n * jb.Kd;
    int g = n / jb.NG, jj = n - g * jb.NG;
    float v = (jj < jb.Hs && k < jb.Ks) ? jb.s[(size_t)(g * jb.Hs + jj) * jb.Ks + k] : 0.f;
    jb.d[e] = f2bf(v);
}

// ---------------------------------------------------------------------------
// Fused encoder + GRU, software-pipelined, ONE barrier per iter (round-4
// structure). Iter i: l1 -> h1(i) | l2 -> xs(i-1) | GRU step (gh, gates) at
// i-2. Wave w owns gate-col tile w; whh/wih B-frags pinned in regs (96 VGPR).
// KEY: kernel is compiled with amdgpu_waves_per_eu(3,3) -> 170-VGPR budget,
// so the pinned fragments actually stay register-resident (round 3/4/5 all
// ran at the compiler's self-chosen 84-VGPR budget and silently re-streamed
// weights from L2 every step).
// LDS (prox-max sizes, 33280 B):
//   0      hlds [2][16][200] bf16 (12800)   22016  w2s [64][72] bf16 (9216)
//   12800  xs   [2][16][72] bf16  (4608)    31232  pts [2][16][4] f32 (512)
//   17408  h1s  [2][16][72] bf16  (4608)    31744  w1s [64][4] f32 (1024)
//   32768  b1s[64] f32 ; 33024 b2s[64] f32
// ---------------------------------------------------------------------------
template<int H, int KP>
DEV void gru_body(int blk,
                  const float* __restrict__ obs, const int* __restrict__ idx,
                  const float* __restrict__ w1, const float* __restrict__ b1,
                  const float* __restrict__ w2, const float* __restrict__ b2,
                  const unsigned short* __restrict__ wih, const unsigned short* __restrict__ whh,
                  const float* __restrict__ bih, const float* __restrict__ bhh,
                  unsigned short* __restrict__ houtb, char* smem)
{
    constexpr int NCT = KP / 16;
    constexpr int KS  = KP / 32;
    constexpr int HP8 = KP + 8;

    unsigned short* hlds = (unsigned short*)(smem);
    unsigned short* xs   = (unsigned short*)(smem + 12800);
    unsigned short* h1s  = (unsigned short*)(smem + 17408);
    unsigned short* w2s  = (unsigned short*)(smem + 22016);
    float* ptsb          = (float*)(smem + 31232);
    float* w1s           = (float*)(smem + 31744);
    float* b1s           = (float*)(smem + 32768);
    float* b2s           = (float*)(smem + 33024);

    const int tid  = threadIdx.x;
    const int wave = tid >> 6, lane = tid & 63, quad = lane >> 4, l16 = lane & 15;
    const int b0   = blk * 16;
    const int ct   = wave;
    const bool act = (ct < NCT);
    const int c    = ct * 16 + l16;

    // ---- one-time staging ----
    for (int e = tid; e < 2*16*HP8; e += 768) hlds[e] = 0;
    for (int e = tid; e < 4096; e += 768) { int n = e >> 6, k = e & 63; w2s[n*72 + k] = f2bf(w2[e]); }
    if (tid < 192) w1s[(tid/3)*4 + (tid - (tid/3)*3)] = w1[tid];
    if (tid < 64) { b1s[tid] = b1[tid]; b2s[tid] = b2[tid]; }

    const float* myrow = obs + (size_t)(b0 + (tid & 15)) * 3120 + 48;
    float px = 0.f, py = 0.f, pz = 0.f;
    if (tid < 16) {
        int p0 = idx[0];
        ptsb[tid*4 + 0] = myrow[3*p0 + 0];
        ptsb[tid*4 + 1] = myrow[3*p0 + 1];
        ptsb[tid*4 + 2] = myrow[3*p0 + 2];
        int p1 = idx[1];
        px = myrow[3*p1 + 0]; py = myrow[3*p1 + 1]; pz = myrow[3*p1 + 2];
    }

    // ---- register-resident (pinned) weight fragments ----
    short8 whr[3][KS];
    short8 wxr[3][2];
    float bsr = 0.f, bsz = 0.f, binx = 0.f, bhnn = 0.f;
    {
        const int cl = act ? c : l16;
#pragma unroll
        for (int g = 0; g < 3; ++g) {
#pragma unroll
            for (int ks = 0; ks < KS; ++ks)
                whr[g][ks] = *(const short8*)(whh + ((size_t)(g*KP + cl))*KP + ks*32 + quad*8);
#pragma unroll
            for (int ks = 0; ks < 2; ++ks)
                wxr[g][ks] = *(const short8*)(wih + ((size_t)(g*KP + cl))*64 + ks*32 + quad*8);
        }
    }
#pragma unroll
    for (int g = 0; g < 3; ++g) {
#pragma unroll
        for (int ks = 0; ks < KS; ++ks) pin(whr[g][ks]);
#pragma unroll
        for (int ks = 0; ks < 2; ++ks)  pin(wxr[g][ks]);
    }
    if (act && c < H) {
        bsr  = bih[c]       + bhh[c];
        bsz  = bih[H + c]   + bhh[H + c];
        binx = bih[2*H + c];
        bhnn = bhh[2*H + c];
    }
    float hreg[4] = {0.f, 0.f, 0.f, 0.f};

    __syncthreads();

    int cur = 0;
    for (int i = 0; i < 514; ++i) {
        // ---- l1: encoder layer 1 for step i ----
        if (i < 512) {
            const float* pt = ptsb + (i & 1) * 64;
            unsigned short* h1w = h1s + (i & 1) * (16*72);
#pragma unroll
            for (int e = tid; e < 1024; e += 768) {
                int p = e >> 6, ch = e & 63;
                float v = w1s[ch*4+0]*pt[p*4+0] + w1s[ch*4+1]*pt[p*4+1]
                        + w1s[ch*4+2]*pt[p*4+2] + b1s[ch];
                h1w[p*72 + ch] = f2bf(elu_(v));
            }
            if (tid < 16) {
                float* dst = ptsb + ((i+1) & 1) * 64 + tid*4;
                dst[0] = px; dst[1] = py; dst[2] = pz;
                int tn = (i + 2 < 512) ? i + 2 : 511;
                int pn = idx[tn];
                px = myrow[3*pn + 0]; py = myrow[3*pn + 1]; pz = myrow[3*pn + 2];
            }
        }
        // ---- l2: encoder layer 2 for step i-1 (waves 0..3) ----
        if (i >= 1 && i < 513 && wave < 4) {
            const unsigned short* h1r = h1s + ((i-1) & 1) * (16*72);
            unsigned short*       xw  = xs  + ((i-1) & 1) * (16*72);
            f32x4 a2 = splat4(0.f);
#pragma unroll
            for (int ks = 0; ks < 2; ++ks) {
                short8 af = *(const short8*)(h1r + l16*72 + ks*32 + quad*8);
                short8 bf = *(const short8*)(w2s + (wave*16 + l16)*72 + ks*32 + quad*8);
                a2 = __builtin_amdgcn_mfma_f32_16x16x32_bf16(af, bf, a2, 0, 0, 0);
            }
            int c2 = wave*16 + l16;
            float b2v = b2s[c2];
#pragma unroll
            for (int j = 0; j < 4; ++j)
                xw[(quad*4 + j)*72 + c2] = f2bf(elu_(a2[j] + b2v));
        }
        // ---- GRU step t = i-2: gx + gh + gates ----
        if (i >= 2) {
            int t = i - 2;
            const unsigned short* xsr = xs + (t & 1) * (16*72);
            const unsigned short* hc  = hlds + cur * (16*HP8);
            unsigned short*       hn  = hlds + (cur ^ 1) * (16*HP8);
            if (act) {
                f32x4 acc[4];                          // r, z, nx, nh
                acc[0] = splat4(bsr);
                acc[1] = splat4(bsz);
                acc[2] = splat4(binx);
                acc[3] = splat4(bhnn);
#pragma unroll
                for (int ks = 0; ks < 2; ++ks) {
                    short8 xf = *(const short8*)(xsr + l16*72 + ks*32 + quad*8);
                    acc[0] = __builtin_amdgcn_mfma_f32_16x16x32_bf16(xf, wxr[0][ks], acc[0], 0, 0, 0);
                    acc[1] = __builtin_amdgcn_mfma_f32_16x16x32_bf16(xf, wxr[1][ks], acc[1], 0, 0, 0);
                    acc[2] = __builtin_amdgcn_mfma_f32_16x16x32_bf16(xf, wxr[2][ks], acc[2], 0, 0, 0);
                }
#pragma unroll
                for (int ks = 0; ks < KS; ++ks) {
                    short8 ah = *(const short8*)(hc + l16*HP8 + ks*32 + quad*8);
                    acc[0] = __builtin_amdgcn_mfma_f32_16x16x32_bf16(ah, whr[0][ks], acc[0], 0, 0, 0);
                    acc[1] = __builtin_amdgcn_mfma_f32_16x16x32_bf16(ah, whr[1][ks], acc[1], 0, 0, 0);
                    acc[3] = __builtin_amdgcn_mfma_f32_16x16x32_bf16(ah, whr[2][ks], acc[3], 0, 0, 0);
                }
#pragma unroll
                for (int j = 0; j < 4; ++j) {
                    int m = quad*4 + j;
                    float r  = sig_(acc[0][j]);
                    float zg = sig_(acc[1][j]);
                    float nn = tanh_(acc[2][j] + r * acc[3][j]);
                    float hv = nn + zg * (hreg[j] - nn);
                    hreg[j] = hv;
                    hn[m*HP8 + c] = f2bf(hv);
                }
            }
            cur ^= 1;
        }
        __syncthreads();
    }

    // ---- final h -> bf16 [16][KP], zero-padded cols ----
    if (act)
#pragma unroll
        for (int j = 0; j < 4; ++j) {
            int m = quad*4 + j;
            houtb[(size_t)(b0 + m)*KP + c] = (c < H) ? f2bf(hreg[j]) : 0;
        }
}

__global__ __launch_bounds__(768)
__attribute__((amdgpu_waves_per_eu(3, 3)))
void gru_kernel(
    const float* __restrict__ obs,
    const int* __restrict__ prox_idx, const int* __restrict__ dist_idx,
    const float* __restrict__ w1p, const float* __restrict__ b1p,
    const float* __restrict__ w2p, const float* __restrict__ b2p,
    const float* __restrict__ w1d, const float* __restrict__ b1d,
    const float* __restrict__ w2d, const float* __restrict__ b2d,
    const unsigned short* __restrict__ wihp, const unsigned short* __restrict__ whhp,
    const unsigned short* __restrict__ wihd, const unsigned short* __restrict__ whhd,
    const float* __restrict__ bihp, const float* __restrict__ bhhp,
    const float* __restrict__ bihd, const float* __restrict__ bhhd,
    unsigned short* __restrict__ hpb, unsigned short* __restrict__ hdb)
{
    __shared__ __align__(16) char smem[33280];
    if (blockIdx.x < 128)
        gru_body<187, 192>(blockIdx.x, obs, prox_idx, w1p, b1p, w2p, b2p,
                           wihp, whhp, bihp, bhhp, hpb, smem);
    else
        gru_body<64, 64>(blockIdx.x - 128, obs, dist_idx, w1d, b1d, w2d, b2d,
                         wihd, whhd, bihd, bhhd, hdb, smem);
}

// ---------------------------------------------------------------------------
// bf16 MFMA GEMM: C[m][n] = act(A[m][:] . B[n][:] + bias[n])
// A [M][Kp] bf16, B [Np][Kp] bf16 (row-major, Kp%32==0). 64x64 tile, 256 thr.
// mode 0: fp32 out (stride Nstore, store n<Nstore). mode 1: ELU + bf16 out.
// ---------------------------------------------------------------------------
__global__ __launch_bounds__(256) void bgemm_kernel(
    const unsigned short* __restrict__ A, const unsigned short* __restrict__ B,
    const float* __restrict__ bias, void* __restrict__ C,
    int Kp, int Np, int Nstore, int mode)
{
    __shared__ __align__(16) unsigned short Asl[64*40];
    __shared__ __align__(16) unsigned short Bsl[64*40];
    const int tid = threadIdx.x;
    const int wave = tid >> 6, lane = tid & 63, quad = lane >> 4, l16 = lane & 15;
    const int n0 = blockIdx.x * 64, m0 = blockIdx.y * 64;
    const int r = tid >> 2, sg = (tid & 3) * 8;

    f32x4 acc[4];
#pragma unroll
    for (int nt = 0; nt < 4; ++nt) acc[nt] = splat4(0.f);

    for (int k0 = 0; k0 < Kp; k0 += 32) {
        short8 av = *(const short8*)(A + (size_t)(m0 + r)*Kp + k0 + sg);
        short8 bv;
        if (n0 + r < Np) bv = *(const short8*)(B + (size_t)(n0 + r)*Kp + k0 + sg);
        else { short8 z; for (int q = 0; q < 8; ++q) z[q] = 0; bv = z; }
        *(short8*)(Asl + r*40 + sg) = av;
        *(short8*)(Bsl + r*40 + sg) = bv;
        __syncthreads();
        short8 af = *(const short8*)(Asl + (wave*16 + l16)*40 + quad*8);
#pragma unroll
        for (int nt = 0; nt < 4; ++nt) {
            short8 bf = *(const short8*)(Bsl + (nt*16 + l16)*40 + quad*8);
            acc[nt] = __builtin_amdgcn_mfma_f32_16x16x32_bf16(af, bf, acc[nt], 0, 0, 0);
        }
        __syncthreads();
    }
#pragma unroll
    for (int nt = 0; nt < 4; ++nt) {
        int n = n0 + nt*16 + l16;
        float bv = (bias && n < Np) ? bias[n] : 0.f;
#pragma unroll
        for (int j = 0; j < 4; ++j) {
            int m = m0 + wave*16 + quad*4 + j;
            float v = acc[nt][j] + bv;
            if (mode == 1) {
                ((unsigned short*)C)[(size_t)m*Np + n] = f2bf(elu_(v));
            } else {
                if (n < Nstore) ((float*)C)[(size_t)m*Nstore + n] = v;
            }
        }
    }
}

// ---------------------------------------------------------------------------
// Fused mem-GRU gates (T=1, h0=0 => f=(1-z)*n) + concat -> bf16 x0 [2048][320]
// ---------------------------------------------------------------------------
__global__ __launch_bounds__(256) void memcat_kernel(
    const float* __restrict__ obs, const float* __restrict__ Gp, const float* __restrict__ Gd,
    const float* __restrict__ mbip, const float* __restrict__ mbhp,
    const float* __restrict__ mbid, const float* __restrict__ mbhd,
    unsigned short* __restrict__ x0b)
{
    int i = blockIdx.x * 256 + threadIdx.x;
    if (i >= 2048 * 320) return;
    int b = i / 320, cc = i - b * 320;
    float v;
    if (cc < 48) {
        v = obs[(size_t)b*3120 + cc];
    } else if (cc < 235) {
        int j = cc - 48;
        float dr = Gp[(size_t)b*576 + j];
        float dz = Gp[(size_t)b*576 + 192 + j];
        float dn = Gp[(size_t)b*576 + 384 + j];
        float r  = sig_(dr + mbip[j] + mbhp[j]);
        float zg = sig_(dz + mbip[187+j] + mbhp[187+j]);
        float nn = tanh_(dn + mbip[374+j] + r * mbhp[374+j]);
        v = (1.f - zg) * nn;
    } else if (cc < 299) {
        int j = cc - 235;
        float dr = Gd[(size_t)b*192 + j];
        float dz = Gd[(size_t)b*192 + 64 + j];
        float dn = Gd[(size_t)b*192 + 128 + j];
        float r  = sig_(dr + mbid[j] + mbhd[j]);
        float zg = sig_(dz + mbid[64+j] + mbhd[64+j]);
        float nn = tanh_(dn + mbid[128+j] + r * mbhd[128+j]);
        v = (1.f - zg) * nn;
    } else {
        v = 0.f;
    }
    x0b[i] = f2bf(v);
}

// ---------------------------------------------------------------------------
extern "C" void kernel_launch(void* const* d_in, const int* in_sizes, int n_in,
                              void* d_out, int out_size, void* d_ws, size_t ws_size,
                              hipStream_t stream)
{
    (void)in_sizes; (void)n_in; (void)out_size; (void)ws_size;
    const float* obs        = (const float*)d_in[0];
    const int*   prox_idx   = (const int*)d_in[1];
    const int*   dist_idx   = (const int*)d_in[2];
    const float* pe_prox_w1 = (const float*)d_in[3];
    const float* pe_prox_b1 = (const float*)d_in[4];
    const float* pe_prox_w2 = (const float*)d_in[5];
    const float* pe_prox_b2 = (const float*)d_in[6];
    const float* pe_dist_w1 = (const float*)d_in[7];
    const float* pe_dist_b1 = (const float*)d_in[8];
    const float* pe_dist_w2 = (const float*)d_in[9];
    const float* pe_dist_b2 = (const float*)d_in[10];
    const float* gp_wih = (const float*)d_in[11];
    const float* gp_whh = (const float*)d_in[12];
    const float* gp_bih = (const float*)d_in[13];
    const float* gp_bhh = (const float*)d_in[14];
    const float* gd_wih = (const float*)d_in[15];
    const float* gd_whh = (const float*)d_in[16];
    const float* gd_bih = (const float*)d_in[17];
    const float* gd_bhh = (const float*)d_in[18];
    const float* mp_wih = (const float*)d_in[19];
    const float* mp_bih = (const float*)d_in[21];
    const float* mp_bhh = (const float*)d_in[22];
    const float* md_wih = (const float*)d_in[23];
    const float* md_bih = (const float*)d_in[25];
    const float* md_bhh = (const float*)d_in[26];
    const float* aw0 = (const float*)d_in[27]; const float* ab0 = (const float*)d_in[28];
    const float* aw1 = (const float*)d_in[29]; const float* ab1 = (const float*)d_in[30];
    const float* aw2 = (const float*)d_in[31]; const float* ab2 = (const float*)d_in[32];
    const float* aw3 = (const float*)d_in[33]; const float* ab3 = (const float*)d_in[34];
    const float* aw4 = (const float*)d_in[35]; const float* ab4 = (const float*)d_in[36];
    float* out = (float*)d_out;

    char* ws = (char*)d_ws;
    size_t off = 0;
    auto alloc = [&](size_t bytes) -> char* {
        char* p = ws + off;
        off = (off + bytes + 255) & ~(size_t)255;
        return p;
    };
    unsigned short* wih_p = (unsigned short*)alloc(36864*2);
    unsigned short* whh_p = (unsigned short*)alloc(110592*2);
    unsigned short* wih_d = (unsigned short*)alloc(12288*2);
    unsigned short* whh_d = (unsigned short*)alloc(12288*2);
    unsigned short* mw_p  = (unsigned short*)alloc(110592*2);
    unsigned short* mw_d  = (unsigned short*)alloc(12288*2);
    unsigned short* w0p   = (unsigned short*)alloc((size_t)1024*320*2);
    unsigned short* w1p   = (unsigned short*)alloc((size_t)512*1024*2);
    unsigned short* w2p   = (unsigned short*)alloc((size_t)256*512*2);
    unsigned short* w3p   = (unsigned short*)alloc((size_t)128*256*2);
    unsigned short* w4p   = (unsigned short*)alloc((size_t)16*128*2);
    unsigned short* hpb   = (unsigned short*)alloc((size_t)2048*192*2);
    unsigned short* hdb   = (unsigned short*)alloc((size_t)2048*64*2);
    float* Gp             = (float*)alloc((size_t)2048*576*4);
    float* Gd             = (float*)alloc((size_t)2048*192*4);
    unsigned short* x0b   = (unsigned short*)alloc((size_t)2048*320*2);
    unsigned short* a1b   = (unsigned short*)alloc((size_t)2048*1024*2);
    unsigned short* a2b   = (unsigned short*)alloc((size_t)2048*512*2);
    unsigned short* a3b   = (unsigned short*)alloc((size_t)2048*256*2);
    unsigned short* a4b   = (unsigned short*)alloc((size_t)2048*128*2);

    // --- one fused pack launch (11 jobs) ---
    PJobs P;
    P.j[0]  = { gp_wih, wih_p, 187, 192, 64, 64, 36864 };
    P.j[1]  = { gp_whh, whh_p, 187, 192, 187, 192, 110592 };
    P.j[2]  = { gd_wih, wih_d, 64, 64, 64, 64, 12288 };
    P.j[3]  = { gd_whh, whh_d, 64, 64, 64, 64, 12288 };
    P.j[4]  = { mp_wih, mw_p, 187, 192, 187, 192, 110592 };
    P.j[5]  = { md_wih, mw_d, 64, 64, 64, 64, 12288 };
    P.j[6]  = { aw0, w0p, 1024, 1024, 299, 320, 327680 };
    P.j[7]  = { aw1, w1p, 512, 512, 1024, 1024, 524288 };
    P.j[8]  = { aw2, w2p, 256, 256, 512, 512, 131072 };
    P.j[9]  = { aw3, w3p, 128, 128, 256, 256, 32768 };
    P.j[10] = { aw4, w4p, 12, 16, 128, 128, 2048 };
    pack_all<<<dim3(2048, 11), 256, 0, stream>>>(P);

    // --- fused encoder + GRU recurrence (128 prox + 128 dist blocks) ---
    gru_kernel<<<256, 768, 0, stream>>>(
        obs, prox_idx, dist_idx,
        pe_prox_w1, pe_prox_b1, pe_prox_w2, pe_prox_b2,
        pe_dist_w1, pe_dist_b1, pe_dist_w2, pe_dist_b2,
        wih_p, whh_p, wih_d, whh_d,
        gp_bih, gp_bhh, gd_bih, gd_bhh, hpb, hdb);

    // --- mem GRUs: G = h @ W^T (MFMA), then fused gates+concat -> bf16 x0 ---
    bgemm_kernel<<<dim3(9, 32), 256, 0, stream>>>(hpb, mw_p, nullptr, Gp, 192, 576, 576, 0);
    bgemm_kernel<<<dim3(3, 32), 256, 0, stream>>>(hdb, mw_d, nullptr, Gd, 64, 192, 192, 0);
    memcat_kernel<<<2560, 256, 0, stream>>>(obs, Gp, Gd, mp_bih, mp_bhh, md_bih, md_bhh, x0b);

    // --- actor MLP (bf16 MFMA chain) ---
    bgemm_kernel<<<dim3(16, 32), 256, 0, stream>>>(x0b, w0p, ab0, a1b, 320, 1024, 1024, 1);
    bgemm_kernel<<<dim3(8,  32), 256, 0, stream>>>(a1b, w1p, ab1, a2b, 1024, 512, 512, 1);
    bgemm_kernel<<<dim3(4,  32), 256, 0, stream>>>(a2b, w2p, ab2, a3b, 512, 256, 256, 1);
    bgemm_kernel<<<dim3(2,  32), 256, 0, stream>>>(a3b, w3p, ab3, a4b, 256, 128, 128, 1);
    bgemm_kernel<<<dim3(1,  32), 256, 0, stream>>>(a4b, w4p, ab4, out, 128, 16, 12, 0);
}

// Round 7
// 851.019 us; speedup vs baseline: 2.0432x; 1.0197x over previous
//
#include <hip/hip_runtime.h>
#include <stdint.h>

typedef __attribute__((ext_vector_type(8))) short short8;
typedef __attribute__((ext_vector_type(4))) float f32x4;
typedef __attribute__((ext_vector_type(4))) unsigned int u32x4;

#define DEV __device__ __forceinline__

#define L2E 1.4426950408889634f

DEV unsigned short f2bf(float f) {
    union { float f; uint32_t u; } v; v.f = f;
    return (unsigned short)((v.u + 0x7FFFu + ((v.u >> 16) & 1u)) >> 16);
}
// f32 -> OCP e4m3fn, RNE on normals, RN on subnormals
DEV uint8_t f2fp8(float f) {
    union { float f; uint32_t u; } v; v.f = f;
    uint32_t s = (v.u >> 24) & 0x80u;
    uint32_t absu = v.u & 0x7FFFFFFFu;
    int E = (int)(absu >> 23);
    if (E >= 135 + 1) return (uint8_t)(s | 0x7E);       // >= 512 -> clamp 448
    if (E >= 121) {                                      // normal fp8
        uint32_t m = absu & 0x7FFFFFu;
        uint32_t keep = m >> 20;
        uint32_t rest = m & 0xFFFFFu;
        uint32_t rnd = (rest > 0x80000u || (rest == 0x80000u && (keep & 1u))) ? 1u : 0u;
        uint32_t mag = (((uint32_t)(E - 120) << 3) | keep) + rnd;
        if (mag > 0x7Eu) mag = 0x7Eu;
        return (uint8_t)(s | mag);
    }
    float sc = __builtin_fabsf(f) * 512.f;               // subnormal: m * 2^-9
    uint32_t m8 = (uint32_t)(sc + 0.5f);
    if (m8 > 7u) return (uint8_t)(s | 0x08);
    return (uint8_t)(s | m8);
}
DEV float sig_(float x) {
    return __builtin_amdgcn_rcpf(1.f + __builtin_amdgcn_exp2f(-L2E * x));
}
DEV float tanh_(float x) {
    return 1.f - 2.f * __builtin_amdgcn_rcpf(1.f + __builtin_amdgcn_exp2f(2.f * L2E * x));
}
DEV float elu_(float x) {
    return x > 0.f ? x : __builtin_amdgcn_exp2f(L2E * x) - 1.f;
}
DEV f32x4 splat4(float v) { f32x4 r; r[0]=v; r[1]=v; r[2]=v; r[3]=v; return r; }
DEV void pin(short8& v) { asm volatile("" : "+v"(v)); }
DEV void pinl(long& v)  { asm volatile("" : "+v"(v)); }

// ---------------------------------------------------------------------------
// Fused weight pack: fp32 -> bf16, MFMA B-operand layout [NG rows pad][Kd pad].
// ---------------------------------------------------------------------------
struct PJob { const float* s; unsigned short* d; int Hs, NG, Ks, Kd, total; };
struct PJobs { PJob j[12]; };

__global__ __launch_bounds__(256) void pack_all(PJobs P)
{
    PJob jb = P.j[blockIdx.y];
    int e = blockIdx.x * 256 + threadIdx.x;
    if (e >= jb.total) return;
    int n = e / jb.Kd, k = e - n * jb.Kd;
    int g = n / jb.NG, jj = n - g * jb.NG;
    float v = (jj < jb.Hs && k < jb.Ks) ? jb.s[(size_t)(g * jb.Hs + jj) * jb.Ks + k] : 0.f;
    jb.d[e] = f2bf(v);
}

// fp32 -> fp8 pack for prox wih: [3*192 rows][64 k]
__global__ __launch_bounds__(256) void pack_fp8(const float* __restrict__ src,
                                                uint8_t* __restrict__ dst)
{
    int e = blockIdx.x * 256 + threadIdx.x;
    if (e >= 576 * 64) return;
    int n = e >> 6, k = e & 63;
    int g = n / 192, jj = n - g * 192;
    float v = (jj < 187) ? src[(size_t)(g * 187 + jj) * 64 + k] : 0.f;
    dst[e] = f2fp8(v);
}

// ---------------------------------------------------------------------------
// Standalone prox encoder: grid (2048, 8), 256 thr. Block: batch b, 64 steps.
// l1 VALU -> bf16 LDS; l2 via MFMA (wave = row tile, loop 4 col tiles);
// output fp8 e4m3 [2048][512][64].
// ---------------------------------------------------------------------------
__global__ __launch_bounds__(256) void enc_kernel(
    const float* __restrict__ obs, const int* __restrict__ idx,
    const float* __restrict__ w1, const float* __restrict__ b1,
    const unsigned short* __restrict__ w2p, const float* __restrict__ b2,
    uint8_t* __restrict__ enc8)
{
    const int b = blockIdx.x, t0 = blockIdx.y * 64;
    const int tid = threadIdx.x;
    __shared__ __align__(16) float pts[64][4];
    __shared__ float w1s[256];
    __shared__ float b1s[64], b2s[64];
    __shared__ __align__(16) unsigned short h1s[64][72];

    if (tid < 192) w1s[(tid/3)*4 + (tid - (tid/3)*3)] = w1[tid];
    if (tid < 64) { b1s[tid] = b1[tid]; b2s[tid] = b2[tid]; }
    for (int e = tid; e < 192; e += 256) {
        int p = e / 3, c2 = e - p * 3;
        int pi = idx[t0 + p];
        pts[p][c2] = obs[(size_t)b * 3120 + 48 + (size_t)pi * 3 + c2];
    }
    __syncthreads();
#pragma unroll
    for (int r = 0; r < 16; ++r) {
        int e = tid + r * 256;
        int p = e >> 6, ch = e & 63;
        float v = w1s[ch*4]*pts[p][0] + w1s[ch*4+1]*pts[p][1]
                + w1s[ch*4+2]*pts[p][2] + b1s[ch];
        h1s[p][ch] = f2bf(elu_(v));
    }
    __syncthreads();
    const int wave = tid >> 6, lane = tid & 63, quad = lane >> 4, l16 = lane & 15;
#pragma unroll
    for (int ct = 0; ct < 4; ++ct) {
        f32x4 a2 = splat4(0.f);
#pragma unroll
        for (int ks = 0; ks < 2; ++ks) {
            short8 af = *(const short8*)(&h1s[wave*16 + l16][ks*32 + quad*8]);
            short8 bf = *(const short8*)(w2p + (ct*16 + l16)*64 + ks*32 + quad*8);
            a2 = __builtin_amdgcn_mfma_f32_16x16x32_bf16(af, bf, a2, 0, 0, 0);
        }
        int c = ct*16 + l16;
        float b2v = b2s[c];
#pragma unroll
        for (int j = 0; j < 4; ++j) {
            int m = wave*16 + quad*4 + j;
            enc8[((size_t)b*512 + t0 + m)*64 + c] = f2fp8(elu_(a2[j] + b2v));
        }
    }
}

// ---------------------------------------------------------------------------
// PROX GRU body, precomputed-enc variant. One block = 16 rows, 12 waves, 512
// steps, ONE barrier/iter. Wave w owns gate-col tile w: whh bf16 frags (72
// VGPR) + wih fp8 frags (12 VGPR) pinned on-chip. Per iter: wave0 stages
// x-tile (fp8, 1 KB) LDS double-buffer + prefetches t+2; all waves do gx
// (fp8 MFMA) + gh (bf16 MFMA) + gates. LDS: hlds [2][16][200] bf16 @0
// (12800 B); xs [2][16][80] fp8 @12800 (2560 B).
// ---------------------------------------------------------------------------
DEV void gru_body_pre(int blk, const uint8_t* __restrict__ enc8,
                      const uint8_t* __restrict__ wih8,
                      const unsigned short* __restrict__ whh,
                      const float* __restrict__ bih, const float* __restrict__ bhh,
                      unsigned short* __restrict__ houtb, char* smem)
{
    constexpr int H = 187, KP = 192, KS = 6, HP8 = 200;
    unsigned short* hlds = (unsigned short*)smem;
    uint8_t* xs = (uint8_t*)(smem + 12800);

    const int tid  = threadIdx.x;
    const int wave = tid >> 6, lane = tid & 63, quad = lane >> 4, l16 = lane & 15;
    const int b0   = blk * 16;
    const int c    = wave * 16 + l16;

    for (int e = tid; e < 2*16*HP8; e += 768) hlds[e] = 0;

    // pinned weight fragments
    short8 whr[3][KS];
    long   wx8[3][2];
#pragma unroll
    for (int g = 0; g < 3; ++g) {
#pragma unroll
        for (int ks = 0; ks < KS; ++ks)
            whr[g][ks] = *(const short8*)(whh + ((size_t)(g*KP + c))*KP + ks*32 + quad*8);
#pragma unroll
        for (int ks = 0; ks < 2; ++ks)
            wx8[g][ks] = *(const long*)(wih8 + ((size_t)(g*KP + c))*64 + ks*32 + quad*8);
    }
#pragma unroll
    for (int g = 0; g < 3; ++g) {
#pragma unroll
        for (int ks = 0; ks < KS; ++ks) pin(whr[g][ks]);
#pragma unroll
        for (int ks = 0; ks < 2; ++ks)  pinl(wx8[g][ks]);
    }
    float bsr = 0.f, bsz = 0.f, binx = 0.f, bhnn = 0.f;
    if (c < H) {
        bsr  = bih[c]       + bhh[c];
        bsz  = bih[H + c]   + bhh[H + c];
        binx = bih[2*H + c];
        bhnn = bhh[2*H + c];
    }
    float hreg[4] = {0.f, 0.f, 0.f, 0.f};

    // x prologue (wave 0): stage x(0), prefetch x(1)
    u32x4 xq;
    const int xrow = lane >> 2, xseg = lane & 3;
    if (wave == 0) {
        xq = *(const u32x4*)(enc8 + ((size_t)(b0 + xrow)*512 + 0)*64 + xseg*16);
        *(u32x4*)(xs + 0*1280 + xrow*80 + xseg*16) = xq;
        xq = *(const u32x4*)(enc8 + ((size_t)(b0 + xrow)*512 + 1)*64 + xseg*16);
    }
    __syncthreads();

    int cur = 0;
    for (int t = 0; t < 512; ++t) {
        // stage x(t+1) -> LDS; prefetch x(t+2)
        if (wave == 0) {
            *(u32x4*)(xs + ((t+1)&1)*1280 + xrow*80 + xseg*16) = xq;
            int tn = (t + 2 < 512) ? t + 2 : 511;
            xq = *(const u32x4*)(enc8 + ((size_t)(b0 + xrow)*512 + tn)*64 + xseg*16);
        }
        const uint8_t* xsr = xs + (t&1)*1280;
        const unsigned short* hc = hlds + cur * (16*HP8);
        unsigned short*       hn = hlds + (cur ^ 1) * (16*HP8);

        f32x4 acc[4];                          // r, z, nx, nh
        acc[0] = splat4(bsr);
        acc[1] = splat4(bsz);
        acc[2] = splat4(binx);
        acc[3] = splat4(bhnn);
        // gx = x @ wih^T (fp8, K=64)
#pragma unroll
        for (int ks = 0; ks < 2; ++ks) {
            long a8 = *(const long*)(xsr + l16*80 + ks*32 + quad*8);
            acc[0] = __builtin_amdgcn_mfma_f32_16x16x32_fp8_fp8(a8, wx8[0][ks], acc[0], 0, 0, 0);
            acc[1] = __builtin_amdgcn_mfma_f32_16x16x32_fp8_fp8(a8, wx8[1][ks], acc[1], 0, 0, 0);
            acc[2] = __builtin_amdgcn_mfma_f32_16x16x32_fp8_fp8(a8, wx8[2][ks], acc[2], 0, 0, 0);
        }
        // gh = h @ whh^T (bf16, K=192)
#pragma unroll
        for (int ks = 0; ks < KS; ++ks) {
            short8 ah = *(const short8*)(hc + l16*HP8 + ks*32 + quad*8);
            acc[0] = __builtin_amdgcn_mfma_f32_16x16x32_bf16(ah, whr[0][ks], acc[0], 0, 0, 0);
            acc[1] = __builtin_amdgcn_mfma_f32_16x16x32_bf16(ah, whr[1][ks], acc[1], 0, 0, 0);
            acc[3] = __builtin_amdgcn_mfma_f32_16x16x32_bf16(ah, whr[2][ks], acc[3], 0, 0, 0);
        }
        // gates + h update
#pragma unroll
        for (int j = 0; j < 4; ++j) {
            int m = quad*4 + j;
            float r  = sig_(acc[0][j]);
            float zg = sig_(acc[1][j]);
            float nn = tanh_(acc[2][j] + r * acc[3][j]);
            float hv = nn + zg * (hreg[j] - nn);
            hreg[j] = hv;
            hn[m*HP8 + c] = f2bf(hv);
        }
        cur ^= 1;
        __syncthreads();
    }
#pragma unroll
    for (int j = 0; j < 4; ++j) {
        int m = quad*4 + j;
        houtb[(size_t)(b0 + m)*KP + c] = (c < H) ? f2bf(hreg[j]) : 0;
    }
}

// ---------------------------------------------------------------------------
// Fused encoder + GRU body (round-6 structure) — used for dist, and as the
// prox fallback when ws is too small for the precomputed-enc path.
// ---------------------------------------------------------------------------
template<int H, int KP>
DEV void gru_body_fused(int blk,
                  const float* __restrict__ obs, const int* __restrict__ idx,
                  const float* __restrict__ w1, const float* __restrict__ b1,
                  const float* __restrict__ w2, const float* __restrict__ b2,
                  const unsigned short* __restrict__ wih, const unsigned short* __restrict__ whh,
                  const float* __restrict__ bih, const float* __restrict__ bhh,
                  unsigned short* __restrict__ houtb, char* smem)
{
    constexpr int NCT = KP / 16;
    constexpr int KS  = KP / 32;
    constexpr int HP8 = KP + 8;

    unsigned short* hlds = (unsigned short*)(smem);
    unsigned short* xs   = (unsigned short*)(smem + 12800);
    unsigned short* h1s  = (unsigned short*)(smem + 17408);
    unsigned short* w2s  = (unsigned short*)(smem + 22016);
    float* ptsb          = (float*)(smem + 31232);
    float* w1s           = (float*)(smem + 31744);
    float* b1s           = (float*)(smem + 32768);
    float* b2s           = (float*)(smem + 33024);

    const int tid  = threadIdx.x;
    const int wave = tid >> 6, lane = tid & 63, quad = lane >> 4, l16 = lane & 15;
    const int b0   = blk * 16;
    const int ct   = wave;
    const bool act = (ct < NCT);
    const int c    = ct * 16 + l16;

    for (int e = tid; e < 2*16*HP8; e += 768) hlds[e] = 0;
    for (int e = tid; e < 4096; e += 768) { int n = e >> 6, k = e & 63; w2s[n*72 + k] = f2bf(w2[e]); }
    if (tid < 192) w1s[(tid/3)*4 + (tid - (tid/3)*3)] = w1[tid];
    if (tid < 64) { b1s[tid] = b1[tid]; b2s[tid] = b2[tid]; }

    const float* myrow = obs + (size_t)(b0 + (tid & 15)) * 3120 + 48;
    float px = 0.f, py = 0.f, pz = 0.f;
    if (tid < 16) {
        int p0 = idx[0];
        ptsb[tid*4 + 0] = myrow[3*p0 + 0];
        ptsb[tid*4 + 1] = myrow[3*p0 + 1];
        ptsb[tid*4 + 2] = myrow[3*p0 + 2];
        int p1 = idx[1];
        px = myrow[3*p1 + 0]; py = myrow[3*p1 + 1]; pz = myrow[3*p1 + 2];
    }

    short8 whr[3][KS];
    short8 wxr[3][2];
    float bsr = 0.f, bsz = 0.f, binx = 0.f, bhnn = 0.f;
    {
        const int cl = act ? c : l16;
#pragma unroll
        for (int g = 0; g < 3; ++g) {
#pragma unroll
            for (int ks = 0; ks < KS; ++ks)
                whr[g][ks] = *(const short8*)(whh + ((size_t)(g*KP + cl))*KP + ks*32 + quad*8);
#pragma unroll
            for (int ks = 0; ks < 2; ++ks)
                wxr[g][ks] = *(const short8*)(wih + ((size_t)(g*KP + cl))*64 + ks*32 + quad*8);
        }
    }
#pragma unroll
    for (int g = 0; g < 3; ++g) {
#pragma unroll
        for (int ks = 0; ks < KS; ++ks) pin(whr[g][ks]);
#pragma unroll
        for (int ks = 0; ks < 2; ++ks)  pin(wxr[g][ks]);
    }
    if (act && c < H) {
        bsr  = bih[c]       + bhh[c];
        bsz  = bih[H + c]   + bhh[H + c];
        binx = bih[2*H + c];
        bhnn = bhh[2*H + c];
    }
    float hreg[4] = {0.f, 0.f, 0.f, 0.f};

    __syncthreads();

    int cur = 0;
    for (int i = 0; i < 514; ++i) {
        if (i < 512) {
            const float* pt = ptsb + (i & 1) * 64;
            unsigned short* h1w = h1s + (i & 1) * (16*72);
#pragma unroll
            for (int e = tid; e < 1024; e += 768) {
                int p = e >> 6, ch = e & 63;
                float v = w1s[ch*4+0]*pt[p*4+0] + w1s[ch*4+1]*pt[p*4+1]
                        + w1s[ch*4+2]*pt[p*4+2] + b1s[ch];
                h1w[p*72 + ch] = f2bf(elu_(v));
            }
            if (tid < 16) {
                float* dst = ptsb + ((i+1) & 1) * 64 + tid*4;
                dst[0] = px; dst[1] = py; dst[2] = pz;
                int tn = (i + 2 < 512) ? i + 2 : 511;
                int pn = idx[tn];
                px = myrow[3*pn + 0]; py = myrow[3*pn + 1]; pz = myrow[3*pn + 2];
            }
        }
        if (i >= 1 && i < 513 && wave < 4) {
            const unsigned short* h1r = h1s + ((i-1) & 1) * (16*72);
            unsigned short*       xw  = xs  + ((i-1) & 1) * (16*72);
            f32x4 a2 = splat4(0.f);
#pragma unroll
            for (int ks = 0; ks < 2; ++ks) {
                short8 af = *(const short8*)(h1r + l16*72 + ks*32 + quad*8);
                short8 bf = *(const short8*)(w2s + (wave*16 + l16)*72 + ks*32 + quad*8);
                a2 = __builtin_amdgcn_mfma_f32_16x16x32_bf16(af, bf, a2, 0, 0, 0);
            }
            int c2 = wave*16 + l16;
            float b2v = b2s[c2];
#pragma unroll
            for (int j = 0; j < 4; ++j)
                xw[(quad*4 + j)*72 + c2] = f2bf(elu_(a2[j] + b2v));
        }
        if (i >= 2) {
            int t = i - 2;
            const unsigned short* xsr = xs + (t & 1) * (16*72);
            const unsigned short* hc  = hlds + cur * (16*HP8);
            unsigned short*       hn  = hlds + (cur ^ 1) * (16*HP8);
            if (act) {
                f32x4 acc[4];
                acc[0] = splat4(bsr);
                acc[1] = splat4(bsz);
                acc[2] = splat4(binx);
                acc[3] = splat4(bhnn);
#pragma unroll
                for (int ks = 0; ks < 2; ++ks) {
                    short8 xf = *(const short8*)(xsr + l16*72 + ks*32 + quad*8);
                    acc[0] = __builtin_amdgcn_mfma_f32_16x16x32_bf16(xf, wxr[0][ks], acc[0], 0, 0, 0);
                    acc[1] = __builtin_amdgcn_mfma_f32_16x16x32_bf16(xf, wxr[1][ks], acc[1], 0, 0, 0);
                    acc[2] = __builtin_amdgcn_mfma_f32_16x16x32_bf16(xf, wxr[2][ks], acc[2], 0, 0, 0);
                }
#pragma unroll
                for (int ks = 0; ks < KS; ++ks) {
                    short8 ah = *(const short8*)(hc + l16*HP8 + ks*32 + quad*8);
                    acc[0] = __builtin_amdgcn_mfma_f32_16x16x32_bf16(ah, whr[0][ks], acc[0], 0, 0, 0);
                    acc[1] = __builtin_amdgcn_mfma_f32_16x16x32_bf16(ah, whr[1][ks], acc[1], 0, 0, 0);
                    acc[3] = __builtin_amdgcn_mfma_f32_16x16x32_bf16(ah, whr[2][ks], acc[3], 0, 0, 0);
                }
#pragma unroll
                for (int j = 0; j < 4; ++j) {
                    int m = quad*4 + j;
                    float r  = sig_(acc[0][j]);
                    float zg = sig_(acc[1][j]);
                    float nn = tanh_(acc[2][j] + r * acc[3][j]);
                    float hv = nn + zg * (hreg[j] - nn);
                    hreg[j] = hv;
                    hn[m*HP8 + c] = f2bf(hv);
                }
            }
            cur ^= 1;
        }
        __syncthreads();
    }

    if (act)
#pragma unroll
        for (int j = 0; j < 4; ++j) {
            int m = quad*4 + j;
            houtb[(size_t)(b0 + m)*KP + c] = (c < H) ? f2bf(hreg[j]) : 0;
        }
}

__global__ __launch_bounds__(768) void gru_kernel(
    int mode,
    const float* __restrict__ obs,
    const int* __restrict__ prox_idx, const int* __restrict__ dist_idx,
    const uint8_t* __restrict__ encp8, const uint8_t* __restrict__ wihp8,
    const float* __restrict__ w1p, const float* __restrict__ b1p,
    const float* __restrict__ w2p, const float* __restrict__ b2p,
    const float* __restrict__ w1d, const float* __restrict__ b1d,
    const float* __restrict__ w2d, const float* __restrict__ b2d,
    const unsigned short* __restrict__ wihp, const unsigned short* __restrict__ whhp,
    const unsigned short* __restrict__ wihd, const unsigned short* __restrict__ whhd,
    const float* __restrict__ bihp, const float* __restrict__ bhhp,
    const float* __restrict__ bihd, const float* __restrict__ bhhd,
    unsigned short* __restrict__ hpb, unsigned short* __restrict__ hdb)
{
    __shared__ __align__(16) char smem[33280];
    if (blockIdx.x < 128) {
        if (mode == 0)
            gru_body_pre(blockIdx.x, encp8, wihp8, whhp, bihp, bhhp, hpb, smem);
        else
            gru_body_fused<187, 192>(blockIdx.x, obs, prox_idx, w1p, b1p, w2p, b2p,
                                     wihp, whhp, bihp, bhhp, hpb, smem);
    } else {
        gru_body_fused<64, 64>(blockIdx.x - 128, obs, dist_idx, w1d, b1d, w2d, b2d,
                               wihd, whhd, bihd, bhhd, hdb, smem);
    }
}

// ---------------------------------------------------------------------------
// bf16 MFMA GEMM: C[m][n] = act(A[m][:] . B[n][:] + bias[n])
// ---------------------------------------------------------------------------
__global__ __launch_bounds__(256) void bgemm_kernel(
    const unsigned short* __restrict__ A, const unsigned short* __restrict__ B,
    const float* __restrict__ bias, void* __restrict__ C,
    int Kp, int Np, int Nstore, int mode)
{
    __shared__ __align__(16) unsigned short Asl[64*40];
    __shared__ __align__(16) unsigned short Bsl[64*40];
    const int tid = threadIdx.x;
    const int wave = tid >> 6, lane = tid & 63, quad = lane >> 4, l16 = lane & 15;
    const int n0 = blockIdx.x * 64, m0 = blockIdx.y * 64;
    const int r = tid >> 2, sg = (tid & 3) * 8;

    f32x4 acc[4];
#pragma unroll
    for (int nt = 0; nt < 4; ++nt) acc[nt] = splat4(0.f);

    for (int k0 = 0; k0 < Kp; k0 += 32) {
        short8 av = *(const short8*)(A + (size_t)(m0 + r)*Kp + k0 + sg);
        short8 bv;
        if (n0 + r < Np) bv = *(const short8*)(B + (size_t)(n0 + r)*Kp + k0 + sg);
        else { short8 z; for (int q = 0; q < 8; ++q) z[q] = 0; bv = z; }
        *(short8*)(Asl + r*40 + sg) = av;
        *(short8*)(Bsl + r*40 + sg) = bv;
        __syncthreads();
        short8 af = *(const short8*)(Asl + (wave*16 + l16)*40 + quad*8);
#pragma unroll
        for (int nt = 0; nt < 4; ++nt) {
            short8 bf = *(const short8*)(Bsl + (nt*16 + l16)*40 + quad*8);
            acc[nt] = __builtin_amdgcn_mfma_f32_16x16x32_bf16(af, bf, acc[nt], 0, 0, 0);
        }
        __syncthreads();
    }
#pragma unroll
    for (int nt = 0; nt < 4; ++nt) {
        int n = n0 + nt*16 + l16;
        float bv = (bias && n < Np) ? bias[n] : 0.f;
#pragma unroll
        for (int j = 0; j < 4; ++j) {
            int m = m0 + wave*16 + quad*4 + j;
            float v = acc[nt][j] + bv;
            if (mode == 1) {
                ((unsigned short*)C)[(size_t)m*Np + n] = f2bf(elu_(v));
            } else {
                if (n < Nstore) ((float*)C)[(size_t)m*Nstore + n] = v;
            }
        }
    }
}

// ---------------------------------------------------------------------------
// Fused mem-GRU gates (T=1, h0=0 => f=(1-z)*n) + concat -> bf16 x0 [2048][320]
// ---------------------------------------------------------------------------
__global__ __launch_bounds__(256) void memcat_kernel(
    const float* __restrict__ obs, const float* __restrict__ Gp, const float* __restrict__ Gd,
    const float* __restrict__ mbip, const float* __restrict__ mbhp,
    const float* __restrict__ mbid, const float* __restrict__ mbhd,
    unsigned short* __restrict__ x0b)
{
    int i = blockIdx.x * 256 + threadIdx.x;
    if (i >= 2048 * 320) return;
    int b = i / 320, cc = i - b * 320;
    float v;
    if (cc < 48) {
        v = obs[(size_t)b*3120 + cc];
    } else if (cc < 235) {
        int j = cc - 48;
        float dr = Gp[(size_t)b*576 + j];
        float dz = Gp[(size_t)b*576 + 192 + j];
        float dn = Gp[(size_t)b*576 + 384 + j];
        float r  = sig_(dr + mbip[j] + mbhp[j]);
        float zg = sig_(dz + mbip[187+j] + mbhp[187+j]);
        float nn = tanh_(dn + mbip[374+j] + r * mbhp[374+j]);
        v = (1.f - zg) * nn;
    } else if (cc < 299) {
        int j = cc - 235;
        float dr = Gd[(size_t)b*192 + j];
        float dz = Gd[(size_t)b*192 + 64 + j];
        float dn = Gd[(size_t)b*192 + 128 + j];
        float r  = sig_(dr + mbid[j] + mbhd[j]);
        float zg = sig_(dz + mbid[64+j] + mbhd[64+j]);
        float nn = tanh_(dn + mbid[128+j] + r * mbhd[128+j]);
        v = (1.f - zg) * nn;
    } else {
        v = 0.f;
    }
    x0b[i] = f2bf(v);
}

// ---------------------------------------------------------------------------
extern "C" void kernel_launch(void* const* d_in, const int* in_sizes, int n_in,
                              void* d_out, int out_size, void* d_ws, size_t ws_size,
                              hipStream_t stream)
{
    (void)in_sizes; (void)n_in; (void)out_size;
    const float* obs        = (const float*)d_in[0];
    const int*   prox_idx   = (const int*)d_in[1];
    const int*   dist_idx   = (const int*)d_in[2];
    const float* pe_prox_w1 = (const float*)d_in[3];
    const float* pe_prox_b1 = (const float*)d_in[4];
    const float* pe_prox_w2 = (const float*)d_in[5];
    const float* pe_prox_b2 = (const float*)d_in[6];
    const float* pe_dist_w1 = (const float*)d_in[7];
    const float* pe_dist_b1 = (const float*)d_in[8];
    const float* pe_dist_w2 = (const float*)d_in[9];
    const float* pe_dist_b2 = (const float*)d_in[10];
    const float* gp_wih = (const float*)d_in[11];
    const float* gp_whh = (const float*)d_in[12];
    const float* gp_bih = (const float*)d_in[13];
    const float* gp_bhh = (const float*)d_in[14];
    const float* gd_wih = (const float*)d_in[15];
    const float* gd_whh = (const float*)d_in[16];
    const float* gd_bih = (const float*)d_in[17];
    const float* gd_bhh = (const float*)d_in[18];
    const float* mp_wih = (const float*)d_in[19];
    const float* mp_bih = (const float*)d_in[21];
    const float* mp_bhh = (const float*)d_in[22];
    const float* md_wih = (const float*)d_in[23];
    const float* md_bih = (const float*)d_in[25];
    const float* md_bhh = (const float*)d_in[26];
    const float* aw0 = (const float*)d_in[27]; const float* ab0 = (const float*)d_in[28];
    const float* aw1 = (const float*)d_in[29]; const float* ab1 = (const float*)d_in[30];
    const float* aw2 = (const float*)d_in[31]; const float* ab2 = (const float*)d_in[32];
    const float* aw3 = (const float*)d_in[33]; const float* ab3 = (const float*)d_in[34];
    const float* aw4 = (const float*)d_in[35]; const float* ab4 = (const float*)d_in[36];
    float* out = (float*)d_out;

    char* ws = (char*)d_ws;
    size_t off = 0;
    auto alloc = [&](size_t bytes) -> char* {
        char* p = ws + off;
        off = (off + bytes + 255) & ~(size_t)255;
        return p;
    };
    unsigned short* wih_p = (unsigned short*)alloc(36864*2);
    unsigned short* whh_p = (unsigned short*)alloc(110592*2);
    unsigned short* wih_d = (unsigned short*)alloc(12288*2);
    unsigned short* whh_d = (unsigned short*)alloc(12288*2);
    unsigned short* mw_p  = (unsigned short*)alloc(110592*2);
    unsigned short* mw_d  = (unsigned short*)alloc(12288*2);
    unsigned short* w0p   = (unsigned short*)alloc((size_t)1024*320*2);
    unsigned short* w1p   = (unsigned short*)alloc((size_t)512*1024*2);
    unsigned short* w2p   = (unsigned short*)alloc((size_t)256*512*2);
    unsigned short* w3p   = (unsigned short*)alloc((size_t)128*256*2);
    unsigned short* w4p   = (unsigned short*)alloc((size_t)16*128*2);
    unsigned short* w2e   = (unsigned short*)alloc(4096*2);
    uint8_t* wih8         = (uint8_t*)alloc(576*64);
    unsigned short* hpb   = (unsigned short*)alloc((size_t)2048*192*2);
    unsigned short* hdb   = (unsigned short*)alloc((size_t)2048*64*2);
    float* Gp             = (float*)alloc((size_t)2048*576*4);
    float* Gd             = (float*)alloc((size_t)2048*192*4);
    unsigned short* x0b   = (unsigned short*)alloc((size_t)2048*320*2);
    unsigned short* a1b   = (unsigned short*)alloc((size_t)2048*1024*2);
    unsigned short* a2b   = (unsigned short*)alloc((size_t)2048*512*2);
    unsigned short* a3b   = (unsigned short*)alloc((size_t)2048*256*2);
    unsigned short* a4b   = (unsigned short*)alloc((size_t)2048*128*2);
    uint8_t* enc8         = (uint8_t*)alloc((size_t)2048*512*64);   // 67 MB, LAST
    const int mode = (off <= ws_size) ? 0 : 1;   // fall back if ws too small

    // --- weight packs (bf16, B-operand layouts) ---
    PJobs P;
    P.j[0]  = { gp_wih, wih_p, 187, 192, 64, 64, 36864 };
    P.j[1]  = { gp_whh, whh_p, 187, 192, 187, 192, 110592 };
    P.j[2]  = { gd_wih, wih_d, 64, 64, 64, 64, 12288 };
    P.j[3]  = { gd_whh, whh_d, 64, 64, 64, 64, 12288 };
    P.j[4]  = { mp_wih, mw_p, 187, 192, 187, 192, 110592 };
    P.j[5]  = { md_wih, mw_d, 64, 64, 64, 64, 12288 };
    P.j[6]  = { aw0, w0p, 1024, 1024, 299, 320, 327680 };
    P.j[7]  = { aw1, w1p, 512, 512, 1024, 1024, 524288 };
    P.j[8]  = { aw2, w2p, 256, 256, 512, 512, 131072 };
    P.j[9]  = { aw3, w3p, 128, 128, 256, 256, 32768 };
    P.j[10] = { aw4, w4p, 12, 16, 128, 128, 2048 };
    P.j[11] = { pe_prox_w2, w2e, 64, 64, 64, 64, 4096 };
    pack_all<<<dim3(2048, 12), 256, 0, stream>>>(P);

    if (mode == 0) {
        pack_fp8<<<144, 256, 0, stream>>>(gp_wih, wih8);
        // --- standalone prox encoder -> fp8 ---
        enc_kernel<<<dim3(2048, 8), 256, 0, stream>>>(
            obs, prox_idx, pe_prox_w1, pe_prox_b1, w2e, pe_prox_b2, enc8);
    }

    // --- GRU recurrences (128 prox + 128 dist blocks) ---
    gru_kernel<<<256, 768, 0, stream>>>(
        mode, obs, prox_idx, dist_idx, enc8, wih8,
        pe_prox_w1, pe_prox_b1, pe_prox_w2, pe_prox_b2,
        pe_dist_w1, pe_dist_b1, pe_dist_w2, pe_dist_b2,
        wih_p, whh_p, wih_d, whh_d,
        gp_bih, gp_bhh, gd_bih, gd_bhh, hpb, hdb);

    // --- mem GRUs: G = h @ W^T (MFMA), then fused gates+concat -> bf16 x0 ---
    bgemm_kernel<<<dim3(9, 32), 256, 0, stream>>>(hpb, mw_p, nullptr, Gp, 192, 576, 576, 0);
    bgemm_kernel<<<dim3(3, 32), 256, 0, stream>>>(hdb, mw_d, nullptr, Gd, 64, 192, 192, 0);
    memcat_kernel<<<2560, 256, 0, stream>>>(obs, Gp, Gd, mp_bih, mp_bhh, md_bih, md_bhh, x0b);

    // --- actor MLP (bf16 MFMA chain) ---
    bgemm_kernel<<<dim3(16, 32), 256, 0, stream>>>(x0b, w0p, ab0, a1b, 320, 1024, 1024, 1);
    bgemm_kernel<<<dim3(8,  32), 256, 0, stream>>>(a1b, w1p, ab1, a2b, 1024, 512, 512, 1);
    bgemm_kernel<<<dim3(4,  32), 256, 0, stream>>>(a2b, w2p, ab2, a3b, 512, 256, 256, 1);
    bgemm_kernel<<<dim3(2,  32), 256, 0, stream>>>(a3b, w3p, ab3, a4b, 256, 128, 128, 1);
    bgemm_kernel<<<dim3(1,  32), 256, 0, stream>>>(a4b, w4p, ab4, out, 128, 16, 12, 0);
}

// Round 8
// 811.029 us; speedup vs baseline: 2.1440x; 1.0493x over previous
//
#include <hip/hip_runtime.h>
#include <stdint.h>

typedef __attribute__((ext_vector_type(8))) short short8;
typedef __attribute__((ext_vector_type(4))) float f32x4;
typedef __attribute__((ext_vector_type(4))) unsigned int u32x4;

#define DEV __device__ __forceinline__

#define L2E 1.4426950408889634f

DEV unsigned short f2bf(float f) {
    union { float f; uint32_t u; } v; v.f = f;
    return (unsigned short)((v.u + 0x7FFFu + ((v.u >> 16) & 1u)) >> 16);
}
#if defined(__has_builtin)
#if __has_builtin(__builtin_amdgcn_cvt_pk_bf16_f32)
#define HAS_PK_BF16 1
#endif
#endif
// pack two f32 -> two bf16 (RNE) in one u32 (lo = a, hi = b)
DEV uint32_t pk_bf16(float a, float b) {
#ifdef HAS_PK_BF16
    typedef __attribute__((ext_vector_type(2))) __bf16 bf2;
    union { bf2 v; uint32_t u; } cv;
    cv.v = __builtin_amdgcn_cvt_pk_bf16_f32(a, b);
    return cv.u;
#else
    return (uint32_t)f2bf(a) | ((uint32_t)f2bf(b) << 16);
#endif
}
// f32 -> OCP e4m3fn, RNE on normals
DEV uint8_t f2fp8(float f) {
    union { float f; uint32_t u; } v; v.f = f;
    uint32_t s = (v.u >> 24) & 0x80u;
    uint32_t absu = v.u & 0x7FFFFFFFu;
    int E = (int)(absu >> 23);
    if (E >= 136) return (uint8_t)(s | 0x7E);
    if (E >= 121) {
        uint32_t m = absu & 0x7FFFFFu;
        uint32_t keep = m >> 20;
        uint32_t rest = m & 0xFFFFFu;
        uint32_t rnd = (rest > 0x80000u || (rest == 0x80000u && (keep & 1u))) ? 1u : 0u;
        uint32_t mag = (((uint32_t)(E - 120) << 3) | keep) + rnd;
        if (mag > 0x7Eu) mag = 0x7Eu;
        return (uint8_t)(s | mag);
    }
    float sc = __builtin_fabsf(f) * 512.f;
    uint32_t m8 = (uint32_t)(sc + 0.5f);
    if (m8 > 7u) return (uint8_t)(s | 0x08);
    return (uint8_t)(s | m8);
}
DEV float rcp1pe_(float x) {          // 1/(1+exp2(x))
    return __builtin_amdgcn_rcpf(1.f + __builtin_amdgcn_exp2f(x));
}
DEV float sig_(float x) { return rcp1pe_(-L2E * x); }
DEV float elu_(float x) {
    return x > 0.f ? x : __builtin_amdgcn_exp2f(L2E * x) - 1.f;
}
DEV f32x4 splat4(float v) { f32x4 r; r[0]=v; r[1]=v; r[2]=v; r[3]=v; return r; }
DEV void pin(short8& v) { asm volatile("" : "+v"(v)); }
DEV void pinl(long& v)  { asm volatile("" : "+v"(v)); }

// ---------------------------------------------------------------------------
// Fused weight pack: fp32 -> bf16/fp8, MFMA B-layout [3*NG rows][Kd], with
// per-gate scale (GRU prescale trick: r,z by -L2E; n by +2*L2E — folds the
// sigmoid/tanh argument scaling into the matmul).
// ---------------------------------------------------------------------------
struct PJob { const float* s; void* d; int Hs, NG, Ks, Kd, total; float s0, s1, s2; int fmt; };
struct PJobs { PJob j[13]; };

__global__ __launch_bounds__(256) void pack_all(PJobs P)
{
    PJob jb = P.j[blockIdx.y];
    int e = blockIdx.x * 256 + threadIdx.x;
    if (e >= jb.total) return;
    int n = e / jb.Kd, k = e - n * jb.Kd;
    int g = n / jb.NG, jj = n - g * jb.NG;
    float sc = (g == 0) ? jb.s0 : ((g == 1) ? jb.s1 : jb.s2);
    float v = (jj < jb.Hs && k < jb.Ks) ? jb.s[(size_t)(g * jb.Hs + jj) * jb.Ks + k] * sc : 0.f;
    if (jb.fmt) ((uint8_t*)jb.d)[e] = f2fp8(v);
    else        ((unsigned short*)jb.d)[e] = f2bf(v);
}

// ---------------------------------------------------------------------------
// Standalone prox encoder -> fp8 e4m3 [2048][512][64]
// ---------------------------------------------------------------------------
__global__ __launch_bounds__(256) void enc_kernel(
    const float* __restrict__ obs, const int* __restrict__ idx,
    const float* __restrict__ w1, const float* __restrict__ b1,
    const unsigned short* __restrict__ w2p, const float* __restrict__ b2,
    uint8_t* __restrict__ enc8)
{
    const int b = blockIdx.x, t0 = blockIdx.y * 64;
    const int tid = threadIdx.x;
    __shared__ __align__(16) float pts[64][4];
    __shared__ float w1s[256];
    __shared__ float b1s[64], b2s[64];
    __shared__ __align__(16) unsigned short h1s[64][72];

    if (tid < 192) w1s[(tid/3)*4 + (tid - (tid/3)*3)] = w1[tid];
    if (tid < 64) { b1s[tid] = b1[tid]; b2s[tid] = b2[tid]; }
    for (int e = tid; e < 192; e += 256) {
        int p = e / 3, c2 = e - p * 3;
        int pi = idx[t0 + p];
        pts[p][c2] = obs[(size_t)b * 3120 + 48 + (size_t)pi * 3 + c2];
    }
    __syncthreads();
#pragma unroll
    for (int r = 0; r < 16; ++r) {
        int e = tid + r * 256;
        int p = e >> 6, ch = e & 63;
        float v = w1s[ch*4]*pts[p][0] + w1s[ch*4+1]*pts[p][1]
                + w1s[ch*4+2]*pts[p][2] + b1s[ch];
        h1s[p][ch] = f2bf(elu_(v));
    }
    __syncthreads();
    const int wave = tid >> 6, lane = tid & 63, quad = lane >> 4, l16 = lane & 15;
#pragma unroll
    for (int ct = 0; ct < 4; ++ct) {
        f32x4 a2 = splat4(0.f);
#pragma unroll
        for (int ks = 0; ks < 2; ++ks) {
            short8 af = *(const short8*)(&h1s[wave*16 + l16][ks*32 + quad*8]);
            short8 bf = *(const short8*)(w2p + (ct*16 + l16)*64 + ks*32 + quad*8);
            a2 = __builtin_amdgcn_mfma_f32_16x16x32_bf16(af, bf, a2, 0, 0, 0);
        }
        int c = ct*16 + l16;
        float b2v = b2s[c];
#pragma unroll
        for (int j = 0; j < 4; ++j) {
            int m = wave*16 + quad*4 + j;
            enc8[((size_t)b*512 + t0 + m)*64 + c] = f2fp8(elu_(a2[j] + b2v));
        }
    }
}

// ---------------------------------------------------------------------------
// PROX GRU, precomputed-enc. Weights PRESCALED (r,z: -L2E; n: 2*L2E), so
// gates are: r=1/(1+exp2(acc0)), z=1/(1+exp2(acc1)),
// n=1-2/(1+exp2(acc2 + r*acc3)), h=n+z*(h_prev-n). No per-gate multiplies.
// ---------------------------------------------------------------------------
DEV void gru_body_pre(int blk, const uint8_t* __restrict__ enc8,
                      const uint8_t* __restrict__ wih8,
                      const unsigned short* __restrict__ whh,
                      const float* __restrict__ bih, const float* __restrict__ bhh,
                      unsigned short* __restrict__ houtb, char* smem)
{
    constexpr int H = 187, KP = 192, KS = 6, HP8 = 200;
    unsigned short* hlds = (unsigned short*)smem;
    uint8_t* xs = (uint8_t*)(smem + 12800);

    const int tid  = threadIdx.x;
    const int wave = tid >> 6, lane = tid & 63, quad = lane >> 4, l16 = lane & 15;
    const int b0   = blk * 16;
    const int c    = wave * 16 + l16;

    for (int e = tid; e < 2*16*HP8; e += 768) hlds[e] = 0;

    short8 whr[3][KS];
    long   wx8[3][2];
#pragma unroll
    for (int g = 0; g < 3; ++g) {
#pragma unroll
        for (int ks = 0; ks < KS; ++ks)
            whr[g][ks] = *(const short8*)(whh + ((size_t)(g*KP + c))*KP + ks*32 + quad*8);
#pragma unroll
        for (int ks = 0; ks < 2; ++ks)
            wx8[g][ks] = *(const long*)(wih8 + ((size_t)(g*KP + c))*64 + ks*32 + quad*8);
    }
#pragma unroll
    for (int g = 0; g < 3; ++g) {
#pragma unroll
        for (int ks = 0; ks < KS; ++ks) pin(whr[g][ks]);
#pragma unroll
        for (int ks = 0; ks < 2; ++ks)  pinl(wx8[g][ks]);
    }
    float bsr = 0.f, bsz = 0.f, binx = 0.f, bhnn = 0.f;
    if (c < H) {
        bsr  = -L2E * (bih[c]       + bhh[c]);
        bsz  = -L2E * (bih[H + c]   + bhh[H + c]);
        binx = 2.f * L2E * bih[2*H + c];
        bhnn = 2.f * L2E * bhh[2*H + c];
    }
    float hreg[4] = {0.f, 0.f, 0.f, 0.f};

    u32x4 xq;
    const int xrow = lane >> 2, xseg = lane & 3;
    if (wave == 0) {
        xq = *(const u32x4*)(enc8 + ((size_t)(b0 + xrow)*512 + 0)*64 + xseg*16);
        *(u32x4*)(xs + 0*1280 + xrow*80 + xseg*16) = xq;
        xq = *(const u32x4*)(enc8 + ((size_t)(b0 + xrow)*512 + 1)*64 + xseg*16);
    }
    __syncthreads();

    int cur = 0;
    for (int t = 0; t < 512; ++t) {
        if (wave == 0) {
            *(u32x4*)(xs + ((t+1)&1)*1280 + xrow*80 + xseg*16) = xq;
            int tn = (t + 2 < 512) ? t + 2 : 511;
            xq = *(const u32x4*)(enc8 + ((size_t)(b0 + xrow)*512 + tn)*64 + xseg*16);
        }
        const uint8_t* xsr = xs + (t&1)*1280;
        const unsigned short* hc = hlds + cur * (16*HP8);
        unsigned short*       hn = hlds + (cur ^ 1) * (16*HP8);

        f32x4 acc[4];                          // r, z, nx, nh
        acc[0] = splat4(bsr);
        acc[1] = splat4(bsz);
        acc[2] = splat4(binx);
        acc[3] = splat4(bhnn);
#pragma unroll
        for (int ks = 0; ks < 2; ++ks) {
            long a8 = *(const long*)(xsr + l16*80 + ks*32 + quad*8);
            acc[0] = __builtin_amdgcn_mfma_f32_16x16x32_fp8_fp8(a8, wx8[0][ks], acc[0], 0, 0, 0);
            acc[1] = __builtin_amdgcn_mfma_f32_16x16x32_fp8_fp8(a8, wx8[1][ks], acc[1], 0, 0, 0);
            acc[2] = __builtin_amdgcn_mfma_f32_16x16x32_fp8_fp8(a8, wx8[2][ks], acc[2], 0, 0, 0);
        }
#pragma unroll
        for (int ks = 0; ks < KS; ++ks) {
            short8 ah = *(const short8*)(hc + l16*HP8 + ks*32 + quad*8);
            acc[0] = __builtin_amdgcn_mfma_f32_16x16x32_bf16(ah, whr[0][ks], acc[0], 0, 0, 0);
            acc[1] = __builtin_amdgcn_mfma_f32_16x16x32_bf16(ah, whr[1][ks], acc[1], 0, 0, 0);
            acc[3] = __builtin_amdgcn_mfma_f32_16x16x32_bf16(ah, whr[2][ks], acc[3], 0, 0, 0);
        }
        float hv[4];
#pragma unroll
        for (int j = 0; j < 4; ++j) {
            float r  = rcp1pe_(acc[0][j]);
            float zg = rcp1pe_(acc[1][j]);
            float nn = __builtin_fmaf(-2.f, rcp1pe_(__builtin_fmaf(r, acc[3][j], acc[2][j])), 1.f);
            hv[j] = __builtin_fmaf(zg, hreg[j] - nn, nn);
            hreg[j] = hv[j];
        }
        uint32_t p01 = pk_bf16(hv[0], hv[1]);
        uint32_t p23 = pk_bf16(hv[2], hv[3]);
        hn[(quad*4+0)*HP8 + c] = (unsigned short)p01;
        hn[(quad*4+1)*HP8 + c] = (unsigned short)(p01 >> 16);
        hn[(quad*4+2)*HP8 + c] = (unsigned short)p23;
        hn[(quad*4+3)*HP8 + c] = (unsigned short)(p23 >> 16);
        cur ^= 1;
        __syncthreads();
    }
#pragma unroll
    for (int j = 0; j < 4; ++j) {
        int m = quad*4 + j;
        houtb[(size_t)(b0 + m)*KP + c] = (c < H) ? f2bf(hreg[j]) : 0;
    }
}

// ---------------------------------------------------------------------------
// Fused encoder + GRU body — dist, and prox fallback. Same prescaled gates.
// ---------------------------------------------------------------------------
template<int H, int KP>
DEV void gru_body_fused(int blk,
                  const float* __restrict__ obs, const int* __restrict__ idx,
                  const float* __restrict__ w1, const float* __restrict__ b1,
                  const float* __restrict__ w2, const float* __restrict__ b2,
                  const unsigned short* __restrict__ wih, const unsigned short* __restrict__ whh,
                  const float* __restrict__ bih, const float* __restrict__ bhh,
                  unsigned short* __restrict__ houtb, char* smem)
{
    constexpr int NCT = KP / 16;
    constexpr int KS  = KP / 32;
    constexpr int HP8 = KP + 8;

    unsigned short* hlds = (unsigned short*)(smem);
    unsigned short* xs   = (unsigned short*)(smem + 12800);
    unsigned short* h1s  = (unsigned short*)(smem + 17408);
    unsigned short* w2s  = (unsigned short*)(smem + 22016);
    float* ptsb          = (float*)(smem + 31232);
    float* w1s           = (float*)(smem + 31744);
    float* b1s           = (float*)(smem + 32768);
    float* b2s           = (float*)(smem + 33024);

    const int tid  = threadIdx.x;
    const int wave = tid >> 6, lane = tid & 63, quad = lane >> 4, l16 = lane & 15;
    const int b0   = blk * 16;
    const int ct   = wave;
    const bool act = (ct < NCT);
    const int c    = ct * 16 + l16;

    for (int e = tid; e < 2*16*HP8; e += 768) hlds[e] = 0;
    for (int e = tid; e < 4096; e += 768) { int n = e >> 6, k = e & 63; w2s[n*72 + k] = f2bf(w2[e]); }
    if (tid < 192) w1s[(tid/3)*4 + (tid - (tid/3)*3)] = w1[tid];
    if (tid < 64) { b1s[tid] = b1[tid]; b2s[tid] = b2[tid]; }

    const float* myrow = obs + (size_t)(b0 + (tid & 15)) * 3120 + 48;
    float px = 0.f, py = 0.f, pz = 0.f;
    if (tid < 16) {
        int p0 = idx[0];
        ptsb[tid*4 + 0] = myrow[3*p0 + 0];
        ptsb[tid*4 + 1] = myrow[3*p0 + 1];
        ptsb[tid*4 + 2] = myrow[3*p0 + 2];
        int p1 = idx[1];
        px = myrow[3*p1 + 0]; py = myrow[3*p1 + 1]; pz = myrow[3*p1 + 2];
    }

    short8 whr[3][KS];
    short8 wxr[3][2];
    float bsr = 0.f, bsz = 0.f, binx = 0.f, bhnn = 0.f;
    {
        const int cl = act ? c : l16;
#pragma unroll
        for (int g = 0; g < 3; ++g) {
#pragma unroll
            for (int ks = 0; ks < KS; ++ks)
                whr[g][ks] = *(const short8*)(whh + ((size_t)(g*KP + cl))*KP + ks*32 + quad*8);
#pragma unroll
            for (int ks = 0; ks < 2; ++ks)
                wxr[g][ks] = *(const short8*)(wih + ((size_t)(g*KP + cl))*64 + ks*32 + quad*8);
        }
    }
#pragma unroll
    for (int g = 0; g < 3; ++g) {
#pragma unroll
        for (int ks = 0; ks < KS; ++ks) pin(whr[g][ks]);
#pragma unroll
        for (int ks = 0; ks < 2; ++ks)  pin(wxr[g][ks]);
    }
    if (act && c < H) {
        bsr  = -L2E * (bih[c]       + bhh[c]);
        bsz  = -L2E * (bih[H + c]   + bhh[H + c]);
        binx = 2.f * L2E * bih[2*H + c];
        bhnn = 2.f * L2E * bhh[2*H + c];
    }
    float hreg[4] = {0.f, 0.f, 0.f, 0.f};

    __syncthreads();

    int cur = 0;
    for (int i = 0; i < 514; ++i) {
        if (i < 512) {
            const float* pt = ptsb + (i & 1) * 64;
            unsigned short* h1w = h1s + (i & 1) * (16*72);
#pragma unroll
            for (int e = tid; e < 1024; e += 768) {
                int p = e >> 6, ch = e & 63;
                float v = w1s[ch*4+0]*pt[p*4+0] + w1s[ch*4+1]*pt[p*4+1]
                        + w1s[ch*4+2]*pt[p*4+2] + b1s[ch];
                h1w[p*72 + ch] = f2bf(elu_(v));
            }
            if (tid < 16) {
                float* dst = ptsb + ((i+1) & 1) * 64 + tid*4;
                dst[0] = px; dst[1] = py; dst[2] = pz;
                int tn = (i + 2 < 512) ? i + 2 : 511;
                int pn = idx[tn];
                px = myrow[3*pn + 0]; py = myrow[3*pn + 1]; pz = myrow[3*pn + 2];
            }
        }
        if (i >= 1 && i < 513 && wave < 4) {
            const unsigned short* h1r = h1s + ((i-1) & 1) * (16*72);
            unsigned short*       xw  = xs  + ((i-1) & 1) * (16*72);
            f32x4 a2 = splat4(0.f);
#pragma unroll
            for (int ks = 0; ks < 2; ++ks) {
                short8 af = *(const short8*)(h1r + l16*72 + ks*32 + quad*8);
                short8 bf = *(const short8*)(w2s + (wave*16 + l16)*72 + ks*32 + quad*8);
                a2 = __builtin_amdgcn_mfma_f32_16x16x32_bf16(af, bf, a2, 0, 0, 0);
            }
            int c2 = wave*16 + l16;
            float b2v = b2s[c2];
#pragma unroll
            for (int j = 0; j < 4; ++j)
                xw[(quad*4 + j)*72 + c2] = f2bf(elu_(a2[j] + b2v));
        }
        if (i >= 2) {
            int t = i - 2;
            const unsigned short* xsr = xs + (t & 1) * (16*72);
            const unsigned short* hc  = hlds + cur * (16*HP8);
            unsigned short*       hn  = hlds + (cur ^ 1) * (16*HP8);
            if (act) {
                f32x4 acc[4];
                acc[0] = splat4(bsr);
                acc[1] = splat4(bsz);
                acc[2] = splat4(binx);
                acc[3] = splat4(bhnn);
#pragma unroll
                for (int ks = 0; ks < 2; ++ks) {
                    short8 xf = *(const short8*)(xsr + l16*72 + ks*32 + quad*8);
                    acc[0] = __builtin_amdgcn_mfma_f32_16x16x32_bf16(xf, wxr[0][ks], acc[0], 0, 0, 0);
                    acc[1] = __builtin_amdgcn_mfma_f32_16x16x32_bf16(xf, wxr[1][ks], acc[1], 0, 0, 0);
                    acc[2] = __builtin_amdgcn_mfma_f32_16x16x32_bf16(xf, wxr[2][ks], acc[2], 0, 0, 0);
                }
#pragma unroll
                for (int ks = 0; ks < KS; ++ks) {
                    short8 ah = *(const short8*)(hc + l16*HP8 + ks*32 + quad*8);
                    acc[0] = __builtin_amdgcn_mfma_f32_16x16x32_bf16(ah, whr[0][ks], acc[0], 0, 0, 0);
                    acc[1] = __builtin_amdgcn_mfma_f32_16x16x32_bf16(ah, whr[1][ks], acc[1], 0, 0, 0);
                    acc[3] = __builtin_amdgcn_mfma_f32_16x16x32_bf16(ah, whr[2][ks], acc[3], 0, 0, 0);
                }
                float hv[4];
#pragma unroll
                for (int j = 0; j < 4; ++j) {
                    float r  = rcp1pe_(acc[0][j]);
                    float zg = rcp1pe_(acc[1][j]);
                    float nn = __builtin_fmaf(-2.f, rcp1pe_(__builtin_fmaf(r, acc[3][j], acc[2][j])), 1.f);
                    hv[j] = __builtin_fmaf(zg, hreg[j] - nn, nn);
                    hreg[j] = hv[j];
                }
                uint32_t p01 = pk_bf16(hv[0], hv[1]);
                uint32_t p23 = pk_bf16(hv[2], hv[3]);
                hn[(quad*4+0)*HP8 + c] = (unsigned short)p01;
                hn[(quad*4+1)*HP8 + c] = (unsigned short)(p01 >> 16);
                hn[(quad*4+2)*HP8 + c] = (unsigned short)p23;
                hn[(quad*4+3)*HP8 + c] = (unsigned short)(p23 >> 16);
            }
            cur ^= 1;
        }
        __syncthreads();
    }

    if (act)
#pragma unroll
        for (int j = 0; j < 4; ++j) {
            int m = quad*4 + j;
            houtb[(size_t)(b0 + m)*KP + c] = (c < H) ? f2bf(hreg[j]) : 0;
        }
}

__global__ __launch_bounds__(768) void gru_kernel(
    int mode,
    const float* __restrict__ obs,
    const int* __restrict__ prox_idx, const int* __restrict__ dist_idx,
    const uint8_t* __restrict__ encp8, const uint8_t* __restrict__ wihp8,
    const float* __restrict__ w1p, const float* __restrict__ b1p,
    const float* __restrict__ w2p, const float* __restrict__ b2p,
    const float* __restrict__ w1d, const float* __restrict__ b1d,
    const float* __restrict__ w2d, const float* __restrict__ b2d,
    const unsigned short* __restrict__ wihp, const unsigned short* __restrict__ whhp,
    const unsigned short* __restrict__ wihd, const unsigned short* __restrict__ whhd,
    const float* __restrict__ bihp, const float* __restrict__ bhhp,
    const float* __restrict__ bihd, const float* __restrict__ bhhd,
    unsigned short* __restrict__ hpb, unsigned short* __restrict__ hdb)
{
    __shared__ __align__(16) char smem[33280];
    if (blockIdx.x < 128) {
        if (mode == 0)
            gru_body_pre(blockIdx.x, encp8, wihp8, whhp, bihp, bhhp, hpb, smem);
        else
            gru_body_fused<187, 192>(blockIdx.x, obs, prox_idx, w1p, b1p, w2p, b2p,
                                     wihp, whhp, bihp, bhhp, hpb, smem);
    } else {
        gru_body_fused<64, 64>(blockIdx.x - 128, obs, dist_idx, w1d, b1d, w2d, b2d,
                               wihd, whhd, bihd, bhhd, hdb, smem);
    }
}

// ---------------------------------------------------------------------------
// Fused mem-GRU (T=1, h0=0 -> f=(1-z)*n) + concat -> bf16 x0 [2048][320].
// grid (4, 32): z=0..2 prox j-tiles (64 cols each), z=3 dist. Block computes
// all 3 gate GEMM slices for its 64 j-cols x 64 rows, applies gates, writes
// x0 slice. z==0 also copies proprio; z==3 also zero-fills cols 299..319.
// mem weights are PRESCALED like the GRU weights.
// ---------------------------------------------------------------------------
__global__ __launch_bounds__(256) void memfuse_kernel(
    const float* __restrict__ obs,
    const unsigned short* __restrict__ hpb, const unsigned short* __restrict__ hdb,
    const unsigned short* __restrict__ mwp, const unsigned short* __restrict__ mwd,
    const float* __restrict__ mbip, const float* __restrict__ mbhp,
    const float* __restrict__ mbid, const float* __restrict__ mbhd,
    unsigned short* __restrict__ x0b)
{
    __shared__ __align__(16) unsigned short Asl[64*40];
    __shared__ __align__(16) unsigned short Bsl[3][64*40];
    const int tid = threadIdx.x;
    const int wave = tid >> 6, lane = tid & 63, quad = lane >> 4, l16 = lane & 15;
    const int z = blockIdx.x, m0 = blockIdx.y * 64;
    const bool isp = (z < 3);
    const unsigned short* A = isp ? hpb : hdb;
    const unsigned short* B = isp ? mwp : mwd;
    const float* bi = isp ? mbip : mbid;
    const float* bh = isp ? mbhp : mbhd;
    const int Kp = isp ? 192 : 64;
    const int Hh = isp ? 187 : 64;
    const int jb = isp ? z * 64 : 0;
    const int cbase = isp ? 48 : 235;
    const int r = tid >> 2, sg = (tid & 3) * 8;

    f32x4 acc[3][4];
#pragma unroll
    for (int g = 0; g < 3; ++g)
#pragma unroll
        for (int nt = 0; nt < 4; ++nt) acc[g][nt] = splat4(0.f);

    for (int k0 = 0; k0 < Kp; k0 += 32) {
        *(short8*)(Asl + r*40 + sg) = *(const short8*)(A + (size_t)(m0 + r)*Kp + k0 + sg);
#pragma unroll
        for (int g = 0; g < 3; ++g)
            *(short8*)(Bsl[g] + r*40 + sg) =
                *(const short8*)(B + (size_t)(g*Kp + jb + r)*Kp + k0 + sg);
        __syncthreads();
        short8 af = *(const short8*)(Asl + (wave*16 + l16)*40 + quad*8);
#pragma unroll
        for (int g = 0; g < 3; ++g)
#pragma unroll
            for (int nt = 0; nt < 4; ++nt) {
                short8 bf = *(const short8*)(Bsl[g] + (nt*16 + l16)*40 + quad*8);
                acc[g][nt] = __builtin_amdgcn_mfma_f32_16x16x32_bf16(af, bf, acc[g][nt], 0, 0, 0);
            }
        __syncthreads();
    }
#pragma unroll
    for (int nt = 0; nt < 4; ++nt) {
        int j = jb + nt*16 + l16;
        bool valid = (j < Hh);
        float br = 0.f, bz = 0.f, bnx = 0.f, bnh = 0.f;
        if (valid) {
            br  = -L2E * (bi[j] + bh[j]);
            bz  = -L2E * (bi[Hh + j] + bh[Hh + j]);
            bnx = 2.f * L2E * bi[2*Hh + j];
            bnh = 2.f * L2E * bh[2*Hh + j];
        }
#pragma unroll
        for (int jj = 0; jj < 4; ++jj) {
            int m = m0 + wave*16 + quad*4 + jj;
            float rr = rcp1pe_(acc[0][nt][jj] + br);
            float zz = rcp1pe_(acc[1][nt][jj] + bz);
            float tt = __builtin_fmaf(rr, bnh, acc[2][nt][jj] + bnx);
            float nn = __builtin_fmaf(-2.f, rcp1pe_(tt), 1.f);
            float v  = (1.f - zz) * nn;
            if (valid) x0b[(size_t)m*320 + cbase + j] = f2bf(v);
        }
    }
    if (z == 0) {
        for (int e = tid; e < 64*48; e += 256) {
            int m = m0 + e / 48, cc = e - (e / 48) * 48;
            x0b[(size_t)m*320 + cc] = f2bf(obs[(size_t)m*3120 + cc]);
        }
    }
    if (z == 3) {
        for (int e = tid; e < 64*21; e += 256) {
            int m = m0 + e / 21, cc = 299 + (e - (e / 21) * 21);
            x0b[(size_t)m*320 + cc] = 0;
        }
    }
}

// ---------------------------------------------------------------------------
// bf16 MFMA GEMM: C[m][n] = act(A[m][:] . B[n][:] + bias[n])
// ---------------------------------------------------------------------------
__global__ __launch_bounds__(256) void bgemm_kernel(
    const unsigned short* __restrict__ A, const unsigned short* __restrict__ B,
    const float* __restrict__ bias, void* __restrict__ C,
    int Kp, int Np, int Nstore, int mode)
{
    __shared__ __align__(16) unsigned short Asl[64*40];
    __shared__ __align__(16) unsigned short Bsl[64*40];
    const int tid = threadIdx.x;
    const int wave = tid >> 6, lane = tid & 63, quad = lane >> 4, l16 = lane & 15;
    const int n0 = blockIdx.x * 64, m0 = blockIdx.y * 64;
    const int r = tid >> 2, sg = (tid & 3) * 8;

    f32x4 acc[4];
#pragma unroll
    for (int nt = 0; nt < 4; ++nt) acc[nt] = splat4(0.f);

    for (int k0 = 0; k0 < Kp; k0 += 32) {
        short8 av = *(const short8*)(A + (size_t)(m0 + r)*Kp + k0 + sg);
        short8 bv;
        if (n0 + r < Np) bv = *(const short8*)(B + (size_t)(n0 + r)*Kp + k0 + sg);
        else { short8 zz; for (int q = 0; q < 8; ++q) zz[q] = 0; bv = zz; }
        *(short8*)(Asl + r*40 + sg) = av;
        *(short8*)(Bsl + r*40 + sg) = bv;
        __syncthreads();
        short8 af = *(const short8*)(Asl + (wave*16 + l16)*40 + quad*8);
#pragma unroll
        for (int nt = 0; nt < 4; ++nt) {
            short8 bf = *(const short8*)(Bsl + (nt*16 + l16)*40 + quad*8);
            acc[nt] = __builtin_amdgcn_mfma_f32_16x16x32_bf16(af, bf, acc[nt], 0, 0, 0);
        }
        __syncthreads();
    }
#pragma unroll
    for (int nt = 0; nt < 4; ++nt) {
        int n = n0 + nt*16 + l16;
        float bv = (bias && n < Np) ? bias[n] : 0.f;
#pragma unroll
        for (int j = 0; j < 4; ++j) {
            int m = m0 + wave*16 + quad*4 + j;
            float v = acc[nt][j] + bv;
            if (mode == 1) {
                ((unsigned short*)C)[(size_t)m*Np + n] = f2bf(elu_(v));
            } else {
                if (n < Nstore) ((float*)C)[(size_t)m*Nstore + n] = v;
            }
        }
    }
}

// ---------------------------------------------------------------------------
extern "C" void kernel_launch(void* const* d_in, const int* in_sizes, int n_in,
                              void* d_out, int out_size, void* d_ws, size_t ws_size,
                              hipStream_t stream)
{
    (void)in_sizes; (void)n_in; (void)out_size;
    const float* obs        = (const float*)d_in[0];
    const int*   prox_idx   = (const int*)d_in[1];
    const int*   dist_idx   = (const int*)d_in[2];
    const float* pe_prox_w1 = (const float*)d_in[3];
    const float* pe_prox_b1 = (const float*)d_in[4];
    const float* pe_prox_w2 = (const float*)d_in[5];
    const float* pe_prox_b2 = (const float*)d_in[6];
    const float* pe_dist_w1 = (const float*)d_in[7];
    const float* pe_dist_b1 = (const float*)d_in[8];
    const float* pe_dist_w2 = (const float*)d_in[9];
    const float* pe_dist_b2 = (const float*)d_in[10];
    const float* gp_wih = (const float*)d_in[11];
    const float* gp_whh = (const float*)d_in[12];
    const float* gp_bih = (const float*)d_in[13];
    const float* gp_bhh = (const float*)d_in[14];
    const float* gd_wih = (const float*)d_in[15];
    const float* gd_whh = (const float*)d_in[16];
    const float* gd_bih = (const float*)d_in[17];
    const float* gd_bhh = (const float*)d_in[18];
    const float* mp_wih = (const float*)d_in[19];
    const float* mp_bih = (const float*)d_in[21];
    const float* mp_bhh = (const float*)d_in[22];
    const float* md_wih = (const float*)d_in[23];
    const float* md_bih = (const float*)d_in[25];
    const float* md_bhh = (const float*)d_in[26];
    const float* aw0 = (const float*)d_in[27]; const float* ab0 = (const float*)d_in[28];
    const float* aw1 = (const float*)d_in[29]; const float* ab1 = (const float*)d_in[30];
    const float* aw2 = (const float*)d_in[31]; const float* ab2 = (const float*)d_in[32];
    const float* aw3 = (const float*)d_in[33]; const float* ab3 = (const float*)d_in[34];
    const float* aw4 = (const float*)d_in[35]; const float* ab4 = (const float*)d_in[36];
    float* out = (float*)d_out;

    char* ws = (char*)d_ws;
    size_t off = 0;
    auto alloc = [&](size_t bytes) -> char* {
        char* p = ws + off;
        off = (off + bytes + 255) & ~(size_t)255;
        return p;
    };
    unsigned short* wih_p = (unsigned short*)alloc(36864*2);
    unsigned short* whh_p = (unsigned short*)alloc(110592*2);
    unsigned short* wih_d = (unsigned short*)alloc(12288*2);
    unsigned short* whh_d = (unsigned short*)alloc(12288*2);
    unsigned short* mw_p  = (unsigned short*)alloc(110592*2);
    unsigned short* mw_d  = (unsigned short*)alloc(12288*2);
    unsigned short* w0p   = (unsigned short*)alloc((size_t)1024*320*2);
    unsigned short* w1p   = (unsigned short*)alloc((size_t)512*1024*2);
    unsigned short* w2p   = (unsigned short*)alloc((size_t)256*512*2);
    unsigned short* w3p   = (unsigned short*)alloc((size_t)128*256*2);
    unsigned short* w4p   = (unsigned short*)alloc((size_t)16*128*2);
    unsigned short* w2e   = (unsigned short*)alloc(4096*2);
    uint8_t* wih8         = (uint8_t*)alloc(576*64);
    unsigned short* hpb   = (unsigned short*)alloc((size_t)2048*192*2);
    unsigned short* hdb   = (unsigned short*)alloc((size_t)2048*64*2);
    unsigned short* x0b   = (unsigned short*)alloc((size_t)2048*320*2);
    unsigned short* a1b   = (unsigned short*)alloc((size_t)2048*1024*2);
    unsigned short* a2b   = (unsigned short*)alloc((size_t)2048*512*2);
    unsigned short* a3b   = (unsigned short*)alloc((size_t)2048*256*2);
    unsigned short* a4b   = (unsigned short*)alloc((size_t)2048*128*2);
    uint8_t* enc8         = (uint8_t*)alloc((size_t)2048*512*64);   // 67 MB, LAST
    const int mode = (off <= ws_size) ? 0 : 1;   // fall back if ws too small

    const float SR = -L2E, SN = 2.f * L2E;
    PJobs P;
    P.j[0]  = { gp_wih, wih_p, 187, 192, 64, 64, 36864, SR, SR, SN, 0 };
    P.j[1]  = { gp_whh, whh_p, 187, 192, 187, 192, 110592, SR, SR, SN, 0 };
    P.j[2]  = { gd_wih, wih_d, 64, 64, 64, 64, 12288, SR, SR, SN, 0 };
    P.j[3]  = { gd_whh, whh_d, 64, 64, 64, 64, 12288, SR, SR, SN, 0 };
    P.j[4]  = { mp_wih, mw_p, 187, 192, 187, 192, 110592, SR, SR, SN, 0 };
    P.j[5]  = { md_wih, mw_d, 64, 64, 64, 64, 12288, SR, SR, SN, 0 };
    P.j[6]  = { aw0, w0p, 1024, 1024, 299, 320, 327680, 1.f, 1.f, 1.f, 0 };
    P.j[7]  = { aw1, w1p, 512, 512, 1024, 1024, 524288, 1.f, 1.f, 1.f, 0 };
    P.j[8]  = { aw2, w2p, 256, 256, 512, 512, 131072, 1.f, 1.f, 1.f, 0 };
    P.j[9]  = { aw3, w3p, 128, 128, 256, 256, 32768, 1.f, 1.f, 1.f, 0 };
    P.j[10] = { aw4, w4p, 12, 16, 128, 128, 2048, 1.f, 1.f, 1.f, 0 };
    P.j[11] = { pe_prox_w2, w2e, 64, 64, 64, 64, 4096, 1.f, 1.f, 1.f, 0 };
    P.j[12] = { gp_wih, wih8, 187, 192, 64, 64, 36864, SR, SR, SN, 1 };
    pack_all<<<dim3(2048, 13), 256, 0, stream>>>(P);

    if (mode == 0) {
        enc_kernel<<<dim3(2048, 8), 256, 0, stream>>>(
            obs, prox_idx, pe_prox_w1, pe_prox_b1, w2e, pe_prox_b2, enc8);
    }

    gru_kernel<<<256, 768, 0, stream>>>(
        mode, obs, prox_idx, dist_idx, enc8, wih8,
        pe_prox_w1, pe_prox_b1, pe_prox_w2, pe_prox_b2,
        pe_dist_w1, pe_dist_b1, pe_dist_w2, pe_dist_b2,
        wih_p, whh_p, wih_d, whh_d,
        gp_bih, gp_bhh, gd_bih, gd_bhh, hpb, hdb);

    // --- fused mem-GRU gemm + gates + concat -> bf16 x0 ---
    memfuse_kernel<<<dim3(4, 32), 256, 0, stream>>>(
        obs, hpb, hdb, mw_p, mw_d, mp_bih, mp_bhh, md_bih, md_bhh, x0b);

    // --- actor MLP (bf16 MFMA chain) ---
    bgemm_kernel<<<dim3(16, 32), 256, 0, stream>>>(x0b, w0p, ab0, a1b, 320, 1024, 1024, 1);
    bgemm_kernel<<<dim3(8,  32), 256, 0, stream>>>(a1b, w1p, ab1, a2b, 1024, 512, 512, 1);
    bgemm_kernel<<<dim3(4,  32), 256, 0, stream>>>(a2b, w2p, ab2, a3b, 512, 256, 256, 1);
    bgemm_kernel<<<dim3(2,  32), 256, 0, stream>>>(a3b, w3p, ab3, a4b, 256, 128, 128, 1);
    bgemm_kernel<<<dim3(1,  32), 256, 0, stream>>>(a4b, w4p, ab4, out, 128, 16, 12, 0);
}

// Round 9
// 805.336 us; speedup vs baseline: 2.1591x; 1.0071x over previous
//
#include <hip/hip_runtime.h>
#include <stdint.h>

typedef __attribute__((ext_vector_type(8))) short short8;
typedef __attribute__((ext_vector_type(4))) float f32x4;
typedef __attribute__((ext_vector_type(4))) unsigned int u32x4;

#define DEV __device__ __forceinline__

#define L2E 1.4426950408889634f

DEV unsigned short f2bf(float f) {
    union { float f; uint32_t u; } v; v.f = f;
    return (unsigned short)((v.u + 0x7FFFu + ((v.u >> 16) & 1u)) >> 16);
}
#if defined(__has_builtin)
#if __has_builtin(__builtin_amdgcn_cvt_pk_bf16_f32)
#define HAS_PK_BF16 1
#endif
#if __has_builtin(__builtin_amdgcn_cvt_pk_fp8_f32)
#define HAS_PK_FP8 1
#endif
#endif
DEV uint32_t pk_bf16(float a, float b) {
#ifdef HAS_PK_BF16
    typedef __attribute__((ext_vector_type(2))) __bf16 bf2;
    union { bf2 v; uint32_t u; } cv;
    cv.v = __builtin_amdgcn_cvt_pk_bf16_f32(a, b);
    return cv.u;
#else
    return (uint32_t)f2bf(a) | ((uint32_t)f2bf(b) << 16);
#endif
}
// f32 -> OCP e4m3fn (manual fallback)
DEV uint8_t f2fp8(float f) {
    union { float f; uint32_t u; } v; v.f = f;
    uint32_t s = (v.u >> 24) & 0x80u;
    uint32_t absu = v.u & 0x7FFFFFFFu;
    int E = (int)(absu >> 23);
    if (E >= 136) return (uint8_t)(s | 0x7E);
    if (E >= 121) {
        uint32_t m = absu & 0x7FFFFFu;
        uint32_t keep = m >> 20;
        uint32_t rest = m & 0xFFFFFu;
        uint32_t rnd = (rest > 0x80000u || (rest == 0x80000u && (keep & 1u))) ? 1u : 0u;
        uint32_t mag = (((uint32_t)(E - 120) << 3) | keep) + rnd;
        if (mag > 0x7Eu) mag = 0x7Eu;
        return (uint8_t)(s | mag);
    }
    float sc = __builtin_fabsf(f) * 512.f;
    uint32_t m8 = (uint32_t)(sc + 0.5f);
    if (m8 > 7u) return (uint8_t)(s | 0x08);
    return (uint8_t)(s | m8);
}
// 4x f32 -> 4x fp8 packed in a dword (HW cvt when available)
DEV uint32_t pk_fp8x4(float a, float b, float c, float d) {
#ifdef HAS_PK_FP8
    int lo   = __builtin_amdgcn_cvt_pk_fp8_f32(a, b, 0, false);
    int both = __builtin_amdgcn_cvt_pk_fp8_f32(c, d, lo, true);
    return (uint32_t)both;
#else
    return (uint32_t)f2fp8(a) | ((uint32_t)f2fp8(b) << 8)
         | ((uint32_t)f2fp8(c) << 16) | ((uint32_t)f2fp8(d) << 24);
#endif
}
DEV float rcp1pe_(float x) {          // 1/(1+exp2(x))
    return __builtin_amdgcn_rcpf(1.f + __builtin_amdgcn_exp2f(x));
}
DEV float sig_(float x) { return rcp1pe_(-L2E * x); }
DEV float elu_(float x) {
    return x > 0.f ? x : __builtin_amdgcn_exp2f(L2E * x) - 1.f;
}
DEV f32x4 splat4(float v) { f32x4 r; r[0]=v; r[1]=v; r[2]=v; r[3]=v; return r; }
DEV void pin(short8& v) { asm volatile("" : "+v"(v)); }
DEV void pinl(long& v)  { asm volatile("" : "+v"(v)); }

// ---------------------------------------------------------------------------
// Fused weight pack: fp32 -> bf16/fp8, MFMA B-layout [3*NG rows][Kd], with
// per-gate scale (prescale trick: r,z by -L2E; n by +2*L2E).
// ---------------------------------------------------------------------------
struct PJob { const float* s; void* d; int Hs, NG, Ks, Kd, total; float s0, s1, s2; int fmt; };
struct PJobs { PJob j[13]; };

__global__ __launch_bounds__(256) void pack_all(PJobs P)
{
    PJob jb = P.j[blockIdx.y];
    int e = blockIdx.x * 256 + threadIdx.x;
    if (e >= jb.total) return;
    int n = e / jb.Kd, k = e - n * jb.Kd;
    int g = n / jb.NG, jj = n - g * jb.NG;
    float sc = (g == 0) ? jb.s0 : ((g == 1) ? jb.s1 : jb.s2);
    float v = (jj < jb.Hs && k < jb.Ks) ? jb.s[(size_t)(g * jb.Hs + jj) * jb.Ks + k] * sc : 0.f;
    if (jb.fmt) ((uint8_t*)jb.d)[e] = (uint8_t)(pk_fp8x4(v, 0.f, 0.f, 0.f) & 0xFFu);
    else        ((unsigned short*)jb.d)[e] = f2bf(v);
}

// ---------------------------------------------------------------------------
// Standalone prox encoder -> fp8 e4m3 [2048][512][64]. HW fp8 cvt + LDS-staged
// coalesced 16B global stores (was 16 scattered byte-stores per thread).
// ---------------------------------------------------------------------------
__global__ __launch_bounds__(256) void enc_kernel(
    const float* __restrict__ obs, const int* __restrict__ idx,
    const float* __restrict__ w1, const float* __restrict__ b1,
    const unsigned short* __restrict__ w2p, const float* __restrict__ b2,
    uint8_t* __restrict__ enc8)
{
    const int b = blockIdx.x, t0 = blockIdx.y * 64;
    const int tid = threadIdx.x;
    __shared__ __align__(16) float pts[64][4];
    __shared__ float w1s[256];
    __shared__ float b1s[64], b2s[64];
    __shared__ __align__(16) unsigned short h1s[64][72];
    __shared__ __align__(16) uint8_t x8s[64 * 80];

    if (tid < 192) w1s[(tid/3)*4 + (tid - (tid/3)*3)] = w1[tid];
    if (tid < 64) { b1s[tid] = b1[tid]; b2s[tid] = b2[tid]; }
    for (int e = tid; e < 192; e += 256) {
        int p = e / 3, c2 = e - p * 3;
        int pi = idx[t0 + p];
        pts[p][c2] = obs[(size_t)b * 3120 + 48 + (size_t)pi * 3 + c2];
    }
    __syncthreads();
#pragma unroll
    for (int r = 0; r < 16; ++r) {
        int e = tid + r * 256;
        int p = e >> 6, ch = e & 63;
        float v = w1s[ch*4]*pts[p][0] + w1s[ch*4+1]*pts[p][1]
                + w1s[ch*4+2]*pts[p][2] + b1s[ch];
        h1s[p][ch] = f2bf(elu_(v));
    }
    __syncthreads();
    const int wave = tid >> 6, lane = tid & 63, quad = lane >> 4, l16 = lane & 15;
#pragma unroll
    for (int ct = 0; ct < 4; ++ct) {
        f32x4 a2 = splat4(0.f);
#pragma unroll
        for (int ks = 0; ks < 2; ++ks) {
            short8 af = *(const short8*)(&h1s[wave*16 + l16][ks*32 + quad*8]);
            short8 bf = *(const short8*)(w2p + (ct*16 + l16)*64 + ks*32 + quad*8);
            a2 = __builtin_amdgcn_mfma_f32_16x16x32_bf16(af, bf, a2, 0, 0, 0);
        }
        int c = ct*16 + l16;
        float b2v = b2s[c];
        uint32_t pk = pk_fp8x4(elu_(a2[0] + b2v), elu_(a2[1] + b2v),
                               elu_(a2[2] + b2v), elu_(a2[3] + b2v));
#pragma unroll
        for (int j = 0; j < 4; ++j)
            x8s[(wave*16 + quad*4 + j)*80 + c] = (uint8_t)(pk >> (8*j));
    }
    __syncthreads();
    {   // coalesced store: 256 thr x 16 B = 64 rows x 64 B
        int row = tid >> 2, seg = tid & 3;
        *(u32x4*)(enc8 + ((size_t)b*512 + t0 + row)*64 + seg*16) =
            *(const u32x4*)(x8s + row*80 + seg*16);
    }
}

// ---------------------------------------------------------------------------
// PROX GRU, precomputed-enc, prescaled gates, XOR-swizzled h LDS layout.
// Swizzle: logical column-chunk cc of row m lives at phys chunk
// (cc&~3)|((cc&3)^((m>>2)&3)). Writer: (m>>2)&3 == quad. Reader (A-frag row
// l16): phys chunk = ks*4 + (quad ^ ((l16>>2)&3)). Kills the quad-{0,2}/{1,3}
// write bank aliasing (was ~520 conflict-cyc/block-iter); reads stay uniform.
// ---------------------------------------------------------------------------
DEV void gru_body_pre(int blk, const uint8_t* __restrict__ enc8,
                      const uint8_t* __restrict__ wih8,
                      const unsigned short* __restrict__ whh,
                      const float* __restrict__ bih, const float* __restrict__ bhh,
                      unsigned short* __restrict__ houtb, char* smem)
{
    constexpr int H = 187, KP = 192, KS = 6, HP8 = 200;
    unsigned short* hlds = (unsigned short*)smem;
    uint8_t* xs = (uint8_t*)(smem + 12800);

    const int tid  = threadIdx.x;
    const int wave = tid >> 6, lane = tid & 63, quad = lane >> 4, l16 = lane & 15;
    const int b0   = blk * 16;
    const int c    = wave * 16 + l16;

    // loop-invariant swizzled offsets
    const int sx = (l16 >> 2) & 3;
    const int qo = (quad ^ sx) * 8;                 // read chunk offset (shorts)
    const int cc = c >> 3, cl = c & 7;
    const int wcol = ((cc & ~3) | ((cc & 3) ^ quad)) * 8 + cl;   // write column

    for (int e = tid; e < 2*16*HP8; e += 768) hlds[e] = 0;

    short8 whr[3][KS];
    long   wx8[3][2];
#pragma unroll
    for (int g = 0; g < 3; ++g) {
#pragma unroll
        for (int ks = 0; ks < KS; ++ks)
            whr[g][ks] = *(const short8*)(whh + ((size_t)(g*KP + c))*KP + ks*32 + quad*8);
#pragma unroll
        for (int ks = 0; ks < 2; ++ks)
            wx8[g][ks] = *(const long*)(wih8 + ((size_t)(g*KP + c))*64 + ks*32 + quad*8);
    }
#pragma unroll
    for (int g = 0; g < 3; ++g) {
#pragma unroll
        for (int ks = 0; ks < KS; ++ks) pin(whr[g][ks]);
#pragma unroll
        for (int ks = 0; ks < 2; ++ks)  pinl(wx8[g][ks]);
    }
    float bsr = 0.f, bsz = 0.f, binx = 0.f, bhnn = 0.f;
    if (c < H) {
        bsr  = -L2E * (bih[c]       + bhh[c]);
        bsz  = -L2E * (bih[H + c]   + bhh[H + c]);
        binx = 2.f * L2E * bih[2*H + c];
        bhnn = 2.f * L2E * bhh[2*H + c];
    }
    float hreg[4] = {0.f, 0.f, 0.f, 0.f};

    u32x4 xq;
    const int xrow = lane >> 2, xseg = lane & 3;
    if (wave == 0) {
        xq = *(const u32x4*)(enc8 + ((size_t)(b0 + xrow)*512 + 0)*64 + xseg*16);
        *(u32x4*)(xs + 0*1280 + xrow*80 + xseg*16) = xq;
        xq = *(const u32x4*)(enc8 + ((size_t)(b0 + xrow)*512 + 1)*64 + xseg*16);
    }
    __syncthreads();

    int cur = 0;
    for (int t = 0; t < 512; ++t) {
        if (wave == 0) {
            *(u32x4*)(xs + ((t+1)&1)*1280 + xrow*80 + xseg*16) = xq;
            int tn = (t + 2 < 512) ? t + 2 : 511;
            xq = *(const u32x4*)(enc8 + ((size_t)(b0 + xrow)*512 + tn)*64 + xseg*16);
        }
        const uint8_t* xsr = xs + (t&1)*1280;
        const unsigned short* hc = hlds + cur * (16*HP8);
        unsigned short*       hn = hlds + (cur ^ 1) * (16*HP8);

        f32x4 acc[4];                          // r, z, nx, nh
        acc[0] = splat4(bsr);
        acc[1] = splat4(bsz);
        acc[2] = splat4(binx);
        acc[3] = splat4(bhnn);
#pragma unroll
        for (int ks = 0; ks < 2; ++ks) {
            long a8 = *(const long*)(xsr + l16*80 + ks*32 + quad*8);
            acc[0] = __builtin_amdgcn_mfma_f32_16x16x32_fp8_fp8(a8, wx8[0][ks], acc[0], 0, 0, 0);
            acc[1] = __builtin_amdgcn_mfma_f32_16x16x32_fp8_fp8(a8, wx8[1][ks], acc[1], 0, 0, 0);
            acc[2] = __builtin_amdgcn_mfma_f32_16x16x32_fp8_fp8(a8, wx8[2][ks], acc[2], 0, 0, 0);
        }
#pragma unroll
        for (int ks = 0; ks < KS; ++ks) {
            short8 ah = *(const short8*)(hc + l16*HP8 + ks*32 + qo);
            acc[0] = __builtin_amdgcn_mfma_f32_16x16x32_bf16(ah, whr[0][ks], acc[0], 0, 0, 0);
            acc[1] = __builtin_amdgcn_mfma_f32_16x16x32_bf16(ah, whr[1][ks], acc[1], 0, 0, 0);
            acc[3] = __builtin_amdgcn_mfma_f32_16x16x32_bf16(ah, whr[2][ks], acc[3], 0, 0, 0);
        }
        float hv[4];
#pragma unroll
        for (int j = 0; j < 4; ++j) {
            float r  = rcp1pe_(acc[0][j]);
            float zg = rcp1pe_(acc[1][j]);
            float nn = __builtin_fmaf(-2.f, rcp1pe_(__builtin_fmaf(r, acc[3][j], acc[2][j])), 1.f);
            hv[j] = __builtin_fmaf(zg, hreg[j] - nn, nn);
            hreg[j] = hv[j];
        }
        uint32_t p01 = pk_bf16(hv[0], hv[1]);
        uint32_t p23 = pk_bf16(hv[2], hv[3]);
        hn[(quad*4+0)*HP8 + wcol] = (unsigned short)p01;
        hn[(quad*4+1)*HP8 + wcol] = (unsigned short)(p01 >> 16);
        hn[(quad*4+2)*HP8 + wcol] = (unsigned short)p23;
        hn[(quad*4+3)*HP8 + wcol] = (unsigned short)(p23 >> 16);
        cur ^= 1;
        __syncthreads();
    }
#pragma unroll
    for (int j = 0; j < 4; ++j) {
        int m = quad*4 + j;
        houtb[(size_t)(b0 + m)*KP + c] = (c < H) ? f2bf(hreg[j]) : 0;
    }
}

// ---------------------------------------------------------------------------
// Fused encoder + GRU body — dist, and prox fallback. Prescaled gates.
// ---------------------------------------------------------------------------
template<int H, int KP>
DEV void gru_body_fused(int blk,
                  const float* __restrict__ obs, const int* __restrict__ idx,
                  const float* __restrict__ w1, const float* __restrict__ b1,
                  const float* __restrict__ w2, const float* __restrict__ b2,
                  const unsigned short* __restrict__ wih, const unsigned short* __restrict__ whh,
                  const float* __restrict__ bih, const float* __restrict__ bhh,
                  unsigned short* __restrict__ houtb, char* smem)
{
    constexpr int NCT = KP / 16;
    constexpr int KS  = KP / 32;
    constexpr int HP8 = KP + 8;

    unsigned short* hlds = (unsigned short*)(smem);
    unsigned short* xs   = (unsigned short*)(smem + 12800);
    unsigned short* h1s  = (unsigned short*)(smem + 17408);
    unsigned short* w2s  = (unsigned short*)(smem + 22016);
    float* ptsb          = (float*)(smem + 31232);
    float* w1s           = (float*)(smem + 31744);
    float* b1s           = (float*)(smem + 32768);
    float* b2s           = (float*)(smem + 33024);

    const int tid  = threadIdx.x;
    const int wave = tid >> 6, lane = tid & 63, quad = lane >> 4, l16 = lane & 15;
    const int b0   = blk * 16;
    const int ct   = wave;
    const bool act = (ct < NCT);
    const int c    = ct * 16 + l16;

    for (int e = tid; e < 2*16*HP8; e += 768) hlds[e] = 0;
    for (int e = tid; e < 4096; e += 768) { int n = e >> 6, k = e & 63; w2s[n*72 + k] = f2bf(w2[e]); }
    if (tid < 192) w1s[(tid/3)*4 + (tid - (tid/3)*3)] = w1[tid];
    if (tid < 64) { b1s[tid] = b1[tid]; b2s[tid] = b2[tid]; }

    const float* myrow = obs + (size_t)(b0 + (tid & 15)) * 3120 + 48;
    float px = 0.f, py = 0.f, pz = 0.f;
    if (tid < 16) {
        int p0 = idx[0];
        ptsb[tid*4 + 0] = myrow[3*p0 + 0];
        ptsb[tid*4 + 1] = myrow[3*p0 + 1];
        ptsb[tid*4 + 2] = myrow[3*p0 + 2];
        int p1 = idx[1];
        px = myrow[3*p1 + 0]; py = myrow[3*p1 + 1]; pz = myrow[3*p1 + 2];
    }

    short8 whr[3][KS];
    short8 wxr[3][2];
    float bsr = 0.f, bsz = 0.f, binx = 0.f, bhnn = 0.f;
    {
        const int cl = act ? c : l16;
#pragma unroll
        for (int g = 0; g < 3; ++g) {
#pragma unroll
            for (int ks = 0; ks < KS; ++ks)
                whr[g][ks] = *(const short8*)(whh + ((size_t)(g*KP + cl))*KP + ks*32 + quad*8);
#pragma unroll
            for (int ks = 0; ks < 2; ++ks)
                wxr[g][ks] = *(const short8*)(wih + ((size_t)(g*KP + cl))*64 + ks*32 + quad*8);
        }
    }
#pragma unroll
    for (int g = 0; g < 3; ++g) {
#pragma unroll
        for (int ks = 0; ks < KS; ++ks) pin(whr[g][ks]);
#pragma unroll
        for (int ks = 0; ks < 2; ++ks)  pin(wxr[g][ks]);
    }
    if (act && c < H) {
        bsr  = -L2E * (bih[c]       + bhh[c]);
        bsz  = -L2E * (bih[H + c]   + bhh[H + c]);
        binx = 2.f * L2E * bih[2*H + c];
        bhnn = 2.f * L2E * bhh[2*H + c];
    }
    float hreg[4] = {0.f, 0.f, 0.f, 0.f};

    __syncthreads();

    int cur = 0;
    for (int i = 0; i < 514; ++i) {
        if (i < 512) {
            const float* pt = ptsb + (i & 1) * 64;
            unsigned short* h1w = h1s + (i & 1) * (16*72);
#pragma unroll
            for (int e = tid; e < 1024; e += 768) {
                int p = e >> 6, ch = e & 63;
                float v = w1s[ch*4+0]*pt[p*4+0] + w1s[ch*4+1]*pt[p*4+1]
                        + w1s[ch*4+2]*pt[p*4+2] + b1s[ch];
                h1w[p*72 + ch] = f2bf(elu_(v));
            }
            if (tid < 16) {
                float* dst = ptsb + ((i+1) & 1) * 64 + tid*4;
                dst[0] = px; dst[1] = py; dst[2] = pz;
                int tn = (i + 2 < 512) ? i + 2 : 511;
                int pn = idx[tn];
                px = myrow[3*pn + 0]; py = myrow[3*pn + 1]; pz = myrow[3*pn + 2];
            }
        }
        if (i >= 1 && i < 513 && wave < 4) {
            const unsigned short* h1r = h1s + ((i-1) & 1) * (16*72);
            unsigned short*       xw  = xs  + ((i-1) & 1) * (16*72);
            f32x4 a2 = splat4(0.f);
#pragma unroll
            for (int ks = 0; ks < 2; ++ks) {
                short8 af = *(const short8*)(h1r + l16*72 + ks*32 + quad*8);
                short8 bf = *(const short8*)(w2s + (wave*16 + l16)*72 + ks*32 + quad*8);
                a2 = __builtin_amdgcn_mfma_f32_16x16x32_bf16(af, bf, a2, 0, 0, 0);
            }
            int c2 = wave*16 + l16;
            float b2v = b2s[c2];
#pragma unroll
            for (int j = 0; j < 4; ++j)
                xw[(quad*4 + j)*72 + c2] = f2bf(elu_(a2[j] + b2v));
        }
        if (i >= 2) {
            int t = i - 2;
            const unsigned short* xsr = xs + (t & 1) * (16*72);
            const unsigned short* hc  = hlds + cur * (16*HP8);
            unsigned short*       hn  = hlds + (cur ^ 1) * (16*HP8);
            if (act) {
                f32x4 acc[4];
                acc[0] = splat4(bsr);
                acc[1] = splat4(bsz);
                acc[2] = splat4(binx);
                acc[3] = splat4(bhnn);
#pragma unroll
                for (int ks = 0; ks < 2; ++ks) {
                    short8 xf = *(const short8*)(xsr + l16*72 + ks*32 + quad*8);
                    acc[0] = __builtin_amdgcn_mfma_f32_16x16x32_bf16(xf, wxr[0][ks], acc[0], 0, 0, 0);
                    acc[1] = __builtin_amdgcn_mfma_f32_16x16x32_bf16(xf, wxr[1][ks], acc[1], 0, 0, 0);
                    acc[2] = __builtin_amdgcn_mfma_f32_16x16x32_bf16(xf, wxr[2][ks], acc[2], 0, 0, 0);
                }
#pragma unroll
                for (int ks = 0; ks < KS; ++ks) {
                    short8 ah = *(const short8*)(hc + l16*HP8 + ks*32 + quad*8);
                    acc[0] = __builtin_amdgcn_mfma_f32_16x16x32_bf16(ah, whr[0][ks], acc[0], 0, 0, 0);
                    acc[1] = __builtin_amdgcn_mfma_f32_16x16x32_bf16(ah, whr[1][ks], acc[1], 0, 0, 0);
                    acc[3] = __builtin_amdgcn_mfma_f32_16x16x32_bf16(ah, whr[2][ks], acc[3], 0, 0, 0);
                }
                float hv[4];
#pragma unroll
                for (int j = 0; j < 4; ++j) {
                    float r  = rcp1pe_(acc[0][j]);
                    float zg = rcp1pe_(acc[1][j]);
                    float nn = __builtin_fmaf(-2.f, rcp1pe_(__builtin_fmaf(r, acc[3][j], acc[2][j])), 1.f);
                    hv[j] = __builtin_fmaf(zg, hreg[j] - nn, nn);
                    hreg[j] = hv[j];
                }
                uint32_t p01 = pk_bf16(hv[0], hv[1]);
                uint32_t p23 = pk_bf16(hv[2], hv[3]);
                hn[(quad*4+0)*HP8 + c] = (unsigned short)p01;
                hn[(quad*4+1)*HP8 + c] = (unsigned short)(p01 >> 16);
                hn[(quad*4+2)*HP8 + c] = (unsigned short)p23;
                hn[(quad*4+3)*HP8 + c] = (unsigned short)(p23 >> 16);
            }
            cur ^= 1;
        }
        __syncthreads();
    }

    if (act)
#pragma unroll
        for (int j = 0; j < 4; ++j) {
            int m = quad*4 + j;
            houtb[(size_t)(b0 + m)*KP + c] = (c < H) ? f2bf(hreg[j]) : 0;
        }
}

__global__ __launch_bounds__(768) void gru_kernel(
    int mode,
    const float* __restrict__ obs,
    const int* __restrict__ prox_idx, const int* __restrict__ dist_idx,
    const uint8_t* __restrict__ encp8, const uint8_t* __restrict__ wihp8,
    const float* __restrict__ w1p, const float* __restrict__ b1p,
    const float* __restrict__ w2p, const float* __restrict__ b2p,
    const float* __restrict__ w1d, const float* __restrict__ b1d,
    const float* __restrict__ w2d, const float* __restrict__ b2d,
    const unsigned short* __restrict__ wihp, const unsigned short* __restrict__ whhp,
    const unsigned short* __restrict__ wihd, const unsigned short* __restrict__ whhd,
    const float* __restrict__ bihp, const float* __restrict__ bhhp,
    const float* __restrict__ bihd, const float* __restrict__ bhhd,
    unsigned short* __restrict__ hpb, unsigned short* __restrict__ hdb)
{
    __shared__ __align__(16) char smem[33280];
    if (blockIdx.x < 128) {
        if (mode == 0)
            gru_body_pre(blockIdx.x, encp8, wihp8, whhp, bihp, bhhp, hpb, smem);
        else
            gru_body_fused<187, 192>(blockIdx.x, obs, prox_idx, w1p, b1p, w2p, b2p,
                                     wihp, whhp, bihp, bhhp, hpb, smem);
    } else {
        gru_body_fused<64, 64>(blockIdx.x - 128, obs, dist_idx, w1d, b1d, w2d, b2d,
                               wihd, whhd, bihd, bhhd, hdb, smem);
    }
}

// ---------------------------------------------------------------------------
// Fused mem-GRU (T=1, h0=0 -> f=(1-z)*n) + concat -> bf16 x0 [2048][320].
// ---------------------------------------------------------------------------
__global__ __launch_bounds__(256) void memfuse_kernel(
    const float* __restrict__ obs,
    const unsigned short* __restrict__ hpb, const unsigned short* __restrict__ hdb,
    const unsigned short* __restrict__ mwp, const unsigned short* __restrict__ mwd,
    const float* __restrict__ mbip, const float* __restrict__ mbhp,
    const float* __restrict__ mbid, const float* __restrict__ mbhd,
    unsigned short* __restrict__ x0b)
{
    __shared__ __align__(16) unsigned short Asl[64*40];
    __shared__ __align__(16) unsigned short Bsl[3][64*40];
    const int tid = threadIdx.x;
    const int wave = tid >> 6, lane = tid & 63, quad = lane >> 4, l16 = lane & 15;
    const int z = blockIdx.x, m0 = blockIdx.y * 64;
    const bool isp = (z < 3);
    const unsigned short* A = isp ? hpb : hdb;
    const unsigned short* B = isp ? mwp : mwd;
    const float* bi = isp ? mbip : mbid;
    const float* bh = isp ? mbhp : mbhd;
    const int Kp = isp ? 192 : 64;
    const int Hh = isp ? 187 : 64;
    const int jb = isp ? z * 64 : 0;
    const int cbase = isp ? 48 : 235;
    const int r = tid >> 2, sg = (tid & 3) * 8;

    f32x4 acc[3][4];
#pragma unroll
    for (int g = 0; g < 3; ++g)
#pragma unroll
        for (int nt = 0; nt < 4; ++nt) acc[g][nt] = splat4(0.f);

    for (int k0 = 0; k0 < Kp; k0 += 32) {
        *(short8*)(Asl + r*40 + sg) = *(const short8*)(A + (size_t)(m0 + r)*Kp + k0 + sg);
#pragma unroll
        for (int g = 0; g < 3; ++g)
            *(short8*)(Bsl[g] + r*40 + sg) =
                *(const short8*)(B + (size_t)(g*Kp + jb + r)*Kp + k0 + sg);
        __syncthreads();
        short8 af = *(const short8*)(Asl + (wave*16 + l16)*40 + quad*8);
#pragma unroll
        for (int g = 0; g < 3; ++g)
#pragma unroll
            for (int nt = 0; nt < 4; ++nt) {
                short8 bf = *(const short8*)(Bsl[g] + (nt*16 + l16)*40 + quad*8);
                acc[g][nt] = __builtin_amdgcn_mfma_f32_16x16x32_bf16(af, bf, acc[g][nt], 0, 0, 0);
            }
        __syncthreads();
    }
#pragma unroll
    for (int nt = 0; nt < 4; ++nt) {
        int j = jb + nt*16 + l16;
        bool valid = (j < Hh);
        float br = 0.f, bz = 0.f, bnx = 0.f, bnh = 0.f;
        if (valid) {
            br  = -L2E * (bi[j] + bh[j]);
            bz  = -L2E * (bi[Hh + j] + bh[Hh + j]);
            bnx = 2.f * L2E * bi[2*Hh + j];
            bnh = 2.f * L2E * bh[2*Hh + j];
        }
#pragma unroll
        for (int jj = 0; jj < 4; ++jj) {
            int m = m0 + wave*16 + quad*4 + jj;
            float rr = rcp1pe_(acc[0][nt][jj] + br);
            float zz = rcp1pe_(acc[1][nt][jj] + bz);
            float tt = __builtin_fmaf(rr, bnh, acc[2][nt][jj] + bnx);
            float nn = __builtin_fmaf(-2.f, rcp1pe_(tt), 1.f);
            float v  = (1.f - zz) * nn;
            if (valid) x0b[(size_t)m*320 + cbase + j] = f2bf(v);
        }
    }
    if (z == 0) {
        for (int e = tid; e < 64*48; e += 256) {
            int m = m0 + e / 48, cc = e - (e / 48) * 48;
            x0b[(size_t)m*320 + cc] = f2bf(obs[(size_t)m*3120 + cc]);
        }
    }
    if (z == 3) {
        for (int e = tid; e < 64*21; e += 256) {
            int m = m0 + e / 21, cc = 299 + (e - (e / 21) * 21);
            x0b[(size_t)m*320 + cc] = 0;
        }
    }
}

// ---------------------------------------------------------------------------
// bf16 MFMA GEMM, K-tile 64 (half the barriers of K32):
// C[m][n] = act(A[m][:] . B[n][:] + bias[n]); Kp%64==0.
// mode 1: ELU + bf16 out (stride Np). mode 0: fp32 out (stride Nstore).
// ---------------------------------------------------------------------------
__global__ __launch_bounds__(256) void bgemm_kernel(
    const unsigned short* __restrict__ A, const unsigned short* __restrict__ B,
    const float* __restrict__ bias, void* __restrict__ C,
    int Kp, int Np, int Nstore, int mode)
{
    __shared__ __align__(16) unsigned short Asl[64*72];
    __shared__ __align__(16) unsigned short Bsl[64*72];
    const int tid = threadIdx.x;
    const int wave = tid >> 6, lane = tid & 63, quad = lane >> 4, l16 = lane & 15;
    const int n0 = blockIdx.x * 64, m0 = blockIdx.y * 64;
    const int r = tid >> 2, sg = (tid & 3) * 16;

    f32x4 acc[4];
#pragma unroll
    for (int nt = 0; nt < 4; ++nt) acc[nt] = splat4(0.f);

    for (int k0 = 0; k0 < Kp; k0 += 64) {
        *(short8*)(Asl + r*72 + sg)     = *(const short8*)(A + (size_t)(m0 + r)*Kp + k0 + sg);
        *(short8*)(Asl + r*72 + sg + 8) = *(const short8*)(A + (size_t)(m0 + r)*Kp + k0 + sg + 8);
        if (n0 + r < Np) {
            *(short8*)(Bsl + r*72 + sg)     = *(const short8*)(B + (size_t)(n0 + r)*Kp + k0 + sg);
            *(short8*)(Bsl + r*72 + sg + 8) = *(const short8*)(B + (size_t)(n0 + r)*Kp + k0 + sg + 8);
        } else {
            short8 zz; for (int q = 0; q < 8; ++q) zz[q] = 0;
            *(short8*)(Bsl + r*72 + sg) = zz;
            *(short8*)(Bsl + r*72 + sg + 8) = zz;
        }
        __syncthreads();
#pragma unroll
        for (int ks = 0; ks < 2; ++ks) {
            short8 af = *(const short8*)(Asl + (wave*16 + l16)*72 + ks*32 + quad*8);
#pragma unroll
            for (int nt = 0; nt < 4; ++nt) {
                short8 bf = *(const short8*)(Bsl + (nt*16 + l16)*72 + ks*32 + quad*8);
                acc[nt] = __builtin_amdgcn_mfma_f32_16x16x32_bf16(af, bf, acc[nt], 0, 0, 0);
            }
        }
        __syncthreads();
    }
#pragma unroll
    for (int nt = 0; nt < 4; ++nt) {
        int n = n0 + nt*16 + l16;
        float bv = (bias && n < Np) ? bias[n] : 0.f;
#pragma unroll
        for (int j = 0; j < 4; ++j) {
            int m = m0 + wave*16 + quad*4 + j;
            float v = acc[nt][j] + bv;
            if (mode == 1) {
                ((unsigned short*)C)[(size_t)m*Np + n] = f2bf(elu_(v));
            } else {
                if (n < Nstore) ((float*)C)[(size_t)m*Nstore + n] = v;
            }
        }
    }
}

// ---------------------------------------------------------------------------
// Fused actor layers 3+4: a3b[2048][256] -> elu(a3@W3^T+b3)[64 rows x 128]
// (LDS only) -> out = (.)@W4^T + b4, fp32 [2048][12]. Grid 32 blocks, 256 thr.
// ---------------------------------------------------------------------------
__global__ __launch_bounds__(256) void gemm34_kernel(
    const unsigned short* __restrict__ A,   // a3b [2048][256]
    const unsigned short* __restrict__ W3,  // w3p [128][256]
    const float* __restrict__ b3,
    const unsigned short* __restrict__ W4,  // w4p [16][128]
    const float* __restrict__ b4,
    float* __restrict__ out)
{
    __shared__ __align__(16) char smem[9216 + 18432];
    unsigned short* Asl  = (unsigned short*)smem;            // [64][72]
    unsigned short* B3sl = (unsigned short*)(smem + 9216);   // [128][72]
    unsigned short* a4s  = (unsigned short*)smem;            // [64][136] (aliases, post-barrier)
    const int tid = threadIdx.x;
    const int wave = tid >> 6, lane = tid & 63, quad = lane >> 4, l16 = lane & 15;
    const int m0 = blockIdx.x * 64;

    f32x4 acc3[8];
#pragma unroll
    for (int nt = 0; nt < 8; ++nt) acc3[nt] = splat4(0.f);

    const int r = tid >> 2, sg = (tid & 3) * 16;
    const int r2 = tid >> 1, sg2 = (tid & 1) * 32;
    for (int k0 = 0; k0 < 256; k0 += 64) {
        *(short8*)(Asl + r*72 + sg)     = *(const short8*)(A + (size_t)(m0 + r)*256 + k0 + sg);
        *(short8*)(Asl + r*72 + sg + 8) = *(const short8*)(A + (size_t)(m0 + r)*256 + k0 + sg + 8);
#pragma unroll
        for (int s = 0; s < 4; ++s)
            *(short8*)(B3sl + r2*72 + sg2 + s*8) =
                *(const short8*)(W3 + (size_t)r2*256 + k0 + sg2 + s*8);
        __syncthreads();
#pragma unroll
        for (int ks = 0; ks < 2; ++ks) {
            short8 af = *(const short8*)(Asl + (wave*16 + l16)*72 + ks*32 + quad*8);
#pragma unroll
            for (int nt = 0; nt < 8; ++nt) {
                short8 bf = *(const short8*)(B3sl + (nt*16 + l16)*72 + ks*32 + quad*8);
                acc3[nt] = __builtin_amdgcn_mfma_f32_16x16x32_bf16(af, bf, acc3[nt], 0, 0, 0);
            }
        }
        __syncthreads();
    }
    // layer-3 epilogue -> a4s (elu, bf16); aliases Asl/B3sl (all reads done)
#pragma unroll
    for (int nt = 0; nt < 8; ++nt) {
        int n = nt*16 + l16;
        float bv = b3[n];
#pragma unroll
        for (int j = 0; j < 4; ++j) {
            int m = wave*16 + quad*4 + j;
            a4s[m*136 + n] = f2bf(elu_(acc3[nt][j] + bv));
        }
    }
    __syncthreads();
    // layer 4: K=128, N=16 (store n<12)
    f32x4 acc4 = splat4(0.f);
#pragma unroll
    for (int ks = 0; ks < 4; ++ks) {
        short8 af = *(const short8*)(a4s + (wave*16 + l16)*136 + ks*32 + quad*8);
        short8 bf = *(const short8*)(W4 + (size_t)l16*128 + ks*32 + quad*8);
        acc4 = __builtin_amdgcn_mfma_f32_16x16x32_bf16(af, bf, acc4, 0, 0, 0);
    }
    if (l16 < 12) {
        float bv = b4[l16];
#pragma unroll
        for (int j = 0; j < 4; ++j)
            out[(size_t)(m0 + wave*16 + quad*4 + j)*12 + l16] = acc4[j] + bv;
    }
}

// ---------------------------------------------------------------------------
extern "C" void kernel_launch(void* const* d_in, const int* in_sizes, int n_in,
                              void* d_out, int out_size, void* d_ws, size_t ws_size,
                              hipStream_t stream)
{
    (void)in_sizes; (void)n_in; (void)out_size;
    const float* obs        = (const float*)d_in[0];
    const int*   prox_idx   = (const int*)d_in[1];
    const int*   dist_idx   = (const int*)d_in[2];
    const float* pe_prox_w1 = (const float*)d_in[3];
    const float* pe_prox_b1 = (const float*)d_in[4];
    const float* pe_prox_w2 = (const float*)d_in[5];
    const float* pe_prox_b2 = (const float*)d_in[6];
    const float* pe_dist_w1 = (const float*)d_in[7];
    const float* pe_dist_b1 = (const float*)d_in[8];
    const float* pe_dist_w2 = (const float*)d_in[9];
    const float* pe_dist_b2 = (const float*)d_in[10];
    const float* gp_wih = (const float*)d_in[11];
    const float* gp_whh = (const float*)d_in[12];
    const float* gp_bih = (const float*)d_in[13];
    const float* gp_bhh = (const float*)d_in[14];
    const float* gd_wih = (const float*)d_in[15];
    const float* gd_whh = (const float*)d_in[16];
    const float* gd_bih = (const float*)d_in[17];
    const float* gd_bhh = (const float*)d_in[18];
    const float* mp_wih = (const float*)d_in[19];
    const float* mp_bih = (const float*)d_in[21];
    const float* mp_bhh = (const float*)d_in[22];
    const float* md_wih = (const float*)d_in[23];
    const float* md_bih = (const float*)d_in[25];
    const float* md_bhh = (const float*)d_in[26];
    const float* aw0 = (const float*)d_in[27]; const float* ab0 = (const float*)d_in[28];
    const float* aw1 = (const float*)d_in[29]; const float* ab1 = (const float*)d_in[30];
    const float* aw2 = (const float*)d_in[31]; const float* ab2 = (const float*)d_in[32];
    const float* aw3 = (const float*)d_in[33]; const float* ab3 = (const float*)d_in[34];
    const float* aw4 = (const float*)d_in[35]; const float* ab4 = (const float*)d_in[36];
    float* out = (float*)d_out;

    char* ws = (char*)d_ws;
    size_t off = 0;
    auto alloc = [&](size_t bytes) -> char* {
        char* p = ws + off;
        off = (off + bytes + 255) & ~(size_t)255;
        return p;
    };
    unsigned short* wih_p = (unsigned short*)alloc(36864*2);
    unsigned short* whh_p = (unsigned short*)alloc(110592*2);
    unsigned short* wih_d = (unsigned short*)alloc(12288*2);
    unsigned short* whh_d = (unsigned short*)alloc(12288*2);
    unsigned short* mw_p  = (unsigned short*)alloc(110592*2);
    unsigned short* mw_d  = (unsigned short*)alloc(12288*2);
    unsigned short* w0p   = (unsigned short*)alloc((size_t)1024*320*2);
    unsigned short* w1p   = (unsigned short*)alloc((size_t)512*1024*2);
    unsigned short* w2p   = (unsigned short*)alloc((size_t)256*512*2);
    unsigned short* w3p   = (unsigned short*)alloc((size_t)128*256*2);
    unsigned short* w4p   = (unsigned short*)alloc((size_t)16*128*2);
    unsigned short* w2e   = (unsigned short*)alloc(4096*2);
    uint8_t* wih8         = (uint8_t*)alloc(576*64);
    unsigned short* hpb   = (unsigned short*)alloc((size_t)2048*192*2);
    unsigned short* hdb   = (unsigned short*)alloc((size_t)2048*64*2);
    unsigned short* x0b   = (unsigned short*)alloc((size_t)2048*320*2);
    unsigned short* a1b   = (unsigned short*)alloc((size_t)2048*1024*2);
    unsigned short* a2b   = (unsigned short*)alloc((size_t)2048*512*2);
    unsigned short* a3b   = (unsigned short*)alloc((size_t)2048*256*2);
    uint8_t* enc8         = (uint8_t*)alloc((size_t)2048*512*64);   // 67 MB, LAST
    const int mode = (off <= ws_size) ? 0 : 1;   // fall back if ws too small

    const float SR = -L2E, SN = 2.f * L2E;
    PJobs P;
    P.j[0]  = { gp_wih, wih_p, 187, 192, 64, 64, 36864, SR, SR, SN, 0 };
    P.j[1]  = { gp_whh, whh_p, 187, 192, 187, 192, 110592, SR, SR, SN, 0 };
    P.j[2]  = { gd_wih, wih_d, 64, 64, 64, 64, 12288, SR, SR, SN, 0 };
    P.j[3]  = { gd_whh, whh_d, 64, 64, 64, 64, 12288, SR, SR, SN, 0 };
    P.j[4]  = { mp_wih, mw_p, 187, 192, 187, 192, 110592, SR, SR, SN, 0 };
    P.j[5]  = { md_wih, mw_d, 64, 64, 64, 64, 12288, SR, SR, SN, 0 };
    P.j[6]  = { aw0, w0p, 1024, 1024, 299, 320, 327680, 1.f, 1.f, 1.f, 0 };
    P.j[7]  = { aw1, w1p, 512, 512, 1024, 1024, 524288, 1.f, 1.f, 1.f, 0 };
    P.j[8]  = { aw2, w2p, 256, 256, 512, 512, 131072, 1.f, 1.f, 1.f, 0 };
    P.j[9]  = { aw3, w3p, 128, 128, 256, 256, 32768, 1.f, 1.f, 1.f, 0 };
    P.j[10] = { aw4, w4p, 12, 16, 128, 128, 2048, 1.f, 1.f, 1.f, 0 };
    P.j[11] = { pe_prox_w2, w2e, 64, 64, 64, 64, 4096, 1.f, 1.f, 1.f, 0 };
    P.j[12] = { gp_wih, wih8, 187, 192, 64, 64, 36864, SR, SR, SN, 1 };
    pack_all<<<dim3(2048, 13), 256, 0, stream>>>(P);

    if (mode == 0) {
        enc_kernel<<<dim3(2048, 8), 256, 0, stream>>>(
            obs, prox_idx, pe_prox_w1, pe_prox_b1, w2e, pe_prox_b2, enc8);
    }

    gru_kernel<<<256, 768, 0, stream>>>(
        mode, obs, prox_idx, dist_idx, enc8, wih8,
        pe_prox_w1, pe_prox_b1, pe_prox_w2, pe_prox_b2,
        pe_dist_w1, pe_dist_b1, pe_dist_w2, pe_dist_b2,
        wih_p, whh_p, wih_d, whh_d,
        gp_bih, gp_bhh, gd_bih, gd_bhh, hpb, hdb);

    // --- fused mem-GRU gemm + gates + concat -> bf16 x0 ---
    memfuse_kernel<<<dim3(4, 32), 256, 0, stream>>>(
        obs, hpb, hdb, mw_p, mw_d, mp_bih, mp_bhh, md_bih, md_bhh, x0b);

    // --- actor MLP: bgemm x3, then fused layers 3+4 ---
    bgemm_kernel<<<dim3(16, 32), 256, 0, stream>>>(x0b, w0p, ab0, a1b, 320, 1024, 1024, 1);
    bgemm_kernel<<<dim3(8,  32), 256, 0, stream>>>(a1b, w1p, ab1, a2b, 1024, 512, 512, 1);
    bgemm_kernel<<<dim3(4,  32), 256, 0, stream>>>(a2b, w2p, ab2, a3b, 512, 256, 256, 1);
    gemm34_kernel<<<32, 256, 0, stream>>>(a3b, w3p, ab3, w4p, ab4, out);
}

// Round 10
// 785.466 us; speedup vs baseline: 2.2138x; 1.0253x over previous
//
#include <hip/hip_runtime.h>
#include <stdint.h>

typedef __attribute__((ext_vector_type(8))) short short8;
typedef __attribute__((ext_vector_type(4))) float f32x4;
typedef __attribute__((ext_vector_type(4))) unsigned int u32x4;
typedef __attribute__((ext_vector_type(4))) float float4v;

#define DEV __device__ __forceinline__

#define L2E 1.4426950408889634f

DEV unsigned short f2bf(float f) {
    union { float f; uint32_t u; } v; v.f = f;
    return (unsigned short)((v.u + 0x7FFFu + ((v.u >> 16) & 1u)) >> 16);
}
#if defined(__has_builtin)
#if __has_builtin(__builtin_amdgcn_cvt_pk_bf16_f32)
#define HAS_PK_BF16 1
#endif
#if __has_builtin(__builtin_amdgcn_cvt_pk_fp8_f32)
#define HAS_PK_FP8 1
#endif
#endif
DEV uint32_t pk_bf16(float a, float b) {
#ifdef HAS_PK_BF16
    typedef __attribute__((ext_vector_type(2))) __bf16 bf2;
    union { bf2 v; uint32_t u; } cv;
    cv.v = __builtin_amdgcn_cvt_pk_bf16_f32(a, b);
    return cv.u;
#else
    return (uint32_t)f2bf(a) | ((uint32_t)f2bf(b) << 16);
#endif
}
// f32 -> OCP e4m3fn (manual fallback)
DEV uint8_t f2fp8(float f) {
    union { float f; uint32_t u; } v; v.f = f;
    uint32_t s = (v.u >> 24) & 0x80u;
    uint32_t absu = v.u & 0x7FFFFFFFu;
    int E = (int)(absu >> 23);
    if (E >= 136) return (uint8_t)(s | 0x7E);
    if (E >= 121) {
        uint32_t m = absu & 0x7FFFFFu;
        uint32_t keep = m >> 20;
        uint32_t rest = m & 0xFFFFFu;
        uint32_t rnd = (rest > 0x80000u || (rest == 0x80000u && (keep & 1u))) ? 1u : 0u;
        uint32_t mag = (((uint32_t)(E - 120) << 3) | keep) + rnd;
        if (mag > 0x7Eu) mag = 0x7Eu;
        return (uint8_t)(s | mag);
    }
    float sc = __builtin_fabsf(f) * 512.f;
    uint32_t m8 = (uint32_t)(sc + 0.5f);
    if (m8 > 7u) return (uint8_t)(s | 0x08);
    return (uint8_t)(s | m8);
}
// 4x f32 -> 4x fp8 packed in a dword (HW cvt when available)
DEV uint32_t pk_fp8x4(float a, float b, float c, float d) {
#ifdef HAS_PK_FP8
    int lo   = __builtin_amdgcn_cvt_pk_fp8_f32(a, b, 0, false);
    int both = __builtin_amdgcn_cvt_pk_fp8_f32(c, d, lo, true);
    return (uint32_t)both;
#else
    return (uint32_t)f2fp8(a) | ((uint32_t)f2fp8(b) << 8)
         | ((uint32_t)f2fp8(c) << 16) | ((uint32_t)f2fp8(d) << 24);
#endif
}
DEV float rcp1pe_(float x) {          // 1/(1+exp2(x))
    return __builtin_amdgcn_rcpf(1.f + __builtin_amdgcn_exp2f(x));
}
DEV float elu_(float x) {
    return x > 0.f ? x : __builtin_amdgcn_exp2f(L2E * x) - 1.f;
}
DEV f32x4 splat4(float v) { f32x4 r; r[0]=v; r[1]=v; r[2]=v; r[3]=v; return r; }
DEV void pin(short8& v) { asm volatile("" : "+v"(v)); }
DEV void pinl(long& v)  { asm volatile("" : "+v"(v)); }

// ---------------------------------------------------------------------------
// Flat fused weight pack: fp32 -> bf16/fp8, MFMA B-layout [3*NG rows][Kd],
// per-gate scale (prescale trick). Prefix-mapped 1D grid — no empty blocks.
// ---------------------------------------------------------------------------
struct PJob { const float* s; void* d; int Hs, NG, Ks, Kd; float s0, s1, s2; int fmt; };
struct PJobs { PJob j[12]; int pref[13]; };

__global__ __launch_bounds__(256) void pack_all(PJobs P)
{
    int e = blockIdx.x * 256 + threadIdx.x;
    if (e >= P.pref[12]) return;
    int ji = 0;
    while (e >= P.pref[ji + 1]) ++ji;
    PJob jb = P.j[ji];
    int le = e - P.pref[ji];
    int n = le / jb.Kd, k = le - n * jb.Kd;
    int g = n / jb.NG, jj = n - g * jb.NG;
    float sc = (g == 0) ? jb.s0 : ((g == 1) ? jb.s1 : jb.s2);
    float v = (jj < jb.Hs && k < jb.Ks) ? jb.s[(size_t)(g * jb.Hs + jj) * jb.Ks + k] * sc : 0.f;
    if (jb.fmt) ((uint8_t*)jb.d)[le] = (uint8_t)(pk_fp8x4(v, 0.f, 0.f, 0.f) & 0xFFu);
    else        ((unsigned short*)jb.d)[le] = f2bf(v);
}

// ---------------------------------------------------------------------------
// Prox encoder v2 -> fp8 e4m3 [2048][512][64]. ONE block per batch row:
// stage the 12 KB lidar row + all 512 indices into LDS once (coalesced),
// then 8 time-chunks gather from LDS (batch-uniform idx => broadcast reads).
// w2 bf16-pack is done in-block (4 KB). Obs lidar read once (was 8x, scattered).
// LDS ~39.5 KB.
// ---------------------------------------------------------------------------
__global__ __launch_bounds__(256) void enc_kernel(
    const float* __restrict__ obs, const int* __restrict__ idx,
    const float* __restrict__ w1, const float* __restrict__ b1,
    const float* __restrict__ w2, const float* __restrict__ b2,
    uint8_t* __restrict__ enc8)
{
    const int b = blockIdx.x;
    const int tid = threadIdx.x;
    __shared__ __align__(16) float lid[3072];
    __shared__ int idxs[512];
    __shared__ float w1s[256], b1s[64], b2s[64];
    __shared__ __align__(16) unsigned short w2s[64*72];
    __shared__ __align__(16) unsigned short h1s[64*72];
    __shared__ __align__(16) uint8_t x8s[64*80];

    {   // coalesced staging
        const float4v* src = (const float4v*)(obs + (size_t)b * 3120 + 48);
#pragma unroll
        for (int r = 0; r < 3; ++r) ((float4v*)lid)[tid + r*256] = src[tid + r*256];
        for (int e = tid; e < 512; e += 256) idxs[e] = idx[e];
        for (int e = tid; e < 4096; e += 256) {
            int n = e >> 6, k = e & 63;
            w2s[n*72 + k] = f2bf(w2[e]);
        }
        if (tid < 192) w1s[(tid/3)*4 + (tid - (tid/3)*3)] = w1[tid];
        if (tid < 64) { b1s[tid] = b1[tid]; b2s[tid] = b2[tid]; }
    }
    __syncthreads();

    const int wave = tid >> 6, lane = tid & 63, quad = lane >> 4, l16 = lane & 15;
    for (int tc = 0; tc < 8; ++tc) {
        const int t0 = tc * 64;
        // ---- layer 1: 64 steps x 64 ch (gather from LDS, broadcast reads) ----
#pragma unroll
        for (int r = 0; r < 16; ++r) {
            int e = tid + r * 256;
            int p = e >> 6, ch = e & 63;
            int pi = idxs[t0 + p];
            float x = lid[3*pi], y = lid[3*pi + 1], z = lid[3*pi + 2];
            float v = w1s[ch*4]*x + w1s[ch*4+1]*y + w1s[ch*4+2]*z + b1s[ch];
            h1s[p*72 + ch] = f2bf(elu_(v));
        }
        __syncthreads();
        // ---- layer 2 (MFMA) + fp8 pack into staging ----
#pragma unroll
        for (int ct = 0; ct < 4; ++ct) {
            f32x4 a2 = splat4(0.f);
#pragma unroll
            for (int ks = 0; ks < 2; ++ks) {
                short8 af = *(const short8*)(h1s + (wave*16 + l16)*72 + ks*32 + quad*8);
                short8 bf = *(const short8*)(w2s + (ct*16 + l16)*72 + ks*32 + quad*8);
                a2 = __builtin_amdgcn_mfma_f32_16x16x32_bf16(af, bf, a2, 0, 0, 0);
            }
            int c = ct*16 + l16;
            float b2v = b2s[c];
            uint32_t pk = pk_fp8x4(elu_(a2[0] + b2v), elu_(a2[1] + b2v),
                                   elu_(a2[2] + b2v), elu_(a2[3] + b2v));
#pragma unroll
            for (int j = 0; j < 4; ++j)
                x8s[(wave*16 + quad*4 + j)*80 + c] = (uint8_t)(pk >> (8*j));
        }
        __syncthreads();
        {   // coalesced store: 256 thr x 16 B = 64 rows x 64 B
            int row = tid >> 2, seg = tid & 3;
            *(u32x4*)(enc8 + ((size_t)b*512 + t0 + row)*64 + seg*16) =
                *(const u32x4*)(x8s + row*80 + seg*16);
        }
        __syncthreads();   // x8s/h1s free for next chunk
    }
}

// ---------------------------------------------------------------------------
// PROX GRU, precomputed-enc, prescaled gates, XOR-swizzled h LDS layout.
// (Swizzle kept from r9 — neutral; conflicts proven read-side/inherent.)
// ---------------------------------------------------------------------------
DEV void gru_body_pre(int blk, const uint8_t* __restrict__ enc8,
                      const uint8_t* __restrict__ wih8,
                      const unsigned short* __restrict__ whh,
                      const float* __restrict__ bih, const float* __restrict__ bhh,
                      unsigned short* __restrict__ houtb, char* smem)
{
    constexpr int H = 187, KP = 192, KS = 6, HP8 = 200;
    unsigned short* hlds = (unsigned short*)smem;
    uint8_t* xs = (uint8_t*)(smem + 12800);

    const int tid  = threadIdx.x;
    const int wave = tid >> 6, lane = tid & 63, quad = lane >> 4, l16 = lane & 15;
    const int b0   = blk * 16;
    const int c    = wave * 16 + l16;

    const int sx = (l16 >> 2) & 3;
    const int qo = (quad ^ sx) * 8;
    const int cc = c >> 3, cl = c & 7;
    const int wcol = ((cc & ~3) | ((cc & 3) ^ quad)) * 8 + cl;

    for (int e = tid; e < 2*16*HP8; e += 768) hlds[e] = 0;

    short8 whr[3][KS];
    long   wx8[3][2];
#pragma unroll
    for (int g = 0; g < 3; ++g) {
#pragma unroll
        for (int ks = 0; ks < KS; ++ks)
            whr[g][ks] = *(const short8*)(whh + ((size_t)(g*KP + c))*KP + ks*32 + quad*8);
#pragma unroll
        for (int ks = 0; ks < 2; ++ks)
            wx8[g][ks] = *(const long*)(wih8 + ((size_t)(g*KP + c))*64 + ks*32 + quad*8);
    }
#pragma unroll
    for (int g = 0; g < 3; ++g) {
#pragma unroll
        for (int ks = 0; ks < KS; ++ks) pin(whr[g][ks]);
#pragma unroll
        for (int ks = 0; ks < 2; ++ks)  pinl(wx8[g][ks]);
    }
    float bsr = 0.f, bsz = 0.f, binx = 0.f, bhnn = 0.f;
    if (c < H) {
        bsr  = -L2E * (bih[c]       + bhh[c]);
        bsz  = -L2E * (bih[H + c]   + bhh[H + c]);
        binx = 2.f * L2E * bih[2*H + c];
        bhnn = 2.f * L2E * bhh[2*H + c];
    }
    float hreg[4] = {0.f, 0.f, 0.f, 0.f};

    u32x4 xq;
    const int xrow = lane >> 2, xseg = lane & 3;
    if (wave == 0) {
        xq = *(const u32x4*)(enc8 + ((size_t)(b0 + xrow)*512 + 0)*64 + xseg*16);
        *(u32x4*)(xs + 0*1280 + xrow*80 + xseg*16) = xq;
        xq = *(const u32x4*)(enc8 + ((size_t)(b0 + xrow)*512 + 1)*64 + xseg*16);
    }
    __syncthreads();

    int cur = 0;
    for (int t = 0; t < 512; ++t) {
        if (wave == 0) {
            *(u32x4*)(xs + ((t+1)&1)*1280 + xrow*80 + xseg*16) = xq;
            int tn = (t + 2 < 512) ? t + 2 : 511;
            xq = *(const u32x4*)(enc8 + ((size_t)(b0 + xrow)*512 + tn)*64 + xseg*16);
        }
        const uint8_t* xsr = xs + (t&1)*1280;
        const unsigned short* hc = hlds + cur * (16*HP8);
        unsigned short*       hn = hlds + (cur ^ 1) * (16*HP8);

        f32x4 acc[4];                          // r, z, nx, nh
        acc[0] = splat4(bsr);
        acc[1] = splat4(bsz);
        acc[2] = splat4(binx);
        acc[3] = splat4(bhnn);
#pragma unroll
        for (int ks = 0; ks < 2; ++ks) {
            long a8 = *(const long*)(xsr + l16*80 + ks*32 + quad*8);
            acc[0] = __builtin_amdgcn_mfma_f32_16x16x32_fp8_fp8(a8, wx8[0][ks], acc[0], 0, 0, 0);
            acc[1] = __builtin_amdgcn_mfma_f32_16x16x32_fp8_fp8(a8, wx8[1][ks], acc[1], 0, 0, 0);
            acc[2] = __builtin_amdgcn_mfma_f32_16x16x32_fp8_fp8(a8, wx8[2][ks], acc[2], 0, 0, 0);
        }
#pragma unroll
        for (int ks = 0; ks < KS; ++ks) {
            short8 ah = *(const short8*)(hc + l16*HP8 + ks*32 + qo);
            acc[0] = __builtin_amdgcn_mfma_f32_16x16x32_bf16(ah, whr[0][ks], acc[0], 0, 0, 0);
            acc[1] = __builtin_amdgcn_mfma_f32_16x16x32_bf16(ah, whr[1][ks], acc[1], 0, 0, 0);
            acc[3] = __builtin_amdgcn_mfma_f32_16x16x32_bf16(ah, whr[2][ks], acc[3], 0, 0, 0);
        }
        float hv[4];
#pragma unroll
        for (int j = 0; j < 4; ++j) {
            float r  = rcp1pe_(acc[0][j]);
            float zg = rcp1pe_(acc[1][j]);
            float nn = __builtin_fmaf(-2.f, rcp1pe_(__builtin_fmaf(r, acc[3][j], acc[2][j])), 1.f);
            hv[j] = __builtin_fmaf(zg, hreg[j] - nn, nn);
            hreg[j] = hv[j];
        }
        uint32_t p01 = pk_bf16(hv[0], hv[1]);
        uint32_t p23 = pk_bf16(hv[2], hv[3]);
        hn[(quad*4+0)*HP8 + wcol] = (unsigned short)p01;
        hn[(quad*4+1)*HP8 + wcol] = (unsigned short)(p01 >> 16);
        hn[(quad*4+2)*HP8 + wcol] = (unsigned short)p23;
        hn[(quad*4+3)*HP8 + wcol] = (unsigned short)(p23 >> 16);
        cur ^= 1;
        __syncthreads();
    }
#pragma unroll
    for (int j = 0; j < 4; ++j) {
        int m = quad*4 + j;
        houtb[(size_t)(b0 + m)*KP + c] = (c < H) ? f2bf(hreg[j]) : 0;
    }
}

// ---------------------------------------------------------------------------
// Fused encoder + GRU body — dist, and prox fallback. Prescaled gates.
// ---------------------------------------------------------------------------
template<int H, int KP>
DEV void gru_body_fused(int blk,
                  const float* __restrict__ obs, const int* __restrict__ idx,
                  const float* __restrict__ w1, const float* __restrict__ b1,
                  const float* __restrict__ w2, const float* __restrict__ b2,
                  const unsigned short* __restrict__ wih, const unsigned short* __restrict__ whh,
                  const float* __restrict__ bih, const float* __restrict__ bhh,
                  unsigned short* __restrict__ houtb, char* smem)
{
    constexpr int NCT = KP / 16;
    constexpr int KS  = KP / 32;
    constexpr int HP8 = KP + 8;

    unsigned short* hlds = (unsigned short*)(smem);
    unsigned short* xs   = (unsigned short*)(smem + 12800);
    unsigned short* h1s  = (unsigned short*)(smem + 17408);
    unsigned short* w2s  = (unsigned short*)(smem + 22016);
    float* ptsb          = (float*)(smem + 31232);
    float* w1s           = (float*)(smem + 31744);
    float* b1s           = (float*)(smem + 32768);
    float* b2s           = (float*)(smem + 33024);

    const int tid  = threadIdx.x;
    const int wave = tid >> 6, lane = tid & 63, quad = lane >> 4, l16 = lane & 15;
    const int b0   = blk * 16;
    const int ct   = wave;
    const bool act = (ct < NCT);
    const int c    = ct * 16 + l16;

    for (int e = tid; e < 2*16*HP8; e += 768) hlds[e] = 0;
    for (int e = tid; e < 4096; e += 768) { int n = e >> 6, k = e & 63; w2s[n*72 + k] = f2bf(w2[e]); }
    if (tid < 192) w1s[(tid/3)*4 + (tid - (tid/3)*3)] = w1[tid];
    if (tid < 64) { b1s[tid] = b1[tid]; b2s[tid] = b2[tid]; }

    const float* myrow = obs + (size_t)(b0 + (tid & 15)) * 3120 + 48;
    float px = 0.f, py = 0.f, pz = 0.f;
    if (tid < 16) {
        int p0 = idx[0];
        ptsb[tid*4 + 0] = myrow[3*p0 + 0];
        ptsb[tid*4 + 1] = myrow[3*p0 + 1];
        ptsb[tid*4 + 2] = myrow[3*p0 + 2];
        int p1 = idx[1];
        px = myrow[3*p1 + 0]; py = myrow[3*p1 + 1]; pz = myrow[3*p1 + 2];
    }

    short8 whr[3][KS];
    short8 wxr[3][2];
    float bsr = 0.f, bsz = 0.f, binx = 0.f, bhnn = 0.f;
    {
        const int cl = act ? c : l16;
#pragma unroll
        for (int g = 0; g < 3; ++g) {
#pragma unroll
            for (int ks = 0; ks < KS; ++ks)
                whr[g][ks] = *(const short8*)(whh + ((size_t)(g*KP + cl))*KP + ks*32 + quad*8);
#pragma unroll
            for (int ks = 0; ks < 2; ++ks)
                wxr[g][ks] = *(const short8*)(wih + ((size_t)(g*KP + cl))*64 + ks*32 + quad*8);
        }
    }
#pragma unroll
    for (int g = 0; g < 3; ++g) {
#pragma unroll
        for (int ks = 0; ks < KS; ++ks) pin(whr[g][ks]);
#pragma unroll
        for (int ks = 0; ks < 2; ++ks)  pin(wxr[g][ks]);
    }
    if (act && c < H) {
        bsr  = -L2E * (bih[c]       + bhh[c]);
        bsz  = -L2E * (bih[H + c]   + bhh[H + c]);
        binx = 2.f * L2E * bih[2*H + c];
        bhnn = 2.f * L2E * bhh[2*H + c];
    }
    float hreg[4] = {0.f, 0.f, 0.f, 0.f};

    __syncthreads();

    int cur = 0;
    for (int i = 0; i < 514; ++i) {
        if (i < 512) {
            const float* pt = ptsb + (i & 1) * 64;
            unsigned short* h1w = h1s + (i & 1) * (16*72);
#pragma unroll
            for (int e = tid; e < 1024; e += 768) {
                int p = e >> 6, ch = e & 63;
                float v = w1s[ch*4+0]*pt[p*4+0] + w1s[ch*4+1]*pt[p*4+1]
                        + w1s[ch*4+2]*pt[p*4+2] + b1s[ch];
                h1w[p*72 + ch] = f2bf(elu_(v));
            }
            if (tid < 16) {
                float* dst = ptsb + ((i+1) & 1) * 64 + tid*4;
                dst[0] = px; dst[1] = py; dst[2] = pz;
                int tn = (i + 2 < 512) ? i + 2 : 511;
                int pn = idx[tn];
                px = myrow[3*pn + 0]; py = myrow[3*pn + 1]; pz = myrow[3*pn + 2];
            }
        }
        if (i >= 1 && i < 513 && wave < 4) {
            const unsigned short* h1r = h1s + ((i-1) & 1) * (16*72);
            unsigned short*       xw  = xs  + ((i-1) & 1) * (16*72);
            f32x4 a2 = splat4(0.f);
#pragma unroll
            for (int ks = 0; ks < 2; ++ks) {
                short8 af = *(const short8*)(h1r + l16*72 + ks*32 + quad*8);
                short8 bf = *(const short8*)(w2s + (wave*16 + l16)*72 + ks*32 + quad*8);
                a2 = __builtin_amdgcn_mfma_f32_16x16x32_bf16(af, bf, a2, 0, 0, 0);
            }
            int c2 = wave*16 + l16;
            float b2v = b2s[c2];
#pragma unroll
            for (int j = 0; j < 4; ++j)
                xw[(quad*4 + j)*72 + c2] = f2bf(elu_(a2[j] + b2v));
        }
        if (i >= 2) {
            int t = i - 2;
            const unsigned short* xsr = xs + (t & 1) * (16*72);
            const unsigned short* hc  = hlds + cur * (16*HP8);
            unsigned short*       hn  = hlds + (cur ^ 1) * (16*HP8);
            if (act) {
                f32x4 acc[4];
                acc[0] = splat4(bsr);
                acc[1] = splat4(bsz);
                acc[2] = splat4(binx);
                acc[3] = splat4(bhnn);
#pragma unroll
                for (int ks = 0; ks < 2; ++ks) {
                    short8 xf = *(const short8*)(xsr + l16*72 + ks*32 + quad*8);
                    acc[0] = __builtin_amdgcn_mfma_f32_16x16x32_bf16(xf, wxr[0][ks], acc[0], 0, 0, 0);
                    acc[1] = __builtin_amdgcn_mfma_f32_16x16x32_bf16(xf, wxr[1][ks], acc[1], 0, 0, 0);
                    acc[2] = __builtin_amdgcn_mfma_f32_16x16x32_bf16(xf, wxr[2][ks], acc[2], 0, 0, 0);
                }
#pragma unroll
                for (int ks = 0; ks < KS; ++ks) {
                    short8 ah = *(const short8*)(hc + l16*HP8 + ks*32 + quad*8);
                    acc[0] = __builtin_amdgcn_mfma_f32_16x16x32_bf16(ah, whr[0][ks], acc[0], 0, 0, 0);
                    acc[1] = __builtin_amdgcn_mfma_f32_16x16x32_bf16(ah, whr[1][ks], acc[1], 0, 0, 0);
                    acc[3] = __builtin_amdgcn_mfma_f32_16x16x32_bf16(ah, whr[2][ks], acc[3], 0, 0, 0);
                }
                float hv[4];
#pragma unroll
                for (int j = 0; j < 4; ++j) {
                    float r  = rcp1pe_(acc[0][j]);
                    float zg = rcp1pe_(acc[1][j]);
                    float nn = __builtin_fmaf(-2.f, rcp1pe_(__builtin_fmaf(r, acc[3][j], acc[2][j])), 1.f);
                    hv[j] = __builtin_fmaf(zg, hreg[j] - nn, nn);
                    hreg[j] = hv[j];
                }
                uint32_t p01 = pk_bf16(hv[0], hv[1]);
                uint32_t p23 = pk_bf16(hv[2], hv[3]);
                hn[(quad*4+0)*HP8 + c] = (unsigned short)p01;
                hn[(quad*4+1)*HP8 + c] = (unsigned short)(p01 >> 16);
                hn[(quad*4+2)*HP8 + c] = (unsigned short)p23;
                hn[(quad*4+3)*HP8 + c] = (unsigned short)(p23 >> 16);
            }
            cur ^= 1;
        }
        __syncthreads();
    }

    if (act)
#pragma unroll
        for (int j = 0; j < 4; ++j) {
            int m = quad*4 + j;
            houtb[(size_t)(b0 + m)*KP + c] = (c < H) ? f2bf(hreg[j]) : 0;
        }
}

__global__ __launch_bounds__(768) void gru_kernel(
    int mode,
    const float* __restrict__ obs,
    const int* __restrict__ prox_idx, const int* __restrict__ dist_idx,
    const uint8_t* __restrict__ encp8, const uint8_t* __restrict__ wihp8,
    const float* __restrict__ w1p, const float* __restrict__ b1p,
    const float* __restrict__ w2p, const float* __restrict__ b2p,
    const float* __restrict__ w1d, const float* __restrict__ b1d,
    const float* __restrict__ w2d, const float* __restrict__ b2d,
    const unsigned short* __restrict__ wihp, const unsigned short* __restrict__ whhp,
    const unsigned short* __restrict__ wihd, const unsigned short* __restrict__ whhd,
    const float* __restrict__ bihp, const float* __restrict__ bhhp,
    const float* __restrict__ bihd, const float* __restrict__ bhhd,
    unsigned short* __restrict__ hpb, unsigned short* __restrict__ hdb)
{
    __shared__ __align__(16) char smem[33280];
    if (blockIdx.x < 128) {
        if (mode == 0)
            gru_body_pre(blockIdx.x, encp8, wihp8, whhp, bihp, bhhp, hpb, smem);
        else
            gru_body_fused<187, 192>(blockIdx.x, obs, prox_idx, w1p, b1p, w2p, b2p,
                                     wihp, whhp, bihp, bhhp, hpb, smem);
    } else {
        gru_body_fused<64, 64>(blockIdx.x - 128, obs, dist_idx, w1d, b1d, w2d, b2d,
                               wihd, whhd, bihd, bhhd, hdb, smem);
    }
}

// ---------------------------------------------------------------------------
// Fused mem-GRU (T=1, h0=0 -> f=(1-z)*n) + concat -> bf16 x0 [2048][320].
// ---------------------------------------------------------------------------
__global__ __launch_bounds__(256) void memfuse_kernel(
    const float* __restrict__ obs,
    const unsigned short* __restrict__ hpb, const unsigned short* __restrict__ hdb,
    const unsigned short* __restrict__ mwp, const unsigned short* __restrict__ mwd,
    const float* __restrict__ mbip, const float* __restrict__ mbhp,
    const float* __restrict__ mbid, const float* __restrict__ mbhd,
    unsigned short* __restrict__ x0b)
{
    __shared__ __align__(16) unsigned short Asl[64*40];
    __shared__ __align__(16) unsigned short Bsl[3][64*40];
    const int tid = threadIdx.x;
    const int wave = tid >> 6, lane = tid & 63, quad = lane >> 4, l16 = lane & 15;
    const int z = blockIdx.x, m0 = blockIdx.y * 64;
    const bool isp = (z < 3);
    const unsigned short* A = isp ? hpb : hdb;
    const unsigned short* B = isp ? mwp : mwd;
    const float* bi = isp ? mbip : mbid;
    const float* bh = isp ? mbhp : mbhd;
    const int Kp = isp ? 192 : 64;
    const int Hh = isp ? 187 : 64;
    const int jb = isp ? z * 64 : 0;
    const int cbase = isp ? 48 : 235;
    const int r = tid >> 2, sg = (tid & 3) * 8;

    f32x4 acc[3][4];
#pragma unroll
    for (int g = 0; g < 3; ++g)
#pragma unroll
        for (int nt = 0; nt < 4; ++nt) acc[g][nt] = splat4(0.f);

    for (int k0 = 0; k0 < Kp; k0 += 32) {
        *(short8*)(Asl + r*40 + sg) = *(const short8*)(A + (size_t)(m0 + r)*Kp + k0 + sg);
#pragma unroll
        for (int g = 0; g < 3; ++g)
            *(short8*)(Bsl[g] + r*40 + sg) =
                *(const short8*)(B + (size_t)(g*Kp + jb + r)*Kp + k0 + sg);
        __syncthreads();
        short8 af = *(const short8*)(Asl + (wave*16 + l16)*40 + quad*8);
#pragma unroll
        for (int g = 0; g < 3; ++g)
#pragma unroll
            for (int nt = 0; nt < 4; ++nt) {
                short8 bf = *(const short8*)(Bsl[g] + (nt*16 + l16)*40 + quad*8);
                acc[g][nt] = __builtin_amdgcn_mfma_f32_16x16x32_bf16(af, bf, acc[g][nt], 0, 0, 0);
            }
        __syncthreads();
    }
#pragma unroll
    for (int nt = 0; nt < 4; ++nt) {
        int j = jb + nt*16 + l16;
        bool valid = (j < Hh);
        float br = 0.f, bz = 0.f, bnx = 0.f, bnh = 0.f;
        if (valid) {
            br  = -L2E * (bi[j] + bh[j]);
            bz  = -L2E * (bi[Hh + j] + bh[Hh + j]);
            bnx = 2.f * L2E * bi[2*Hh + j];
            bnh = 2.f * L2E * bh[2*Hh + j];
        }
#pragma unroll
        for (int jj = 0; jj < 4; ++jj) {
            int m = m0 + wave*16 + quad*4 + jj;
            float rr = rcp1pe_(acc[0][nt][jj] + br);
            float zz = rcp1pe_(acc[1][nt][jj] + bz);
            float tt = __builtin_fmaf(rr, bnh, acc[2][nt][jj] + bnx);
            float nn = __builtin_fmaf(-2.f, rcp1pe_(tt), 1.f);
            float v  = (1.f - zz) * nn;
            if (valid) x0b[(size_t)m*320 + cbase + j] = f2bf(v);
        }
    }
    if (z == 0) {
        for (int e = tid; e < 64*48; e += 256) {
            int m = m0 + e / 48, cc = e - (e / 48) * 48;
            x0b[(size_t)m*320 + cc] = f2bf(obs[(size_t)m*3120 + cc]);
        }
    }
    if (z == 3) {
        for (int e = tid; e < 64*21; e += 256) {
            int m = m0 + e / 21, cc = 299 + (e - (e / 21) * 21);
            x0b[(size_t)m*320 + cc] = 0;
        }
    }
}

// ---------------------------------------------------------------------------
// bf16 MFMA GEMM, K-tile 64. mode 1: ELU + bf16 out. mode 0: fp32 out.
// ---------------------------------------------------------------------------
__global__ __launch_bounds__(256) void bgemm_kernel(
    const unsigned short* __restrict__ A, const unsigned short* __restrict__ B,
    const float* __restrict__ bias, void* __restrict__ C,
    int Kp, int Np, int Nstore, int mode)
{
    __shared__ __align__(16) unsigned short Asl[64*72];
    __shared__ __align__(16) unsigned short Bsl[64*72];
    const int tid = threadIdx.x;
    const int wave = tid >> 6, lane = tid & 63, quad = lane >> 4, l16 = lane & 15;
    const int n0 = blockIdx.x * 64, m0 = blockIdx.y * 64;
    const int r = tid >> 2, sg = (tid & 3) * 16;

    f32x4 acc[4];
#pragma unroll
    for (int nt = 0; nt < 4; ++nt) acc[nt] = splat4(0.f);

    for (int k0 = 0; k0 < Kp; k0 += 64) {
        *(short8*)(Asl + r*72 + sg)     = *(const short8*)(A + (size_t)(m0 + r)*Kp + k0 + sg);
        *(short8*)(Asl + r*72 + sg + 8) = *(const short8*)(A + (size_t)(m0 + r)*Kp + k0 + sg + 8);
        if (n0 + r < Np) {
            *(short8*)(Bsl + r*72 + sg)     = *(const short8*)(B + (size_t)(n0 + r)*Kp + k0 + sg);
            *(short8*)(Bsl + r*72 + sg + 8) = *(const short8*)(B + (size_t)(n0 + r)*Kp + k0 + sg + 8);
        } else {
            short8 zz; for (int q = 0; q < 8; ++q) zz[q] = 0;
            *(short8*)(Bsl + r*72 + sg) = zz;
            *(short8*)(Bsl + r*72 + sg + 8) = zz;
        }
        __syncthreads();
#pragma unroll
        for (int ks = 0; ks < 2; ++ks) {
            short8 af = *(const short8*)(Asl + (wave*16 + l16)*72 + ks*32 + quad*8);
#pragma unroll
            for (int nt = 0; nt < 4; ++nt) {
                short8 bf = *(const short8*)(Bsl + (nt*16 + l16)*72 + ks*32 + quad*8);
                acc[nt] = __builtin_amdgcn_mfma_f32_16x16x32_bf16(af, bf, acc[nt], 0, 0, 0);
            }
        }
        __syncthreads();
    }
#pragma unroll
    for (int nt = 0; nt < 4; ++nt) {
        int n = n0 + nt*16 + l16;
        float bv = (bias && n < Np) ? bias[n] : 0.f;
#pragma unroll
        for (int j = 0; j < 4; ++j) {
            int m = m0 + wave*16 + quad*4 + j;
            float v = acc[nt][j] + bv;
            if (mode == 1) {
                ((unsigned short*)C)[(size_t)m*Np + n] = f2bf(elu_(v));
            } else {
                if (n < Nstore) ((float*)C)[(size_t)m*Nstore + n] = v;
            }
        }
    }
}

// ---------------------------------------------------------------------------
// Fused actor layers 3+4 -> out fp32 [2048][12]. 32 blocks, 256 thr.
// ---------------------------------------------------------------------------
__global__ __launch_bounds__(256) void gemm34_kernel(
    const unsigned short* __restrict__ A,   // a3b [2048][256]
    const unsigned short* __restrict__ W3,  // w3p [128][256]
    const float* __restrict__ b3,
    const unsigned short* __restrict__ W4,  // w4p [16][128]
    const float* __restrict__ b4,
    float* __restrict__ out)
{
    __shared__ __align__(16) char smem[9216 + 18432];
    unsigned short* Asl  = (unsigned short*)smem;
    unsigned short* B3sl = (unsigned short*)(smem + 9216);
    unsigned short* a4s  = (unsigned short*)smem;            // aliases, post-barrier
    const int tid = threadIdx.x;
    const int wave = tid >> 6, lane = tid & 63, quad = lane >> 4, l16 = lane & 15;
    const int m0 = blockIdx.x * 64;

    f32x4 acc3[8];
#pragma unroll
    for (int nt = 0; nt < 8; ++nt) acc3[nt] = splat4(0.f);

    const int r = tid >> 2, sg = (tid & 3) * 16;
    const int r2 = tid >> 1, sg2 = (tid & 1) * 32;
    for (int k0 = 0; k0 < 256; k0 += 64) {
        *(short8*)(Asl + r*72 + sg)     = *(const short8*)(A + (size_t)(m0 + r)*256 + k0 + sg);
        *(short8*)(Asl + r*72 + sg + 8) = *(const short8*)(A + (size_t)(m0 + r)*256 + k0 + sg + 8);
#pragma unroll
        for (int s = 0; s < 4; ++s)
            *(short8*)(B3sl + r2*72 + sg2 + s*8) =
                *(const short8*)(W3 + (size_t)r2*256 + k0 + sg2 + s*8);
        __syncthreads();
#pragma unroll
        for (int ks = 0; ks < 2; ++ks) {
            short8 af = *(const short8*)(Asl + (wave*16 + l16)*72 + ks*32 + quad*8);
#pragma unroll
            for (int nt = 0; nt < 8; ++nt) {
                short8 bf = *(const short8*)(B3sl + (nt*16 + l16)*72 + ks*32 + quad*8);
                acc3[nt] = __builtin_amdgcn_mfma_f32_16x16x32_bf16(af, bf, acc3[nt], 0, 0, 0);
            }
        }
        __syncthreads();
    }
#pragma unroll
    for (int nt = 0; nt < 8; ++nt) {
        int n = nt*16 + l16;
        float bv = b3[n];
#pragma unroll
        for (int j = 0; j < 4; ++j) {
            int m = wave*16 + quad*4 + j;
            a4s[m*136 + n] = f2bf(elu_(acc3[nt][j] + bv));
        }
    }
    __syncthreads();
    f32x4 acc4 = splat4(0.f);
#pragma unroll
    for (int ks = 0; ks < 4; ++ks) {
        short8 af = *(const short8*)(a4s + (wave*16 + l16)*136 + ks*32 + quad*8);
        short8 bf = *(const short8*)(W4 + (size_t)l16*128 + ks*32 + quad*8);
        acc4 = __builtin_amdgcn_mfma_f32_16x16x32_bf16(af, bf, acc4, 0, 0, 0);
    }
    if (l16 < 12) {
        float bv = b4[l16];
#pragma unroll
        for (int j = 0; j < 4; ++j)
            out[(size_t)(m0 + wave*16 + quad*4 + j)*12 + l16] = acc4[j] + bv;
    }
}

// ---------------------------------------------------------------------------
extern "C" void kernel_launch(void* const* d_in, const int* in_sizes, int n_in,
                              void* d_out, int out_size, void* d_ws, size_t ws_size,
                              hipStream_t stream)
{
    (void)in_sizes; (void)n_in; (void)out_size;
    const float* obs        = (const float*)d_in[0];
    const int*   prox_idx   = (const int*)d_in[1];
    const int*   dist_idx   = (const int*)d_in[2];
    const float* pe_prox_w1 = (const float*)d_in[3];
    const float* pe_prox_b1 = (const float*)d_in[4];
    const float* pe_prox_w2 = (const float*)d_in[5];
    const float* pe_prox_b2 = (const float*)d_in[6];
    const float* pe_dist_w1 = (const float*)d_in[7];
    const float* pe_dist_b1 = (const float*)d_in[8];
    const float* pe_dist_w2 = (const float*)d_in[9];
    const float* pe_dist_b2 = (const float*)d_in[10];
    const float* gp_wih = (const float*)d_in[11];
    const float* gp_whh = (const float*)d_in[12];
    const float* gp_bih = (const float*)d_in[13];
    const float* gp_bhh = (const float*)d_in[14];
    const float* gd_wih = (const float*)d_in[15];
    const float* gd_whh = (const float*)d_in[16];
    const float* gd_bih = (const float*)d_in[17];
    const float* gd_bhh = (const float*)d_in[18];
    const float* mp_wih = (const float*)d_in[19];
    const float* mp_bih = (const float*)d_in[21];
    const float* mp_bhh = (const float*)d_in[22];
    const float* md_wih = (const float*)d_in[23];
    const float* md_bih = (const float*)d_in[25];
    const float* md_bhh = (const float*)d_in[26];
    const float* aw0 = (const float*)d_in[27]; const float* ab0 = (const float*)d_in[28];
    const float* aw1 = (const float*)d_in[29]; const float* ab1 = (const float*)d_in[30];
    const float* aw2 = (const float*)d_in[31]; const float* ab2 = (const float*)d_in[32];
    const float* aw3 = (const float*)d_in[33]; const float* ab3 = (const float*)d_in[34];
    const float* aw4 = (const float*)d_in[35]; const float* ab4 = (const float*)d_in[36];
    float* out = (float*)d_out;

    char* ws = (char*)d_ws;
    size_t off = 0;
    auto alloc = [&](size_t bytes) -> char* {
        char* p = ws + off;
        off = (off + bytes + 255) & ~(size_t)255;
        return p;
    };
    unsigned short* wih_p = (unsigned short*)alloc(36864*2);
    unsigned short* whh_p = (unsigned short*)alloc(110592*2);
    unsigned short* wih_d = (unsigned short*)alloc(12288*2);
    unsigned short* whh_d = (unsigned short*)alloc(12288*2);
    unsigned short* mw_p  = (unsigned short*)alloc(110592*2);
    unsigned short* mw_d  = (unsigned short*)alloc(12288*2);
    unsigned short* w0p   = (unsigned short*)alloc((size_t)1024*320*2);
    unsigned short* w1p   = (unsigned short*)alloc((size_t)512*1024*2);
    unsigned short* w2p   = (unsigned short*)alloc((size_t)256*512*2);
    unsigned short* w3p   = (unsigned short*)alloc((size_t)128*256*2);
    unsigned short* w4p   = (unsigned short*)alloc((size_t)16*128*2);
    uint8_t* wih8         = (uint8_t*)alloc(576*64);
    unsigned short* hpb   = (unsigned short*)alloc((size_t)2048*192*2);
    unsigned short* hdb   = (unsigned short*)alloc((size_t)2048*64*2);
    unsigned short* x0b   = (unsigned short*)alloc((size_t)2048*320*2);
    unsigned short* a1b   = (unsigned short*)alloc((size_t)2048*1024*2);
    unsigned short* a2b   = (unsigned short*)alloc((size_t)2048*512*2);
    unsigned short* a3b   = (unsigned short*)alloc((size_t)2048*256*2);
    uint8_t* enc8         = (uint8_t*)alloc((size_t)2048*512*64);   // 67 MB, LAST
    const int mode = (off <= ws_size) ? 0 : 1;   // fall back if ws too small

    const float SR = -L2E, SN = 2.f * L2E;
    PJobs P;
    int tot[12];
    P.j[0]  = { gp_wih, wih_p, 187, 192, 64, 64, SR, SR, SN, 0 };      tot[0]  = 36864;
    P.j[1]  = { gp_whh, whh_p, 187, 192, 187, 192, SR, SR, SN, 0 };    tot[1]  = 110592;
    P.j[2]  = { gd_wih, wih_d, 64, 64, 64, 64, SR, SR, SN, 0 };        tot[2]  = 12288;
    P.j[3]  = { gd_whh, whh_d, 64, 64, 64, 64, SR, SR, SN, 0 };        tot[3]  = 12288;
    P.j[4]  = { mp_wih, mw_p, 187, 192, 187, 192, SR, SR, SN, 0 };     tot[4]  = 110592;
    P.j[5]  = { md_wih, mw_d, 64, 64, 64, 64, SR, SR, SN, 0 };         tot[5]  = 12288;
    P.j[6]  = { aw0, w0p, 1024, 1024, 299, 320, 1.f, 1.f, 1.f, 0 };    tot[6]  = 327680;
    P.j[7]  = { aw1, w1p, 512, 512, 1024, 1024, 1.f, 1.f, 1.f, 0 };    tot[7]  = 524288;
    P.j[8]  = { aw2, w2p, 256, 256, 512, 512, 1.f, 1.f, 1.f, 0 };      tot[8]  = 131072;
    P.j[9]  = { aw3, w3p, 128, 128, 256, 256, 1.f, 1.f, 1.f, 0 };      tot[9]  = 32768;
    P.j[10] = { aw4, w4p, 12, 16, 128, 128, 1.f, 1.f, 1.f, 0 };        tot[10] = 2048;
    P.j[11] = { gp_wih, wih8, 187, 192, 64, 64, SR, SR, SN, 1 };       tot[11] = 36864;
    P.pref[0] = 0;
    for (int i = 0; i < 12; ++i) P.pref[i+1] = P.pref[i] + tot[i];
    const int npack = (P.pref[12] + 255) / 256;
    pack_all<<<npack, 256, 0, stream>>>(P);

    if (mode == 0) {
        enc_kernel<<<2048, 256, 0, stream>>>(
            obs, prox_idx, pe_prox_w1, pe_prox_b1, pe_prox_w2, pe_prox_b2, enc8);
    }

    gru_kernel<<<256, 768, 0, stream>>>(
        mode, obs, prox_idx, dist_idx, enc8, wih8,
        pe_prox_w1, pe_prox_b1, pe_prox_w2, pe_prox_b2,
        pe_dist_w1, pe_dist_b1, pe_dist_w2, pe_dist_b2,
        wih_p, whh_p, wih_d, whh_d,
        gp_bih, gp_bhh, gd_bih, gd_bhh, hpb, hdb);

    // --- fused mem-GRU gemm + gates + concat -> bf16 x0 ---
    memfuse_kernel<<<dim3(4, 32), 256, 0, stream>>>(
        obs, hpb, hdb, mw_p, mw_d, mp_bih, mp_bhh, md_bih, md_bhh, x0b);

    // --- actor MLP: bgemm x3, then fused layers 3+4 ---
    bgemm_kernel<<<dim3(16, 32), 256, 0, stream>>>(x0b, w0p, ab0, a1b, 320, 1024, 1024, 1);
    bgemm_kernel<<<dim3(8,  32), 256, 0, stream>>>(a1b, w1p, ab1, a2b, 1024, 512, 512, 1);
    bgemm_kernel<<<dim3(4,  32), 256, 0, stream>>>(a2b, w2p, ab2, a3b, 512, 256, 256, 1);
    gemm34_kernel<<<32, 256, 0, stream>>>(a3b, w3p, ab3, w4p, ab4, out);
}